// Round 8
// baseline (2443.939 us; speedup 1.0000x reference)
//
#include <hip/hip_runtime.h>
#include <math.h>

#define HW 4096
#define NB 256

typedef __attribute__((ext_vector_type(8))) short bf16x8_t;
typedef __attribute__((ext_vector_type(16))) float f32x16_t;

__device__ __forceinline__ float gelu_f(float x) {
    return 0.5f * x * (1.0f + erff(x * 0.70710678118654752440f));
}
__device__ __forceinline__ unsigned short f2bf(float f) {
    unsigned int u = __float_as_uint(f);
    unsigned int r = u + 0x7FFFu + ((u >> 16) & 1u);
    return (unsigned short)(r >> 16);
}
__device__ __forceinline__ float bf2f(unsigned short h) {
    return __uint_as_float(((unsigned int)h) << 16);
}

// ---------------------------------------------------------------------------
// Gaussian center window
// ---------------------------------------------------------------------------
__global__ __launch_bounds__(256) void gauss_kernel(float* __restrict__ gauss) {
    __shared__ float sg[HW];
    __shared__ float sR[4];
    int tid = threadIdx.x;
    float part = 0.0f;
    for (int p = tid; p < HW; p += 256) {
        int y = p >> 6, x = p & 63;
        float yy = -1.0f + (2.0f / 63.0f) * (float)y;
        float xx = -1.0f + (2.0f / 63.0f) * (float)x;
        float g = expf(-(yy * yy + xx * xx) * 2.0f);
        sg[p] = g;
        part += g;
    }
#pragma unroll
    for (int off = 32; off > 0; off >>= 1) part += __shfl_down(part, off);
    if ((tid & 63) == 0) sR[tid >> 6] = part;
    __syncthreads();
    float invt = 1.0f / (sR[0] + sR[1] + sR[2] + sR[3]);
    for (int p = tid; p < HW; p += 256) gauss[p] = sg[p] * invt;
}

// ---------------------------------------------------------------------------
// Pack conv weights (fp32 OIHW) into MFMA B-fragment order, split bf16 hi/lo.
// ---------------------------------------------------------------------------
__global__ __launch_bounds__(256) void prep_w_kernel(
    const float* __restrict__ rWs, const float* __restrict__ vWs,
    unsigned short* __restrict__ wq) {
    int i = blockIdx.x * 256 + threadIdx.x;
    if (i >= 110592) return;
    int j = i & 7;
    int lane = (i >> 3) & 63;
    int f = i >> 9;
    int hl = f & 1, k2 = (f >> 1) & 1, tap = (f >> 2) % 9, layer = (f >> 2) / 9;
    int co = lane & 31, hf = lane >> 5;
    int ci = k2 * 16 + hf * 8 + j;
    int ky = tap / 3, kx = tap % 3;
    float wv = (layer < 3)
        ? rWs[(((size_t)layer * 32 + co) * 32 + ci) * 9 + ky * 3 + kx]
        : vWs[(((size_t)(layer - 3) * 32 + co) * 32 + ci) * 9 + ky * 3 + kx];
    unsigned short h = f2bf(wv);
    unsigned short l = f2bf(wv - bf2f(h));
    wq[i] = hl ? l : h;
}

// ---------------------------------------------------------------------------
// First conv layer (CIN=6 rubin / CIN=1 vis), fp32 VALU. Writes RAW Q + stats.
// ---------------------------------------------------------------------------
template <int CIN>
__global__ __launch_bounds__(256) void conv_first_kernel(
    const float* __restrict__ in, const float* __restrict__ w,
    unsigned short* __restrict__ qout, float* __restrict__ statp) {
    const int b = blockIdx.y;
    const int strip = blockIdx.x;
    const int tid = threadIdx.x;
    const int x = tid & 63;
    const int wid = tid >> 6;

    __shared__ float sIn[CIN][6][66];
    __shared__ float sRed[4][8];

    const float* inb = in + (size_t)b * CIN * HW;
    for (int idx = tid; idx < CIN * 6 * 66; idx += 256) {
        int ci = idx / (6 * 66);
        int rem = idx - ci * (6 * 66);
        int r = rem / 66;
        int p = rem - r * 66;
        int gy = strip * 4 - 1 + r;
        int gx = p - 1;
        float v = 0.0f;
        if (gy >= 0 && gy < 64 && gx >= 0 && gx < 64) v = inb[ci * HW + gy * 64 + gx];
        sIn[ci][r][p] = v;
    }
    __syncthreads();

    float acc[32];
#pragma unroll
    for (int co = 0; co < 32; ++co) acc[co] = 0.0f;

    for (int ci = 0; ci < CIN; ++ci) {
        float vv[9];
#pragma unroll
        for (int ky = 0; ky < 3; ++ky)
#pragma unroll
            for (int kx = 0; kx < 3; ++kx) vv[ky * 3 + kx] = sIn[ci][wid + ky][x + kx];
#pragma unroll
        for (int co = 0; co < 32; ++co) {
            const float* wk = w + ((size_t)co * CIN + ci) * 9;
            float s = acc[co];
#pragma unroll
            for (int k = 0; k < 9; ++k) s = fmaf(wk[k], vv[k], s);
            acc[co] = s;
        }
    }

    const int gy = strip * 4 + wid;
    {
        int rot = x & 7;
        char* pb = (char*)qout + (((size_t)b * HW) + (size_t)gy * 64 + x) * 128;
#pragma unroll
        for (int s = 0; s < 4; ++s) {
            unsigned int hw_[4], lw_[4];
#pragma unroll
            for (int e = 0; e < 4; ++e) {
                int c = s * 8 + e * 2;
                unsigned short h0 = f2bf(acc[c]);
                float r0 = acc[c] - bf2f(h0);
                unsigned short h1 = f2bf(acc[c + 1]);
                float r1 = acc[c + 1] - bf2f(h1);
                hw_[e] = (unsigned)h0 | ((unsigned)h1 << 16);
                lw_[e] = (unsigned)f2bf(r0) | ((unsigned)f2bf(r1) << 16);
            }
            uint4 uh; uh.x = hw_[0]; uh.y = hw_[1]; uh.z = hw_[2]; uh.w = hw_[3];
            uint4 ul; ul.x = lw_[0]; ul.y = lw_[1]; ul.z = lw_[2]; ul.w = lw_[3];
            *(uint4*)(pb + (((s + rot) & 7) * 16)) = uh;
            *(uint4*)(pb + (((s + 4 + rot) & 7) * 16)) = ul;
        }
    }
    float s1[4] = {0, 0, 0, 0}, s2[4] = {0, 0, 0, 0};
#pragma unroll
    for (int co = 0; co < 32; ++co) {
        float v = acc[co];
        s1[co >> 3] += v;
        s2[co >> 3] = fmaf(v, v, s2[co >> 3]);
    }
#pragma unroll
    for (int off = 32; off > 0; off >>= 1) {
#pragma unroll
        for (int g = 0; g < 4; ++g) {
            s1[g] += __shfl_down(s1[g], off);
            s2[g] += __shfl_down(s2[g], off);
        }
    }
    if ((tid & 63) == 0) {
#pragma unroll
        for (int g = 0; g < 4; ++g) {
            sRed[wid][g] = s1[g];
            sRed[wid][4 + g] = s2[g];
        }
    }
    __syncthreads();
    if (tid < 8) {
        float t = sRed[0][tid] + sRed[1][tid] + sRed[2][tid] + sRed[3][tid];
        statp[((size_t)b * 16 + strip) * 8 + tid] = t;
    }
}

// ---------------------------------------------------------------------------
// GN finalize: per-strip stats -> per-(b,c) affine coefs  y = a*x + b
// ---------------------------------------------------------------------------
__global__ __launch_bounds__(256) void gn_finalize_kernel(
    const float* __restrict__ statp, const float* __restrict__ gma,
    const float* __restrict__ bta, float* __restrict__ coef, int n) {
    int i = blockIdx.x * 256 + threadIdx.x;
    if (i >= n) return;
    int b = i >> 5, c = i & 31, g = c >> 3;
    float s1 = 0.0f, s2 = 0.0f;
    for (int s = 0; s < 16; ++s) {
        s1 += statp[((size_t)b * 16 + s) * 8 + g];
        s2 += statp[((size_t)b * 16 + s) * 8 + 4 + g];
    }
    const float invN = 1.0f / 32768.0f;
    float mean = s1 * invN;
    float var = s2 * invN - mean * mean;
    float rstd = rsqrtf(var + 1e-5f);
    float a = rstd * gma[c];
    float bb = bta[c] - mean * a;
    coef[i * 2 + 0] = a;
    coef[i * 2 + 1] = bb;
}

// ---------------------------------------------------------------------------
// MFMA 3x3 conv with FUSED input GN+GELU, CIN=COUT=32, split-bf16 3-term,
// CHANNEL-SPLIT staging: two k2-halves of 16 ci each; per half stage 6 rows x
// 66 slots x 80B (64B data: H0,H1,L0,L1 16B sub-blocks + 16B pad) = 31.7 KiB
// -> ~5 blocks/CU (was 3 at 50.7 KiB). acc carried across halves; output and
// all math value-identical to the single-pass version.
// Epilogue: 2 chunks of 128 px via LDS transpose [128][34], coalesced stores.
// ---------------------------------------------------------------------------
#define ROWB 5280  // 66 slots * 80 B
__global__ __launch_bounds__(128) void convm_kernel(
    const unsigned short* __restrict__ qin, const float* __restrict__ coef,
    const unsigned short* __restrict__ wq,
    unsigned short* __restrict__ qout, float* __restrict__ statp) {
    const int b = blockIdx.y;
    const int strip = blockIdx.x;
    const int tid = threadIdx.x;
    const int wv = tid >> 6;
    const int lane = tid & 63;
    const int m = lane & 31;
    const int hf = lane >> 5;
    const int xh32 = wv * 32;

    __shared__ __align__(16) char sQ[6 * ROWB];   // 31680 B
    __shared__ float sRed[2][8];

    const int y0 = strip * 4;
    const char* img = (const char*)qin + (size_t)b * HW * 128;

    // staging ownership: thread -> (pixel, ci-pair), constant across rows
    const int pair = tid & 1;       // which 8-ci group within the half
    const int spx = tid >> 1;       // pixel 0..63
    const int srot = spx & 7;

    // zero halo slots 0 and 65 (not touched by staging; persists both halves)
    if (tid < 48) {
        int r = tid >> 3, side = (tid >> 2) & 1, sub = tid & 3;
        uint4 z; z.x = z.y = z.z = z.w = 0;
        *(uint4*)(sQ + r * ROWB + side * 65 * 80 + sub * 16) = z;
    }

    f32x16_t acc[4];
#pragma unroll
    for (int i = 0; i < 4; ++i)
#pragma unroll
        for (int j = 0; j < 16; ++j) acc[i][j] = 0.0f;

#pragma unroll 1
    for (int half = 0; half < 2; ++half) {
        // per-thread GN coefs for its 8 channels of this half
        const int ci0 = half * 16 + pair * 8;
        float ca[8], cb[8];
#pragma unroll
        for (int e = 0; e < 8; ++e) {
            ca[e] = coef[b * 64 + (ci0 + e) * 2 + 0];
            cb[e] = coef[b * 64 + (ci0 + e) * 2 + 1];
        }
        if (half) __syncthreads();  // previous half's MFMA reads done

        const int g = half * 2 + pair;
        const int offH = ((g + srot) & 7) * 16;
        const int offL = ((g + 4 + srot) & 7) * 16;
        char* dstc = sQ + (spx + 1) * 80 + pair * 16;
#pragma unroll
        for (int r = 0; r < 6; ++r) {
            int gy = y0 - 1 + r;
            uint4 oh, ol;
            if (gy >= 0 && gy < 64) {
                const char* src = img + (size_t)gy * 8192 + spx * 128;
                uint4 uhv = *(const uint4*)(src + offH);
                uint4 ulv = *(const uint4*)(src + offL);
                unsigned int hd[4] = {uhv.x, uhv.y, uhv.z, uhv.w};
                unsigned int ld[4] = {ulv.x, ulv.y, ulv.z, ulv.w};
                unsigned int ho[4], lo_[4];
#pragma unroll
                for (int e = 0; e < 4; ++e) {
                    float x0 = bf2f((unsigned short)(hd[e] & 0xFFFF)) + bf2f((unsigned short)(ld[e] & 0xFFFF));
                    float x1 = bf2f((unsigned short)(hd[e] >> 16)) + bf2f((unsigned short)(ld[e] >> 16));
                    float y0v = gelu_f(fmaf(ca[e * 2], x0, cb[e * 2]));
                    float y1v = gelu_f(fmaf(ca[e * 2 + 1], x1, cb[e * 2 + 1]));
                    unsigned short h0 = f2bf(y0v), h1 = f2bf(y1v);
                    unsigned short l0 = f2bf(y0v - bf2f(h0)), l1 = f2bf(y1v - bf2f(h1));
                    ho[e] = (unsigned)h0 | ((unsigned)h1 << 16);
                    lo_[e] = (unsigned)l0 | ((unsigned)l1 << 16);
                }
                oh.x = ho[0]; oh.y = ho[1]; oh.z = ho[2]; oh.w = ho[3];
                ol.x = lo_[0]; ol.y = lo_[1]; ol.z = lo_[2]; ol.w = lo_[3];
            } else {
                oh.x = oh.y = oh.z = oh.w = 0;
                ol.x = ol.y = ol.z = ol.w = 0;
            }
            *(uint4*)(dstc + r * ROWB) = oh;        // H at pair*16
            *(uint4*)(dstc + r * ROWB + 32) = ol;   // L at 32 + pair*16
        }
        __syncthreads();

#pragma unroll
        for (int kx = 0; kx < 3; ++kx) {
            bf16x8_t Wf[3][2];  // [ky][hl]
#pragma unroll
            for (int ky = 0; ky < 3; ++ky)
#pragma unroll
                for (int hl = 0; hl < 2; ++hl) {
                    int fi = ((ky * 3 + kx) * 2 + half) * 2 + hl;
                    Wf[ky][hl] = __builtin_bit_cast(
                        bf16x8_t, *(const uint4*)(wq + (size_t)fi * 512 + lane * 8));
                }
            const char* colp = sQ + (xh32 + kx + m) * 80 + hf * 16;
#pragma unroll
            for (int li = 0; li < 6; ++li) {
                const char* rowp = colp + li * ROWB;
                bf16x8_t Ah = __builtin_bit_cast(bf16x8_t, *(const uint4*)(rowp));
                bf16x8_t Al = __builtin_bit_cast(bf16x8_t, *(const uint4*)(rowp + 32));
#pragma unroll
                for (int ky = 0; ky < 3; ++ky) {
                    int orow = li - ky;
                    if (orow < 0 || orow > 3) continue;
                    acc[orow] = __builtin_amdgcn_mfma_f32_32x32x16_bf16(Ah, Wf[ky][0], acc[orow], 0, 0, 0);
                    acc[orow] = __builtin_amdgcn_mfma_f32_32x32x16_bf16(Ah, Wf[ky][1], acc[orow], 0, 0, 0);
                    acc[orow] = __builtin_amdgcn_mfma_f32_32x32x16_bf16(Al, Wf[ky][0], acc[orow], 0, 0, 0);
                }
            }
        }
    }

    // ---- epilogue: stats + 2-chunk LDS transpose + coalesced stores
    __syncthreads();  // all MFMA reads of sQ complete; sQ reusable
    const int co = lane & 31;
    float s1 = 0.0f, s2 = 0.0f;
#pragma unroll
    for (int orow = 0; orow < 4; ++orow)
#pragma unroll
        for (int r = 0; r < 16; ++r) {
            float v = acc[orow][r];
            s1 += v;
            s2 = fmaf(v, v, s2);
        }
    s1 += __shfl_xor(s1, 32); s2 += __shfl_xor(s2, 32);
    s1 += __shfl_xor(s1, 1);  s2 += __shfl_xor(s2, 1);
    s1 += __shfl_xor(s1, 2);  s2 += __shfl_xor(s2, 2);
    s1 += __shfl_xor(s1, 4);  s2 += __shfl_xor(s2, 4);
    if (lane < 32 && (lane & 7) == 0) {
        sRed[wv][co >> 3] = s1;
        sRed[wv][4 + (co >> 3)] = s2;
    }

    unsigned int* lds_t = (unsigned int*)sQ;  // [128 px][34] u32 per chunk
    char* ob = (char*)qout + ((size_t)b * HW + (size_t)y0 * 64) * 128;
#pragma unroll 1
    for (int c = 0; c < 2; ++c) {
#pragma unroll
        for (int oi = 0; oi < 2; ++oi) {
            int orow = c * 2 + oi;
#pragma unroll
            for (int r = 0; r < 16; ++r) {
                int mm = (r & 3) + 8 * (r >> 2) + 4 * hf;
                int pxl = oi * 64 + xh32 + mm;
                float v = acc[orow][r];
                unsigned short hv = f2bf(v);
                unsigned short lv = f2bf(v - bf2f(hv));
                lds_t[pxl * 34 + co] = (unsigned)hv | ((unsigned)lv << 16);
            }
        }
        __syncthreads();
        if (c == 0 && tid < 8)
            statp[((size_t)b * 16 + strip) * 8 + tid] = sRed[0][tid] + sRed[1][tid];
        {
            int pxg = c * 128 + tid;
            int rot = pxg & 7;
            char* pb = ob + (size_t)pxg * 128;
#pragma unroll
            for (int s = 0; s < 4; ++s) {
                unsigned int hw_[4], lw_[4];
#pragma unroll
                for (int j = 0; j < 4; ++j) {
                    int c0 = s * 8 + j * 2;
                    uint2 t2 = *(const uint2*)(lds_t + tid * 34 + c0);
                    hw_[j] = (t2.x & 0xFFFFu) | (t2.y << 16);
                    lw_[j] = (t2.x >> 16) | (t2.y & 0xFFFF0000u);
                }
                uint4 uh; uh.x = hw_[0]; uh.y = hw_[1]; uh.z = hw_[2]; uh.w = hw_[3];
                uint4 ul; ul.x = lw_[0]; ul.y = lw_[1]; ul.z = lw_[2]; ul.w = lw_[3];
                *(uint4*)(pb + (((s + rot) & 7) * 16)) = uh;
                *(uint4*)(pb + (((s + 4 + rot) & 7) * 16)) = ul;
            }
        }
        __syncthreads();
    }
}

// ---------------------------------------------------------------------------
// Projection + l2norm + FUSED gauss-pool partials from RAW Q (GN+GELU on read).
// ---------------------------------------------------------------------------
__global__ __launch_bounds__(256) void proj_kernel(
    const unsigned short* __restrict__ q, const float* __restrict__ coef,
    const float* __restrict__ pw, unsigned short* __restrict__ outn,
    float* __restrict__ poolp, float* __restrict__ E, float* __restrict__ swp,
    const float* __restrict__ gauss) {
    int b = blockIdx.y, chunk = blockIdx.x, tid = threadIdx.x;
    int p = chunk * 256 + tid;
    __shared__ float sR[4];
    __shared__ float sc[64];
    __shared__ float red[32][257];
    if (tid < 64) sc[tid] = coef[b * 64 + tid];
    __syncthreads();
    float feat[32];
    {
        int rot = p & 7;
        const char* pb = (const char*)q + (((size_t)b * HW) + p) * 128;
#pragma unroll
        for (int s = 0; s < 4; ++s) {
            uint4 uh = *(const uint4*)(pb + (((s + rot) & 7) * 16));
            uint4 ul = *(const uint4*)(pb + (((s + 4 + rot) & 7) * 16));
            unsigned int hd[4] = {uh.x, uh.y, uh.z, uh.w};
            unsigned int ld[4] = {ul.x, ul.y, ul.z, ul.w};
#pragma unroll
            for (int e = 0; e < 4; ++e) {
                int c0 = s * 8 + e * 2;
                float x0 = bf2f((unsigned short)(hd[e] & 0xFFFF)) + bf2f((unsigned short)(ld[e] & 0xFFFF));
                float x1 = bf2f((unsigned short)(hd[e] >> 16)) + bf2f((unsigned short)(ld[e] >> 16));
                feat[c0] = gelu_f(fmaf(sc[c0 * 2], x0, sc[c0 * 2 + 1]));
                feat[c0 + 1] = gelu_f(fmaf(sc[(c0 + 1) * 2], x1, sc[(c0 + 1) * 2 + 1]));
            }
        }
    }
    float g = gauss[p];
#pragma unroll
    for (int c = 0; c < 32; ++c) red[c][tid] = feat[c] * g;

    float o[32];
#pragma unroll
    for (int oo = 0; oo < 32; ++oo) o[oo] = 0.0f;
    for (int c = 0; c < 32; ++c) {
        float f = feat[c];
#pragma unroll
        for (int oo = 0; oo < 32; ++oo) o[oo] = fmaf(pw[oo * 32 + c], f, o[oo]);
    }
    float nn = 0.0f;
#pragma unroll
    for (int oo = 0; oo < 32; ++oo) nn = fmaf(o[oo], o[oo], nn);
    float n = sqrtf(nn);
    float inv = 1.0f / fmaxf(n, 1e-6f);
    unsigned short* obp = outn + (size_t)b * 32 * HW + p;
#pragma unroll
    for (int oo = 0; oo < 32; ++oo) obp[(size_t)oo * HW] = f2bf(o[oo] * inv);

    __syncthreads();
    if (tid < 32) {
        float s = 0.0f;
#pragma unroll 8
        for (int i = 0; i < 256; ++i) s += red[tid][i];
        poolp[((size_t)b * 16 + chunk) * 32 + tid] = s;
    }

    if (E != nullptr) {
        float e = nn * inv * inv;
        E[(size_t)b * HW + p] = e;
        float wvv = e * g;
#pragma unroll
        for (int off = 32; off > 0; off >>= 1) wvv += __shfl_down(wvv, off);
        if ((tid & 63) == 0) sR[tid >> 6] = wvv;
        __syncthreads();
        if (tid == 0) swp[b * 16 + chunk] = sR[0] + sR[1] + sR[2] + sR[3];
    }
}

// ---------------------------------------------------------------------------
// E <- E * gauss * scale / (sum_p(E*gauss) + 1e-8)
// ---------------------------------------------------------------------------
__global__ __launch_bounds__(256) void swapply_kernel(
    float* __restrict__ E, const float* __restrict__ swp,
    const float* __restrict__ gauss) {
    int b = blockIdx.y, p = blockIdx.x * 256 + threadIdx.x;
    float s = 0.0f;
#pragma unroll
    for (int i = 0; i < 16; ++i) s += swp[b * 16 + i];
    const float scale = 0.17677669529663688f;
    E[(size_t)b * HW + p] = E[(size_t)b * HW + p] * gauss[p] * scale / (s + 1e-8f);
}

// ---------------------------------------------------------------------------
// 49-offset correlation logits, channel-split: grid (bc, 8).
// ---------------------------------------------------------------------------
__global__ __launch_bounds__(256) void logits_kernel(
    const unsigned short* __restrict__ rn, const unsigned short* __restrict__ vn,
    const float* __restrict__ sw, float* __restrict__ lgpart) {
    int b = blockIdx.x, cg = blockIdx.y, tid = threadIdx.x;
    __shared__ float P[38][76];
    __shared__ float sR[4][49];
    float acc[49];
#pragma unroll
    for (int k = 0; k < 49; ++k) acc[k] = 0.0f;
    const float* swb = sw + (size_t)b * HW;
#pragma unroll 1
    for (int cc = 0; cc < 4; ++cc) {
        int c = cg * 4 + cc;
        const unsigned short* vb = vn + ((size_t)b * 32 + c) * HW;
        const unsigned short* rb = rn + ((size_t)b * 32 + c) * HW;
#pragma unroll 1
        for (int half = 0; half < 2; ++half) {
            const int base = half * 32;
            __syncthreads();
            for (int idx = tid; idx < 38 * 72; idx += 256) {
                int r = idx / 72, j = idx - r * 72;
                int gy = base - 3 + r;
                gy = gy < 0 ? 0 : (gy > 63 ? 63 : gy);
                int gx = j - 4;
                gx = gx < 0 ? 0 : (gx > 63 ? 63 : gx);
                P[r][j] = bf2f(vb[gy * 64 + gx]);
            }
            __syncthreads();
            int y = tid >> 3, x0 = (tid & 7) * 8;
            int pbase = (base + y) * 64 + x0;
            uint4 rv = *(const uint4*)(rb + pbase);
            float4 q0 = *(const float4*)(swb + pbase);
            float4 q1 = *(const float4*)(swb + pbase + 4);
            unsigned int rd[4] = {rv.x, rv.y, rv.z, rv.w};
            float r_[8];
            r_[0] = bf2f((unsigned short)(rd[0] & 0xFFFF)) * q0.x;
            r_[1] = bf2f((unsigned short)(rd[0] >> 16)) * q0.y;
            r_[2] = bf2f((unsigned short)(rd[1] & 0xFFFF)) * q0.z;
            r_[3] = bf2f((unsigned short)(rd[1] >> 16)) * q0.w;
            r_[4] = bf2f((unsigned short)(rd[2] & 0xFFFF)) * q1.x;
            r_[5] = bf2f((unsigned short)(rd[2] >> 16)) * q1.y;
            r_[6] = bf2f((unsigned short)(rd[3] & 0xFFFF)) * q1.z;
            r_[7] = bf2f((unsigned short)(rd[3] >> 16)) * q1.w;
#pragma unroll
            for (int dy = 0; dy < 7; ++dy) {
                const float4* Pr = (const float4*)(&P[y + dy][x0]);
                float4 a0 = Pr[0], a1 = Pr[1], a2 = Pr[2], a3 = Pr[3];
                float v[16] = {a0.x, a0.y, a0.z, a0.w, a1.x, a1.y, a1.z, a1.w,
                               a2.x, a2.y, a2.z, a2.w, a3.x, a3.y, a3.z, a3.w};
#pragma unroll
                for (int dx = 0; dx < 7; ++dx) {
#pragma unroll
                    for (int j = 0; j < 8; ++j)
                        acc[dy * 7 + dx] = fmaf(r_[j], v[j + dx + 1], acc[dy * 7 + dx]);
                }
            }
        }
    }
#pragma unroll
    for (int k = 0; k < 49; ++k) {
#pragma unroll
        for (int off = 32; off > 0; off >>= 1) acc[k] += __shfl_down(acc[k], off);
    }
    int wid = tid >> 6;
    __syncthreads();
    if ((tid & 63) == 0) {
#pragma unroll
        for (int k = 0; k < 49; ++k) sR[wid][k] = acc[k];
    }
    __syncthreads();
    if (tid < 49)
        lgpart[((size_t)b * 8 + cg) * 49 + tid] =
            sR[0][tid] + sR[1][tid] + sR[2][tid] + sR[3][tid];
}

// ---------------------------------------------------------------------------
// Softmax/coarse + MLP head + output assembly. Reduces logit & pool partials.
// ---------------------------------------------------------------------------
__global__ __launch_bounds__(128) void head_kernel(
    const float* __restrict__ lg, const float* __restrict__ rpp,
    const float* __restrict__ vpp, const float* __restrict__ p2s,
    const float* __restrict__ log_temp,
    const float* __restrict__ W1, const float* __restrict__ b1,
    const float* __restrict__ W2, const float* __restrict__ b2,
    const float* __restrict__ W3, const float* __restrict__ b3,
    float* __restrict__ out) {
    int b = blockIdx.x, t = threadIdx.x;
    __shared__ float slg[49];
    __shared__ float pooled[98];
    __shared__ float h1[128], h2[128];
    __shared__ float cxy[2];
    __shared__ float res[3];
    const float* lgp = lg + (size_t)b * 8 * 49;
    if (t < 49) {
        float s = 0.0f;
#pragma unroll
        for (int g = 0; g < 8; ++g) s += lgp[g * 49 + t];
        slg[t] = s;
    }
    __syncthreads();
    if (t == 0) {
        float temp = fmaxf(expf(log_temp[0]), 0.001f);
        float invT = 1.0f / temp;
        float m = -1e30f;
        for (int k = 0; k < 49; ++k) m = fmaxf(m, slg[k] * invT);
        float s = 0.0f, pdx = 0.0f, pdy = 0.0f;
        for (int k = 0; k < 49; ++k) {
            float e = expf(slg[k] * invT - m);
            s += e;
            pdx += e * (float)((k % 7) - 3);
            pdy += e * (float)((k / 7) - 3);
        }
        cxy[0] = pdx / s;
        cxy[1] = pdy / s;
    }
    __syncthreads();
    if (t < 32) {
        float a = 0.0f, c = 0.0f;
#pragma unroll
        for (int k = 0; k < 16; ++k) {
            a += rpp[((size_t)b * 16 + k) * 32 + t];
            c += vpp[((size_t)b * 16 + k) * 32 + t];
        }
        pooled[t] = a;
        pooled[32 + t] = c;
        pooled[64 + t] = a - c;
    }
    if (t == 0) {
        pooled[96] = cxy[0];
        pooled[97] = cxy[1];
    }
    __syncthreads();
    float s1 = b1[t];
    for (int i = 0; i < 98; ++i) s1 = fmaf(pooled[i], W1[i * 128 + t], s1);
    h1[t] = gelu_f(s1);
    __syncthreads();
    float s2 = b2[t];
    for (int i = 0; i < 128; ++i) s2 = fmaf(h1[i], W2[i * 128 + t], s2);
    h2[t] = gelu_f(s2);
    __syncthreads();
    if (t < 3) {
        float r = b3[t];
        for (int i = 0; i < 128; ++i) r = fmaf(h2[i], W3[i * 3 + t], r);
        res[t] = r;
    }
    __syncthreads();
    if (t == 0) {
        float dxp = cxy[0] + res[0];
        float dyp = cxy[1] + res[1];
        float ls = fminf(fmaxf(res[2], -6.0f), 3.0f);
        const float* M = p2s + b * 4;
        float* ob = out + b * 54;
        ob[0] = dxp;
        ob[1] = dyp;
        ob[2] = M[0] * dxp + M[1] * dyp;
        ob[3] = M[2] * dxp + M[3] * dyp;
        ob[4] = ls;
    }
    if (t < 49) out[b * 54 + 5 + t] = slg[t];
}

extern "C" void kernel_launch(void* const* d_in, const int* in_sizes, int n_in,
                              void* d_out, int out_size, void* d_ws, size_t ws_size,
                              hipStream_t stream) {
    (void)in_sizes; (void)n_in; (void)out_size;
    const float* rubin = (const float*)d_in[0];
    const float* vis   = (const float*)d_in[1];
    const float* p2s   = (const float*)d_in[2];
    const float* rW0   = (const float*)d_in[3];
    const float* rWs   = (const float*)d_in[4];
    const float* rG    = (const float*)d_in[5];
    const float* rBt   = (const float*)d_in[6];
    const float* vW0   = (const float*)d_in[7];
    const float* vWs   = (const float*)d_in[8];
    const float* vG    = (const float*)d_in[9];
    const float* vBt   = (const float*)d_in[10];
    const float* projR = (const float*)d_in[11];
    const float* projV = (const float*)d_in[12];
    const float* logT  = (const float*)d_in[13];
    const float* W1    = (const float*)d_in[14];
    const float* b1    = (const float*)d_in[15];
    const float* W2    = (const float*)d_in[16];
    const float* b2    = (const float*)d_in[17];
    const float* W3    = (const float*)d_in[18];
    const float* b3    = (const float*)d_in[19];
    float* out = (float*)d_out;

    // ---- workspace layout (bytes)
    char* ws = (char*)d_ws;
    size_t off = 0;
    unsigned short* vnB = (unsigned short*)(ws + off); off += (size_t)NB * 32 * HW * 2;  // 67.1 MB
    float* gauss  = (float*)(ws + off); off += HW * 4;
    float* statp  = (float*)(ws + off); off += (size_t)NB * 16 * 8 * 4;
    float* coefS  = (float*)(ws + off); off += (size_t)NB * 64 * 4;
    float* swp    = (float*)(ws + off); off += (size_t)NB * 16 * 4;
    float* rpp    = (float*)(ws + off); off += (size_t)NB * 16 * 32 * 4;
    float* vpp    = (float*)(ws + off); off += (size_t)NB * 16 * 32 * 4;
    float* lgbuf  = (float*)(ws + off); off += (size_t)NB * 8 * 49 * 4;
    unsigned short* wq = (unsigned short*)(ws + off); off += 110592ull * 2;
    off = (off + 255) & ~(size_t)255;
    const size_t fixed_bytes = off;
    const size_t perb = 2ull * HW * 128 + HW * 4;  // Q1+Q2 pixel blocks + E
    int BC = 1;
    if (ws_size > fixed_bytes + perb) {
        size_t t = (ws_size - fixed_bytes) / perb;
        BC = t > (size_t)NB ? NB : (int)t;
    }
    unsigned short* Q1 = (unsigned short*)(ws + off);
    unsigned short* Q2 = (unsigned short*)(ws + off + (size_t)BC * HW * 128);
    float* E = (float*)(ws + off + 2ull * BC * HW * 128);

    dim3 blk256(256), blk128(128);
    gauss_kernel<<<1, 256, 0, stream>>>(gauss);
    prep_w_kernel<<<432, 256, 0, stream>>>(rWs, vWs, wq);

    // ================= VIS encoder (all chunks) =================
    for (int b0 = 0; b0 < NB; b0 += BC) {
        const int bc = (NB - b0) < BC ? (NB - b0) : BC;
        dim3 cg16(16, bc);
        const int gnblk = (bc * 32 + 255) / 256;
        float* sp = statp + (size_t)b0 * 128;
        float* cS = coefS + (size_t)b0 * 64;

        conv_first_kernel<1><<<cg16, blk256, 0, stream>>>(vis + (size_t)b0 * HW, vW0, Q1, sp);
        gn_finalize_kernel<<<gnblk, 256, 0, stream>>>(sp, vG + 0, vBt + 0, cS, bc * 32);
        convm_kernel<<<cg16, blk128, 0, stream>>>(Q1, cS, wq + 3 * 18432, Q2, sp);
        gn_finalize_kernel<<<gnblk, 256, 0, stream>>>(sp, vG + 32, vBt + 32, cS, bc * 32);
        convm_kernel<<<cg16, blk128, 0, stream>>>(Q2, cS, wq + 4 * 18432, Q1, sp);
        gn_finalize_kernel<<<gnblk, 256, 0, stream>>>(sp, vG + 64, vBt + 64, cS, bc * 32);
        convm_kernel<<<cg16, blk128, 0, stream>>>(Q1, cS, wq + 5 * 18432, Q2, sp);
        gn_finalize_kernel<<<gnblk, 256, 0, stream>>>(sp, vG + 96, vBt + 96, cS, bc * 32);
        proj_kernel<<<cg16, blk256, 0, stream>>>(Q2, cS, projV, vnB + (size_t)b0 * 32 * HW,
                                                 vpp + (size_t)b0 * 512,
                                                 (float*)nullptr, (float*)nullptr, gauss);
    }

    // ================= RUBIN encoder + logits (all chunks) =================
    for (int b0 = 0; b0 < NB; b0 += BC) {
        const int bc = (NB - b0) < BC ? (NB - b0) : BC;
        dim3 cg16(16, bc);
        const int gnblk = (bc * 32 + 255) / 256;
        float* sp = statp + (size_t)b0 * 128;
        float* cS = coefS + (size_t)b0 * 64;
        float* sw = swp + (size_t)b0 * 16;
        unsigned short* rnB = Q1;  // dead after last convm reads it

        conv_first_kernel<6><<<cg16, blk256, 0, stream>>>(rubin + (size_t)b0 * 6 * HW, rW0, Q1, sp);
        gn_finalize_kernel<<<gnblk, 256, 0, stream>>>(sp, rG + 0, rBt + 0, cS, bc * 32);
        convm_kernel<<<cg16, blk128, 0, stream>>>(Q1, cS, wq + 0 * 18432, Q2, sp);
        gn_finalize_kernel<<<gnblk, 256, 0, stream>>>(sp, rG + 32, rBt + 32, cS, bc * 32);
        convm_kernel<<<cg16, blk128, 0, stream>>>(Q2, cS, wq + 1 * 18432, Q1, sp);
        gn_finalize_kernel<<<gnblk, 256, 0, stream>>>(sp, rG + 64, rBt + 64, cS, bc * 32);
        convm_kernel<<<cg16, blk128, 0, stream>>>(Q1, cS, wq + 2 * 18432, Q2, sp);
        gn_finalize_kernel<<<gnblk, 256, 0, stream>>>(sp, rG + 96, rBt + 96, cS, bc * 32);
        proj_kernel<<<cg16, blk256, 0, stream>>>(Q2, cS, projR, rnB,
                                                 rpp + (size_t)b0 * 512, E, sw, gauss);
        swapply_kernel<<<cg16, blk256, 0, stream>>>(E, sw, gauss);
        logits_kernel<<<dim3(bc, 8), blk256, 0, stream>>>(rnB, vnB + (size_t)b0 * 32 * HW, E,
                                                          lgbuf + (size_t)b0 * 8 * 49);
    }

    head_kernel<<<NB, 128, 0, stream>>>(lgbuf, rpp, vpp, p2s, logT, W1, b1, W2, b2, W3, b3, out);
}

// Round 9
// 1802.007 us; speedup vs baseline: 1.3562x; 1.3562x over previous
//
#include <hip/hip_runtime.h>
#include <math.h>

#define HW 4096
#define NB 256

typedef __attribute__((ext_vector_type(8))) short bf16x8_t;
typedef __attribute__((ext_vector_type(16))) float f32x16_t;

__device__ __forceinline__ float gelu_f(float x) {
    return 0.5f * x * (1.0f + erff(x * 0.70710678118654752440f));
}
__device__ __forceinline__ unsigned short f2bf(float f) {
    unsigned int u = __float_as_uint(f);
    unsigned int r = u + 0x7FFFu + ((u >> 16) & 1u);
    return (unsigned short)(r >> 16);
}
__device__ __forceinline__ float bf2f(unsigned short h) {
    return __uint_as_float(((unsigned int)h) << 16);
}

// Q layout (PLANAR): Q[b][s][p], s=0..7 (0-3 = H sub-blocks of ci-group s,
// 4-7 = L), p = pixel 0..4095, 16 B each. All global Q accesses are
// lane-consecutive-p -> fully coalesced 1 KB/wave transactions.

// ---------------------------------------------------------------------------
// Gaussian center window
// ---------------------------------------------------------------------------
__global__ __launch_bounds__(256) void gauss_kernel(float* __restrict__ gauss) {
    __shared__ float sg[HW];
    __shared__ float sR[4];
    int tid = threadIdx.x;
    float part = 0.0f;
    for (int p = tid; p < HW; p += 256) {
        int y = p >> 6, x = p & 63;
        float yy = -1.0f + (2.0f / 63.0f) * (float)y;
        float xx = -1.0f + (2.0f / 63.0f) * (float)x;
        float g = expf(-(yy * yy + xx * xx) * 2.0f);
        sg[p] = g;
        part += g;
    }
#pragma unroll
    for (int off = 32; off > 0; off >>= 1) part += __shfl_down(part, off);
    if ((tid & 63) == 0) sR[tid >> 6] = part;
    __syncthreads();
    float invt = 1.0f / (sR[0] + sR[1] + sR[2] + sR[3]);
    for (int p = tid; p < HW; p += 256) gauss[p] = sg[p] * invt;
}

// ---------------------------------------------------------------------------
// Pack conv weights (fp32 OIHW) into MFMA B-fragment order, split bf16 hi/lo.
// ---------------------------------------------------------------------------
__global__ __launch_bounds__(256) void prep_w_kernel(
    const float* __restrict__ rWs, const float* __restrict__ vWs,
    unsigned short* __restrict__ wq) {
    int i = blockIdx.x * 256 + threadIdx.x;
    if (i >= 110592) return;
    int j = i & 7;
    int lane = (i >> 3) & 63;
    int f = i >> 9;
    int hl = f & 1, k2 = (f >> 1) & 1, tap = (f >> 2) % 9, layer = (f >> 2) / 9;
    int co = lane & 31, hf = lane >> 5;
    int ci = k2 * 16 + hf * 8 + j;
    int ky = tap / 3, kx = tap % 3;
    float wv = (layer < 3)
        ? rWs[(((size_t)layer * 32 + co) * 32 + ci) * 9 + ky * 3 + kx]
        : vWs[(((size_t)(layer - 3) * 32 + co) * 32 + ci) * 9 + ky * 3 + kx];
    unsigned short h = f2bf(wv);
    unsigned short l = f2bf(wv - bf2f(h));
    wq[i] = hl ? l : h;
}

// ---------------------------------------------------------------------------
// First conv layer (CIN=6 rubin / CIN=1 vis), fp32 VALU. Writes RAW planar Q
// (coalesced plane stores) + per-strip GN stats.
// ---------------------------------------------------------------------------
template <int CIN>
__global__ __launch_bounds__(256) void conv_first_kernel(
    const float* __restrict__ in, const float* __restrict__ w,
    unsigned short* __restrict__ qout, float* __restrict__ statp) {
    const int b = blockIdx.y;
    const int strip = blockIdx.x;
    const int tid = threadIdx.x;
    const int x = tid & 63;
    const int wid = tid >> 6;

    __shared__ float sIn[CIN][6][66];
    __shared__ float sRed[4][8];

    const float* inb = in + (size_t)b * CIN * HW;
    for (int idx = tid; idx < CIN * 6 * 66; idx += 256) {
        int ci = idx / (6 * 66);
        int rem = idx - ci * (6 * 66);
        int r = rem / 66;
        int p = rem - r * 66;
        int gy = strip * 4 - 1 + r;
        int gx = p - 1;
        float v = 0.0f;
        if (gy >= 0 && gy < 64 && gx >= 0 && gx < 64) v = inb[ci * HW + gy * 64 + gx];
        sIn[ci][r][p] = v;
    }
    __syncthreads();

    float acc[32];
#pragma unroll
    for (int co = 0; co < 32; ++co) acc[co] = 0.0f;

    for (int ci = 0; ci < CIN; ++ci) {
        float vv[9];
#pragma unroll
        for (int ky = 0; ky < 3; ++ky)
#pragma unroll
            for (int kx = 0; kx < 3; ++kx) vv[ky * 3 + kx] = sIn[ci][wid + ky][x + kx];
#pragma unroll
        for (int co = 0; co < 32; ++co) {
            const float* wk = w + ((size_t)co * CIN + ci) * 9;
            float s = acc[co];
#pragma unroll
            for (int k = 0; k < 9; ++k) s = fmaf(wk[k], vv[k], s);
            acc[co] = s;
        }
    }

    const int gy = strip * 4 + wid;
    {
        int gp = gy * 64 + x;
        char* qb = (char*)qout + (size_t)b * 8 * HW * 16;
#pragma unroll
        for (int s = 0; s < 4; ++s) {
            unsigned int hw_[4], lw_[4];
#pragma unroll
            for (int e = 0; e < 4; ++e) {
                int c = s * 8 + e * 2;
                unsigned short h0 = f2bf(acc[c]);
                float r0 = acc[c] - bf2f(h0);
                unsigned short h1 = f2bf(acc[c + 1]);
                float r1 = acc[c + 1] - bf2f(h1);
                hw_[e] = (unsigned)h0 | ((unsigned)h1 << 16);
                lw_[e] = (unsigned)f2bf(r0) | ((unsigned)f2bf(r1) << 16);
            }
            uint4 uh; uh.x = hw_[0]; uh.y = hw_[1]; uh.z = hw_[2]; uh.w = hw_[3];
            uint4 ul; ul.x = lw_[0]; ul.y = lw_[1]; ul.z = lw_[2]; ul.w = lw_[3];
            *(uint4*)(qb + ((size_t)(s * HW) + gp) * 16) = uh;
            *(uint4*)(qb + ((size_t)((s + 4) * HW) + gp) * 16) = ul;
        }
    }
    float s1[4] = {0, 0, 0, 0}, s2[4] = {0, 0, 0, 0};
#pragma unroll
    for (int co = 0; co < 32; ++co) {
        float v = acc[co];
        s1[co >> 3] += v;
        s2[co >> 3] = fmaf(v, v, s2[co >> 3]);
    }
#pragma unroll
    for (int off = 32; off > 0; off >>= 1) {
#pragma unroll
        for (int g = 0; g < 4; ++g) {
            s1[g] += __shfl_down(s1[g], off);
            s2[g] += __shfl_down(s2[g], off);
        }
    }
    if ((tid & 63) == 0) {
#pragma unroll
        for (int g = 0; g < 4; ++g) {
            sRed[wid][g] = s1[g];
            sRed[wid][4 + g] = s2[g];
        }
    }
    __syncthreads();
    if (tid < 8) {
        float t = sRed[0][tid] + sRed[1][tid] + sRed[2][tid] + sRed[3][tid];
        statp[((size_t)b * 16 + strip) * 8 + tid] = t;
    }
}

// ---------------------------------------------------------------------------
// GN finalize: per-strip stats -> per-(b,c) affine coefs  y = a*x + b
// ---------------------------------------------------------------------------
__global__ __launch_bounds__(256) void gn_finalize_kernel(
    const float* __restrict__ statp, const float* __restrict__ gma,
    const float* __restrict__ bta, float* __restrict__ coef, int n) {
    int i = blockIdx.x * 256 + threadIdx.x;
    if (i >= n) return;
    int b = i >> 5, c = i & 31, g = c >> 3;
    float s1 = 0.0f, s2 = 0.0f;
    for (int s = 0; s < 16; ++s) {
        s1 += statp[((size_t)b * 16 + s) * 8 + g];
        s2 += statp[((size_t)b * 16 + s) * 8 + 4 + g];
    }
    const float invN = 1.0f / 32768.0f;
    float mean = s1 * invN;
    float var = s2 * invN - mean * mean;
    float rstd = rsqrtf(var + 1e-5f);
    float a = rstd * gma[c];
    float bb = bta[c] - mean * a;
    coef[i * 2 + 0] = a;
    coef[i * 2 + 1] = bb;
}

// ---------------------------------------------------------------------------
// MFMA 3x3 conv with FUSED input GN+GELU, CIN=COUT=32, split-bf16 3-term.
// Planar-Q global reads (coalesced); LDS keeps the swizzled pixel-block
// layout (rot applied at LDS-write). Staging: wave w, iter k -> sub-block
// s = 2k+w; lane -> pixel. Coefs via LDS table (wave-uniform -> broadcast).
// Epilogue: LDS transpose [256][34] then coalesced plane stores.
// ---------------------------------------------------------------------------
__global__ __launch_bounds__(128) void convm_kernel(
    const unsigned short* __restrict__ qin, const float* __restrict__ coef,
    const unsigned short* __restrict__ wq,
    unsigned short* __restrict__ qout, float* __restrict__ statp) {
    const int b = blockIdx.y;
    const int strip = blockIdx.x;
    const int tid = threadIdx.x;
    const int wv = tid >> 6;
    const int lane = tid & 63;
    const int m = lane & 31;
    const int hf = lane >> 5;
    const int xh32 = wv * 32;

    __shared__ __align__(16) char sQ[6 * 8448];   // 50688 B
    __shared__ float sRed[2][8];
    __shared__ float sc[64];

    const int y0 = strip * 4;
    const char* img = (const char*)qin + (size_t)b * 8 * HW * 16;

    if (tid < 64) sc[tid] = coef[b * 64 + tid];
    // zero halo slots 0 and 65
    if (tid < 96) {
        int pb_ = tid >> 3, sub = tid & 7;
        int r = pb_ >> 1, side = pb_ & 1;
        uint4 z; z.x = z.y = z.z = z.w = 0;
        *(uint4*)(sQ + r * 8448 + side * 8320 + sub * 16) = z;
    }
    __syncthreads();

    // staging: lane -> pixel px, wave+k -> sub-block s
    const int px = tid & 63;
    const int rot = px & 7;
    char* dstp = sQ + 128 + px * 128;
#pragma unroll
    for (int r = 0; r < 6; ++r) {
        int gy = y0 - 1 + r;
        int gp = gy * 64 + px;
        char* dst = dstp + r * 8448;
#pragma unroll
        for (int k = 0; k < 2; ++k) {
            int s = k * 2 + wv;
            uint4 oh, ol;
            if (gy >= 0 && gy < 64) {
                uint4 uhv = *(const uint4*)(img + ((size_t)(s * HW) + gp) * 16);
                uint4 ulv = *(const uint4*)(img + ((size_t)((s + 4) * HW) + gp) * 16);
                unsigned int hd[4] = {uhv.x, uhv.y, uhv.z, uhv.w};
                unsigned int ld[4] = {ulv.x, ulv.y, ulv.z, ulv.w};
                unsigned int ho[4], lo_[4];
#pragma unroll
                for (int e = 0; e < 4; ++e) {
                    int c0 = s * 8 + e * 2;
                    float x0 = bf2f((unsigned short)(hd[e] & 0xFFFF)) + bf2f((unsigned short)(ld[e] & 0xFFFF));
                    float x1 = bf2f((unsigned short)(hd[e] >> 16)) + bf2f((unsigned short)(ld[e] >> 16));
                    float y0v = gelu_f(fmaf(sc[c0 * 2], x0, sc[c0 * 2 + 1]));
                    float y1v = gelu_f(fmaf(sc[c0 * 2 + 2], x1, sc[c0 * 2 + 3]));
                    unsigned short h0 = f2bf(y0v), h1 = f2bf(y1v);
                    unsigned short l0 = f2bf(y0v - bf2f(h0)), l1 = f2bf(y1v - bf2f(h1));
                    ho[e] = (unsigned)h0 | ((unsigned)h1 << 16);
                    lo_[e] = (unsigned)l0 | ((unsigned)l1 << 16);
                }
                oh.x = ho[0]; oh.y = ho[1]; oh.z = ho[2]; oh.w = ho[3];
                ol.x = lo_[0]; ol.y = lo_[1]; ol.z = lo_[2]; ol.w = lo_[3];
            } else {
                oh.x = oh.y = oh.z = oh.w = 0;
                ol.x = ol.y = ol.z = ol.w = 0;
            }
            *(uint4*)(dst + ((s + rot) & 7) * 16) = oh;
            *(uint4*)(dst + ((s + 4 + rot) & 7) * 16) = ol;
        }
    }
    __syncthreads();

    f32x16_t acc[4];
#pragma unroll
    for (int i = 0; i < 4; ++i)
#pragma unroll
        for (int j = 0; j < 16; ++j) acc[i][j] = 0.0f;

    for (int kx = 0; kx < 3; ++kx) {
        bf16x8_t Wf[3][2][2];  // [ky][kstep][hl]
#pragma unroll
        for (int ky = 0; ky < 3; ++ky)
#pragma unroll
            for (int k2 = 0; k2 < 2; ++k2)
#pragma unroll
                for (int hl = 0; hl < 2; ++hl) {
                    int fi = ((ky * 3 + kx) * 2 + k2) * 2 + hl;
                    Wf[ky][k2][hl] = __builtin_bit_cast(
                        bf16x8_t, *(const uint4*)(wq + (size_t)fi * 512 + lane * 8));
                }
        const int slotb = xh32 + kx + m;
        const int mrot = (m + kx + 7) & 7;
#pragma unroll
        for (int li = 0; li < 6; ++li) {
            const char* rowp = sQ + li * 8448 + slotb * 128;
            bf16x8_t Ah[2], Al[2];
#pragma unroll
            for (int k2 = 0; k2 < 2; ++k2) {
                int sh = k2 * 2 + hf;
                Ah[k2] = __builtin_bit_cast(bf16x8_t, *(const uint4*)(rowp + ((sh + mrot) & 7) * 16));
                Al[k2] = __builtin_bit_cast(bf16x8_t, *(const uint4*)(rowp + ((sh + 4 + mrot) & 7) * 16));
            }
#pragma unroll
            for (int ky = 0; ky < 3; ++ky) {
                int orow = li - ky;
                if (orow < 0 || orow > 3) continue;
#pragma unroll
                for (int k2 = 0; k2 < 2; ++k2) {
                    acc[orow] = __builtin_amdgcn_mfma_f32_32x32x16_bf16(Ah[k2], Wf[ky][k2][0], acc[orow], 0, 0, 0);
                    acc[orow] = __builtin_amdgcn_mfma_f32_32x32x16_bf16(Ah[k2], Wf[ky][k2][1], acc[orow], 0, 0, 0);
                    acc[orow] = __builtin_amdgcn_mfma_f32_32x32x16_bf16(Al[k2], Wf[ky][k2][0], acc[orow], 0, 0, 0);
                }
            }
        }
    }

    // ---- epilogue: stats + LDS transpose (reuse sQ) + coalesced plane stores
    __syncthreads();
    unsigned int* lds_t = (unsigned int*)sQ;  // [256 px][34] u32
    const int co = lane & 31;
    float s1 = 0.0f, s2 = 0.0f;
#pragma unroll
    for (int orow = 0; orow < 4; ++orow) {
#pragma unroll
        for (int r = 0; r < 16; ++r) {
            int mm = (r & 3) + 8 * (r >> 2) + 4 * hf;
            int pxl = (orow << 6) + xh32 + mm;
            float v = acc[orow][r];
            s1 += v;
            s2 = fmaf(v, v, s2);
            unsigned short hv = f2bf(v);
            unsigned short lv = f2bf(v - bf2f(hv));
            lds_t[pxl * 34 + co] = (unsigned)hv | ((unsigned)lv << 16);
        }
    }
    s1 += __shfl_xor(s1, 32); s2 += __shfl_xor(s2, 32);
    s1 += __shfl_xor(s1, 1);  s2 += __shfl_xor(s2, 1);
    s1 += __shfl_xor(s1, 2);  s2 += __shfl_xor(s2, 2);
    s1 += __shfl_xor(s1, 4);  s2 += __shfl_xor(s2, 4);
    if (lane < 32 && (lane & 7) == 0) {
        sRed[wv][co >> 3] = s1;
        sRed[wv][4 + (co >> 3)] = s2;
    }
    __syncthreads();
    if (tid < 8) statp[((size_t)b * 16 + strip) * 8 + tid] = sRed[0][tid] + sRed[1][tid];

    char* qb = (char*)qout + (size_t)b * 8 * HW * 16;
    const int p0 = y0 * 64;
#pragma unroll
    for (int pi = 0; pi < 2; ++pi) {
        int p = pi * 128 + tid;          // 0..255
#pragma unroll
        for (int s = 0; s < 4; ++s) {
            unsigned int hw_[4], lw_[4];
#pragma unroll
            for (int j = 0; j < 4; ++j) {
                int c0 = s * 8 + j * 2;
                uint2 t2 = *(const uint2*)(lds_t + p * 34 + c0);
                hw_[j] = (t2.x & 0xFFFFu) | (t2.y << 16);
                lw_[j] = (t2.x >> 16) | (t2.y & 0xFFFF0000u);
            }
            uint4 uh; uh.x = hw_[0]; uh.y = hw_[1]; uh.z = hw_[2]; uh.w = hw_[3];
            uint4 ul; ul.x = lw_[0]; ul.y = lw_[1]; ul.z = lw_[2]; ul.w = lw_[3];
            *(uint4*)(qb + ((size_t)(s * HW) + p0 + p) * 16) = uh;
            *(uint4*)(qb + ((size_t)((s + 4) * HW) + p0 + p) * 16) = ul;
        }
    }
}

// ---------------------------------------------------------------------------
// Projection + l2norm + FUSED gauss-pool partials from planar Q (GN+GELU on
// read, coalesced plane loads).
// ---------------------------------------------------------------------------
__global__ __launch_bounds__(256) void proj_kernel(
    const unsigned short* __restrict__ q, const float* __restrict__ coef,
    const float* __restrict__ pw, unsigned short* __restrict__ outn,
    float* __restrict__ poolp, float* __restrict__ E, float* __restrict__ swp,
    const float* __restrict__ gauss) {
    int b = blockIdx.y, chunk = blockIdx.x, tid = threadIdx.x;
    int p = chunk * 256 + tid;
    __shared__ float sR[4];
    __shared__ float sc[64];
    __shared__ float red[32][257];
    if (tid < 64) sc[tid] = coef[b * 64 + tid];
    __syncthreads();
    float feat[32];
    {
        const char* qb = (const char*)q + (size_t)b * 8 * HW * 16;
#pragma unroll
        for (int s = 0; s < 4; ++s) {
            uint4 uh = *(const uint4*)(qb + ((size_t)(s * HW) + p) * 16);
            uint4 ul = *(const uint4*)(qb + ((size_t)((s + 4) * HW) + p) * 16);
            unsigned int hd[4] = {uh.x, uh.y, uh.z, uh.w};
            unsigned int ld[4] = {ul.x, ul.y, ul.z, ul.w};
#pragma unroll
            for (int e = 0; e < 4; ++e) {
                int c0 = s * 8 + e * 2;
                float x0 = bf2f((unsigned short)(hd[e] & 0xFFFF)) + bf2f((unsigned short)(ld[e] & 0xFFFF));
                float x1 = bf2f((unsigned short)(hd[e] >> 16)) + bf2f((unsigned short)(ld[e] >> 16));
                feat[c0] = gelu_f(fmaf(sc[c0 * 2], x0, sc[c0 * 2 + 1]));
                feat[c0 + 1] = gelu_f(fmaf(sc[(c0 + 1) * 2], x1, sc[(c0 + 1) * 2 + 1]));
            }
        }
    }
    float g = gauss[p];
#pragma unroll
    for (int c = 0; c < 32; ++c) red[c][tid] = feat[c] * g;

    float o[32];
#pragma unroll
    for (int oo = 0; oo < 32; ++oo) o[oo] = 0.0f;
    for (int c = 0; c < 32; ++c) {
        float f = feat[c];
#pragma unroll
        for (int oo = 0; oo < 32; ++oo) o[oo] = fmaf(pw[oo * 32 + c], f, o[oo]);
    }
    float nn = 0.0f;
#pragma unroll
    for (int oo = 0; oo < 32; ++oo) nn = fmaf(o[oo], o[oo], nn);
    float n = sqrtf(nn);
    float inv = 1.0f / fmaxf(n, 1e-6f);
    unsigned short* obp = outn + (size_t)b * 32 * HW + p;
#pragma unroll
    for (int oo = 0; oo < 32; ++oo) obp[(size_t)oo * HW] = f2bf(o[oo] * inv);

    __syncthreads();
    if (tid < 32) {
        float s = 0.0f;
#pragma unroll 8
        for (int i = 0; i < 256; ++i) s += red[tid][i];
        poolp[((size_t)b * 16 + chunk) * 32 + tid] = s;
    }

    if (E != nullptr) {
        float e = nn * inv * inv;
        E[(size_t)b * HW + p] = e;
        float wvv = e * g;
#pragma unroll
        for (int off = 32; off > 0; off >>= 1) wvv += __shfl_down(wvv, off);
        if ((tid & 63) == 0) sR[tid >> 6] = wvv;
        __syncthreads();
        if (tid == 0) swp[b * 16 + chunk] = sR[0] + sR[1] + sR[2] + sR[3];
    }
}

// ---------------------------------------------------------------------------
// E <- E * gauss * scale / (sum_p(E*gauss) + 1e-8)
// ---------------------------------------------------------------------------
__global__ __launch_bounds__(256) void swapply_kernel(
    float* __restrict__ E, const float* __restrict__ swp,
    const float* __restrict__ gauss) {
    int b = blockIdx.y, p = blockIdx.x * 256 + threadIdx.x;
    float s = 0.0f;
#pragma unroll
    for (int i = 0; i < 16; ++i) s += swp[b * 16 + i];
    const float scale = 0.17677669529663688f;
    E[(size_t)b * HW + p] = E[(size_t)b * HW + p] * gauss[p] * scale / (s + 1e-8f);
}

// ---------------------------------------------------------------------------
// 49-offset correlation logits, channel-split: grid (bc, 8).
// ---------------------------------------------------------------------------
__global__ __launch_bounds__(256) void logits_kernel(
    const unsigned short* __restrict__ rn, const unsigned short* __restrict__ vn,
    const float* __restrict__ sw, float* __restrict__ lgpart) {
    int b = blockIdx.x, cg = blockIdx.y, tid = threadIdx.x;
    __shared__ float P[38][76];
    __shared__ float sR[4][49];
    float acc[49];
#pragma unroll
    for (int k = 0; k < 49; ++k) acc[k] = 0.0f;
    const float* swb = sw + (size_t)b * HW;
#pragma unroll 1
    for (int cc = 0; cc < 4; ++cc) {
        int c = cg * 4 + cc;
        const unsigned short* vb = vn + ((size_t)b * 32 + c) * HW;
        const unsigned short* rb = rn + ((size_t)b * 32 + c) * HW;
#pragma unroll 1
        for (int half = 0; half < 2; ++half) {
            const int base = half * 32;
            __syncthreads();
            for (int idx = tid; idx < 38 * 72; idx += 256) {
                int r = idx / 72, j = idx - r * 72;
                int gy = base - 3 + r;
                gy = gy < 0 ? 0 : (gy > 63 ? 63 : gy);
                int gx = j - 4;
                gx = gx < 0 ? 0 : (gx > 63 ? 63 : gx);
                P[r][j] = bf2f(vb[gy * 64 + gx]);
            }
            __syncthreads();
            int y = tid >> 3, x0 = (tid & 7) * 8;
            int pbase = (base + y) * 64 + x0;
            uint4 rv = *(const uint4*)(rb + pbase);
            float4 q0 = *(const float4*)(swb + pbase);
            float4 q1 = *(const float4*)(swb + pbase + 4);
            unsigned int rd[4] = {rv.x, rv.y, rv.z, rv.w};
            float r_[8];
            r_[0] = bf2f((unsigned short)(rd[0] & 0xFFFF)) * q0.x;
            r_[1] = bf2f((unsigned short)(rd[0] >> 16)) * q0.y;
            r_[2] = bf2f((unsigned short)(rd[1] & 0xFFFF)) * q0.z;
            r_[3] = bf2f((unsigned short)(rd[1] >> 16)) * q0.w;
            r_[4] = bf2f((unsigned short)(rd[2] & 0xFFFF)) * q1.x;
            r_[5] = bf2f((unsigned short)(rd[2] >> 16)) * q1.y;
            r_[6] = bf2f((unsigned short)(rd[3] & 0xFFFF)) * q1.z;
            r_[7] = bf2f((unsigned short)(rd[3] >> 16)) * q1.w;
#pragma unroll
            for (int dy = 0; dy < 7; ++dy) {
                const float4* Pr = (const float4*)(&P[y + dy][x0]);
                float4 a0 = Pr[0], a1 = Pr[1], a2 = Pr[2], a3 = Pr[3];
                float v[16] = {a0.x, a0.y, a0.z, a0.w, a1.x, a1.y, a1.z, a1.w,
                               a2.x, a2.y, a2.z, a2.w, a3.x, a3.y, a3.z, a3.w};
#pragma unroll
                for (int dx = 0; dx < 7; ++dx) {
#pragma unroll
                    for (int j = 0; j < 8; ++j)
                        acc[dy * 7 + dx] = fmaf(r_[j], v[j + dx + 1], acc[dy * 7 + dx]);
                }
            }
        }
    }
#pragma unroll
    for (int k = 0; k < 49; ++k) {
#pragma unroll
        for (int off = 32; off > 0; off >>= 1) acc[k] += __shfl_down(acc[k], off);
    }
    int wid = tid >> 6;
    __syncthreads();
    if ((tid & 63) == 0) {
#pragma unroll
        for (int k = 0; k < 49; ++k) sR[wid][k] = acc[k];
    }
    __syncthreads();
    if (tid < 49)
        lgpart[((size_t)b * 8 + cg) * 49 + tid] =
            sR[0][tid] + sR[1][tid] + sR[2][tid] + sR[3][tid];
}

// ---------------------------------------------------------------------------
// Softmax/coarse + MLP head + output assembly. Reduces logit & pool partials.
// ---------------------------------------------------------------------------
__global__ __launch_bounds__(128) void head_kernel(
    const float* __restrict__ lg, const float* __restrict__ rpp,
    const float* __restrict__ vpp, const float* __restrict__ p2s,
    const float* __restrict__ log_temp,
    const float* __restrict__ W1, const float* __restrict__ b1,
    const float* __restrict__ W2, const float* __restrict__ b2,
    const float* __restrict__ W3, const float* __restrict__ b3,
    float* __restrict__ out) {
    int b = blockIdx.x, t = threadIdx.x;
    __shared__ float slg[49];
    __shared__ float pooled[98];
    __shared__ float h1[128], h2[128];
    __shared__ float cxy[2];
    __shared__ float res[3];
    const float* lgp = lg + (size_t)b * 8 * 49;
    if (t < 49) {
        float s = 0.0f;
#pragma unroll
        for (int g = 0; g < 8; ++g) s += lgp[g * 49 + t];
        slg[t] = s;
    }
    __syncthreads();
    if (t == 0) {
        float temp = fmaxf(expf(log_temp[0]), 0.001f);
        float invT = 1.0f / temp;
        float m = -1e30f;
        for (int k = 0; k < 49; ++k) m = fmaxf(m, slg[k] * invT);
        float s = 0.0f, pdx = 0.0f, pdy = 0.0f;
        for (int k = 0; k < 49; ++k) {
            float e = expf(slg[k] * invT - m);
            s += e;
            pdx += e * (float)((k % 7) - 3);
            pdy += e * (float)((k / 7) - 3);
        }
        cxy[0] = pdx / s;
        cxy[1] = pdy / s;
    }
    __syncthreads();
    if (t < 32) {
        float a = 0.0f, c = 0.0f;
#pragma unroll
        for (int k = 0; k < 16; ++k) {
            a += rpp[((size_t)b * 16 + k) * 32 + t];
            c += vpp[((size_t)b * 16 + k) * 32 + t];
        }
        pooled[t] = a;
        pooled[32 + t] = c;
        pooled[64 + t] = a - c;
    }
    if (t == 0) {
        pooled[96] = cxy[0];
        pooled[97] = cxy[1];
    }
    __syncthreads();
    float s1 = b1[t];
    for (int i = 0; i < 98; ++i) s1 = fmaf(pooled[i], W1[i * 128 + t], s1);
    h1[t] = gelu_f(s1);
    __syncthreads();
    float s2 = b2[t];
    for (int i = 0; i < 128; ++i) s2 = fmaf(h1[i], W2[i * 128 + t], s2);
    h2[t] = gelu_f(s2);
    __syncthreads();
    if (t < 3) {
        float r = b3[t];
        for (int i = 0; i < 128; ++i) r = fmaf(h2[i], W3[i * 3 + t], r);
        res[t] = r;
    }
    __syncthreads();
    if (t == 0) {
        float dxp = cxy[0] + res[0];
        float dyp = cxy[1] + res[1];
        float ls = fminf(fmaxf(res[2], -6.0f), 3.0f);
        const float* M = p2s + b * 4;
        float* ob = out + b * 54;
        ob[0] = dxp;
        ob[1] = dyp;
        ob[2] = M[0] * dxp + M[1] * dyp;
        ob[3] = M[2] * dxp + M[3] * dyp;
        ob[4] = ls;
    }
    if (t < 49) out[b * 54 + 5 + t] = slg[t];
}

extern "C" void kernel_launch(void* const* d_in, const int* in_sizes, int n_in,
                              void* d_out, int out_size, void* d_ws, size_t ws_size,
                              hipStream_t stream) {
    (void)in_sizes; (void)n_in; (void)out_size;
    const float* rubin = (const float*)d_in[0];
    const float* vis   = (const float*)d_in[1];
    const float* p2s   = (const float*)d_in[2];
    const float* rW0   = (const float*)d_in[3];
    const float* rWs   = (const float*)d_in[4];
    const float* rG    = (const float*)d_in[5];
    const float* rBt   = (const float*)d_in[6];
    const float* vW0   = (const float*)d_in[7];
    const float* vWs   = (const float*)d_in[8];
    const float* vG    = (const float*)d_in[9];
    const float* vBt   = (const float*)d_in[10];
    const float* projR = (const float*)d_in[11];
    const float* projV = (const float*)d_in[12];
    const float* logT  = (const float*)d_in[13];
    const float* W1    = (const float*)d_in[14];
    const float* b1    = (const float*)d_in[15];
    const float* W2    = (const float*)d_in[16];
    const float* b2    = (const float*)d_in[17];
    const float* W3    = (const float*)d_in[18];
    const float* b3    = (const float*)d_in[19];
    float* out = (float*)d_out;

    // ---- workspace layout (bytes)
    char* ws = (char*)d_ws;
    size_t off = 0;
    unsigned short* vnB = (unsigned short*)(ws + off); off += (size_t)NB * 32 * HW * 2;  // 67.1 MB
    float* gauss  = (float*)(ws + off); off += HW * 4;
    float* statp  = (float*)(ws + off); off += (size_t)NB * 16 * 8 * 4;
    float* coefS  = (float*)(ws + off); off += (size_t)NB * 64 * 4;
    float* swp    = (float*)(ws + off); off += (size_t)NB * 16 * 4;
    float* rpp    = (float*)(ws + off); off += (size_t)NB * 16 * 32 * 4;
    float* vpp    = (float*)(ws + off); off += (size_t)NB * 16 * 32 * 4;
    float* lgbuf  = (float*)(ws + off); off += (size_t)NB * 8 * 49 * 4;
    unsigned short* wq = (unsigned short*)(ws + off); off += 110592ull * 2;
    off = (off + 255) & ~(size_t)255;
    const size_t fixed_bytes = off;
    const size_t perb = 2ull * HW * 128 + HW * 4;  // Q1+Q2 planar blocks + E
    int BC = 1;
    if (ws_size > fixed_bytes + perb) {
        size_t t = (ws_size - fixed_bytes) / perb;
        BC = t > (size_t)NB ? NB : (int)t;
    }
    unsigned short* Q1 = (unsigned short*)(ws + off);
    unsigned short* Q2 = (unsigned short*)(ws + off + (size_t)BC * HW * 128);
    float* E = (float*)(ws + off + 2ull * BC * HW * 128);

    dim3 blk256(256), blk128(128);
    gauss_kernel<<<1, 256, 0, stream>>>(gauss);
    prep_w_kernel<<<432, 256, 0, stream>>>(rWs, vWs, wq);

    // ================= VIS encoder (all chunks) =================
    for (int b0 = 0; b0 < NB; b0 += BC) {
        const int bc = (NB - b0) < BC ? (NB - b0) : BC;
        dim3 cg16(16, bc);
        const int gnblk = (bc * 32 + 255) / 256;
        float* sp = statp + (size_t)b0 * 128;
        float* cS = coefS + (size_t)b0 * 64;

        conv_first_kernel<1><<<cg16, blk256, 0, stream>>>(vis + (size_t)b0 * HW, vW0, Q1, sp);
        gn_finalize_kernel<<<gnblk, 256, 0, stream>>>(sp, vG + 0, vBt + 0, cS, bc * 32);
        convm_kernel<<<cg16, blk128, 0, stream>>>(Q1, cS, wq + 3 * 18432, Q2, sp);
        gn_finalize_kernel<<<gnblk, 256, 0, stream>>>(sp, vG + 32, vBt + 32, cS, bc * 32);
        convm_kernel<<<cg16, blk128, 0, stream>>>(Q2, cS, wq + 4 * 18432, Q1, sp);
        gn_finalize_kernel<<<gnblk, 256, 0, stream>>>(sp, vG + 64, vBt + 64, cS, bc * 32);
        convm_kernel<<<cg16, blk128, 0, stream>>>(Q1, cS, wq + 5 * 18432, Q2, sp);
        gn_finalize_kernel<<<gnblk, 256, 0, stream>>>(sp, vG + 96, vBt + 96, cS, bc * 32);
        proj_kernel<<<cg16, blk256, 0, stream>>>(Q2, cS, projV, vnB + (size_t)b0 * 32 * HW,
                                                 vpp + (size_t)b0 * 512,
                                                 (float*)nullptr, (float*)nullptr, gauss);
    }

    // ================= RUBIN encoder + logits (all chunks) =================
    for (int b0 = 0; b0 < NB; b0 += BC) {
        const int bc = (NB - b0) < BC ? (NB - b0) : BC;
        dim3 cg16(16, bc);
        const int gnblk = (bc * 32 + 255) / 256;
        float* sp = statp + (size_t)b0 * 128;
        float* cS = coefS + (size_t)b0 * 64;
        float* sw = swp + (size_t)b0 * 16;
        unsigned short* rnB = Q1;  // dead after last convm reads it

        conv_first_kernel<6><<<cg16, blk256, 0, stream>>>(rubin + (size_t)b0 * 6 * HW, rW0, Q1, sp);
        gn_finalize_kernel<<<gnblk, 256, 0, stream>>>(sp, rG + 0, rBt + 0, cS, bc * 32);
        convm_kernel<<<cg16, blk128, 0, stream>>>(Q1, cS, wq + 0 * 18432, Q2, sp);
        gn_finalize_kernel<<<gnblk, 256, 0, stream>>>(sp, rG + 32, rBt + 32, cS, bc * 32);
        convm_kernel<<<cg16, blk128, 0, stream>>>(Q2, cS, wq + 1 * 18432, Q1, sp);
        gn_finalize_kernel<<<gnblk, 256, 0, stream>>>(sp, rG + 64, rBt + 64, cS, bc * 32);
        convm_kernel<<<cg16, blk128, 0, stream>>>(Q1, cS, wq + 2 * 18432, Q2, sp);
        gn_finalize_kernel<<<gnblk, 256, 0, stream>>>(sp, rG + 96, rBt + 96, cS, bc * 32);
        proj_kernel<<<cg16, blk256, 0, stream>>>(Q2, cS, projR, rnB,
                                                 rpp + (size_t)b0 * 512, E, sw, gauss);
        swapply_kernel<<<cg16, blk256, 0, stream>>>(E, sw, gauss);
        logits_kernel<<<dim3(bc, 8), blk256, 0, stream>>>(rnB, vnB + (size_t)b0 * 32 * HW, E,
                                                          lgbuf + (size_t)b0 * 8 * 49);
    }

    head_kernel<<<NB, 128, 0, stream>>>(lgbuf, rpp, vpp, p2s, logT, W1, b1, W2, b2, W3, b3, out);
}

// Round 10
// 1532.479 us; speedup vs baseline: 1.5948x; 1.1759x over previous
//
#include <hip/hip_runtime.h>
#include <math.h>

#define HW 4096
#define NB 256

typedef __attribute__((ext_vector_type(8))) short bf16x8_t;
typedef __attribute__((ext_vector_type(16))) float f32x16_t;

// Fast erf-based GELU: Abramowitz-Stegun 7.1.26, |err(erf)| <= 1.5e-7 —
// ~50x below the split-bf16 quantization noise (2^-17). ~15 VALU ops vs
// ~60-80 for libm erff (branchy multi-path under exec masks).
__device__ __forceinline__ float gelu_f(float x) {
    float z = x * 0.70710678118654752440f;
    float az = fabsf(z);
    float t = 1.0f / fmaf(0.3275911f, az, 1.0f);
    float p = t * fmaf(t, fmaf(t, fmaf(t, fmaf(t, 1.061405429f, -1.453152027f),
                                       1.421413741f), -0.284496736f), 0.254829592f);
    float e = __expf(-az * az);
    float er = 1.0f - p * e;
    er = copysignf(er, z);
    return 0.5f * x * (1.0f + er);
}
__device__ __forceinline__ unsigned short f2bf(float f) {
    unsigned int u = __float_as_uint(f);
    unsigned int r = u + 0x7FFFu + ((u >> 16) & 1u);
    return (unsigned short)(r >> 16);
}
__device__ __forceinline__ float bf2f(unsigned short h) {
    return __uint_as_float(((unsigned int)h) << 16);
}

// Q layout (PLANAR): Q[b][s][p], s=0..7 (0-3 = H sub-blocks of ci-group s,
// 4-7 = L), p = pixel 0..4095, 16 B each — all global Q accesses coalesced.
// vis l2n planes are edge-PADDED: vn[b][c][64][72] bf16, col j <-> gx=clamp(j-4,0,63).

// ---------------------------------------------------------------------------
// Gaussian center window
// ---------------------------------------------------------------------------
__global__ __launch_bounds__(256) void gauss_kernel(float* __restrict__ gauss) {
    __shared__ float sg[HW];
    __shared__ float sR[4];
    int tid = threadIdx.x;
    float part = 0.0f;
    for (int p = tid; p < HW; p += 256) {
        int y = p >> 6, x = p & 63;
        float yy = -1.0f + (2.0f / 63.0f) * (float)y;
        float xx = -1.0f + (2.0f / 63.0f) * (float)x;
        float g = expf(-(yy * yy + xx * xx) * 2.0f);
        sg[p] = g;
        part += g;
    }
#pragma unroll
    for (int off = 32; off > 0; off >>= 1) part += __shfl_down(part, off);
    if ((tid & 63) == 0) sR[tid >> 6] = part;
    __syncthreads();
    float invt = 1.0f / (sR[0] + sR[1] + sR[2] + sR[3]);
    for (int p = tid; p < HW; p += 256) gauss[p] = sg[p] * invt;
}

// ---------------------------------------------------------------------------
// Pack conv weights (fp32 OIHW) into MFMA B-fragment order, split bf16 hi/lo.
// ---------------------------------------------------------------------------
__global__ __launch_bounds__(256) void prep_w_kernel(
    const float* __restrict__ rWs, const float* __restrict__ vWs,
    unsigned short* __restrict__ wq) {
    int i = blockIdx.x * 256 + threadIdx.x;
    if (i >= 110592) return;
    int j = i & 7;
    int lane = (i >> 3) & 63;
    int f = i >> 9;
    int hl = f & 1, k2 = (f >> 1) & 1, tap = (f >> 2) % 9, layer = (f >> 2) / 9;
    int co = lane & 31, hf = lane >> 5;
    int ci = k2 * 16 + hf * 8 + j;
    int ky = tap / 3, kx = tap % 3;
    float wv = (layer < 3)
        ? rWs[(((size_t)layer * 32 + co) * 32 + ci) * 9 + ky * 3 + kx]
        : vWs[(((size_t)(layer - 3) * 32 + co) * 32 + ci) * 9 + ky * 3 + kx];
    unsigned short h = f2bf(wv);
    unsigned short l = f2bf(wv - bf2f(h));
    wq[i] = hl ? l : h;
}

// ---------------------------------------------------------------------------
// First conv layer (CIN=6 rubin / CIN=1 vis), fp32 VALU. Writes RAW planar Q.
// ---------------------------------------------------------------------------
template <int CIN>
__global__ __launch_bounds__(256) void conv_first_kernel(
    const float* __restrict__ in, const float* __restrict__ w,
    unsigned short* __restrict__ qout, float* __restrict__ statp) {
    const int b = blockIdx.y;
    const int strip = blockIdx.x;
    const int tid = threadIdx.x;
    const int x = tid & 63;
    const int wid = tid >> 6;

    __shared__ float sIn[CIN][6][66];
    __shared__ float sRed[4][8];

    const float* inb = in + (size_t)b * CIN * HW;
    for (int idx = tid; idx < CIN * 6 * 66; idx += 256) {
        int ci = idx / (6 * 66);
        int rem = idx - ci * (6 * 66);
        int r = rem / 66;
        int p = rem - r * 66;
        int gy = strip * 4 - 1 + r;
        int gx = p - 1;
        float v = 0.0f;
        if (gy >= 0 && gy < 64 && gx >= 0 && gx < 64) v = inb[ci * HW + gy * 64 + gx];
        sIn[ci][r][p] = v;
    }
    __syncthreads();

    float acc[32];
#pragma unroll
    for (int co = 0; co < 32; ++co) acc[co] = 0.0f;

    for (int ci = 0; ci < CIN; ++ci) {
        float vv[9];
#pragma unroll
        for (int ky = 0; ky < 3; ++ky)
#pragma unroll
            for (int kx = 0; kx < 3; ++kx) vv[ky * 3 + kx] = sIn[ci][wid + ky][x + kx];
#pragma unroll
        for (int co = 0; co < 32; ++co) {
            const float* wk = w + ((size_t)co * CIN + ci) * 9;
            float s = acc[co];
#pragma unroll
            for (int k = 0; k < 9; ++k) s = fmaf(wk[k], vv[k], s);
            acc[co] = s;
        }
    }

    const int gy = strip * 4 + wid;
    {
        int gp = gy * 64 + x;
        char* qb = (char*)qout + (size_t)b * 8 * HW * 16;
#pragma unroll
        for (int s = 0; s < 4; ++s) {
            unsigned int hw_[4], lw_[4];
#pragma unroll
            for (int e = 0; e < 4; ++e) {
                int c = s * 8 + e * 2;
                unsigned short h0 = f2bf(acc[c]);
                float r0 = acc[c] - bf2f(h0);
                unsigned short h1 = f2bf(acc[c + 1]);
                float r1 = acc[c + 1] - bf2f(h1);
                hw_[e] = (unsigned)h0 | ((unsigned)h1 << 16);
                lw_[e] = (unsigned)f2bf(r0) | ((unsigned)f2bf(r1) << 16);
            }
            uint4 uh; uh.x = hw_[0]; uh.y = hw_[1]; uh.z = hw_[2]; uh.w = hw_[3];
            uint4 ul; ul.x = lw_[0]; ul.y = lw_[1]; ul.z = lw_[2]; ul.w = lw_[3];
            *(uint4*)(qb + ((size_t)(s * HW) + gp) * 16) = uh;
            *(uint4*)(qb + ((size_t)((s + 4) * HW) + gp) * 16) = ul;
        }
    }
    float s1[4] = {0, 0, 0, 0}, s2[4] = {0, 0, 0, 0};
#pragma unroll
    for (int co = 0; co < 32; ++co) {
        float v = acc[co];
        s1[co >> 3] += v;
        s2[co >> 3] = fmaf(v, v, s2[co >> 3]);
    }
#pragma unroll
    for (int off = 32; off > 0; off >>= 1) {
#pragma unroll
        for (int g = 0; g < 4; ++g) {
            s1[g] += __shfl_down(s1[g], off);
            s2[g] += __shfl_down(s2[g], off);
        }
    }
    if ((tid & 63) == 0) {
#pragma unroll
        for (int g = 0; g < 4; ++g) {
            sRed[wid][g] = s1[g];
            sRed[wid][4 + g] = s2[g];
        }
    }
    __syncthreads();
    if (tid < 8) {
        float t = sRed[0][tid] + sRed[1][tid] + sRed[2][tid] + sRed[3][tid];
        statp[((size_t)b * 16 + strip) * 8 + tid] = t;
    }
}

// ---------------------------------------------------------------------------
// GN finalize: per-strip stats -> per-(b,c) affine coefs  y = a*x + b
// ---------------------------------------------------------------------------
__global__ __launch_bounds__(256) void gn_finalize_kernel(
    const float* __restrict__ statp, const float* __restrict__ gma,
    const float* __restrict__ bta, float* __restrict__ coef, int n) {
    int i = blockIdx.x * 256 + threadIdx.x;
    if (i >= n) return;
    int b = i >> 5, c = i & 31, g = c >> 3;
    float s1 = 0.0f, s2 = 0.0f;
    for (int s = 0; s < 16; ++s) {
        s1 += statp[((size_t)b * 16 + s) * 8 + g];
        s2 += statp[((size_t)b * 16 + s) * 8 + 4 + g];
    }
    const float invN = 1.0f / 32768.0f;
    float mean = s1 * invN;
    float var = s2 * invN - mean * mean;
    float rstd = rsqrtf(var + 1e-5f);
    float a = rstd * gma[c];
    float bb = bta[c] - mean * a;
    coef[i * 2 + 0] = a;
    coef[i * 2 + 1] = bb;
}

// ---------------------------------------------------------------------------
// MFMA 3x3 conv with FUSED input GN+GELU, CIN=COUT=32, split-bf16 3-term.
// Planar-Q global reads; swizzled pixel-block LDS; fast-erf gelu in staging.
// ---------------------------------------------------------------------------
__global__ __launch_bounds__(128) void convm_kernel(
    const unsigned short* __restrict__ qin, const float* __restrict__ coef,
    const unsigned short* __restrict__ wq,
    unsigned short* __restrict__ qout, float* __restrict__ statp) {
    const int b = blockIdx.y;
    const int strip = blockIdx.x;
    const int tid = threadIdx.x;
    const int wv = tid >> 6;
    const int lane = tid & 63;
    const int m = lane & 31;
    const int hf = lane >> 5;
    const int xh32 = wv * 32;

    __shared__ __align__(16) char sQ[6 * 8448];   // 50688 B
    __shared__ float sRed[2][8];
    __shared__ float sc[64];

    const int y0 = strip * 4;
    const char* img = (const char*)qin + (size_t)b * 8 * HW * 16;

    if (tid < 64) sc[tid] = coef[b * 64 + tid];
    if (tid < 96) {
        int pb_ = tid >> 3, sub = tid & 7;
        int r = pb_ >> 1, side = pb_ & 1;
        uint4 z; z.x = z.y = z.z = z.w = 0;
        *(uint4*)(sQ + r * 8448 + side * 8320 + sub * 16) = z;
    }
    __syncthreads();

    const int px = tid & 63;
    const int rot = px & 7;
    char* dstp = sQ + 128 + px * 128;
#pragma unroll
    for (int r = 0; r < 6; ++r) {
        int gy = y0 - 1 + r;
        int gp = gy * 64 + px;
        char* dst = dstp + r * 8448;
#pragma unroll
        for (int k = 0; k < 2; ++k) {
            int s = k * 2 + wv;
            uint4 oh, ol;
            if (gy >= 0 && gy < 64) {
                uint4 uhv = *(const uint4*)(img + ((size_t)(s * HW) + gp) * 16);
                uint4 ulv = *(const uint4*)(img + ((size_t)((s + 4) * HW) + gp) * 16);
                unsigned int hd[4] = {uhv.x, uhv.y, uhv.z, uhv.w};
                unsigned int ld[4] = {ulv.x, ulv.y, ulv.z, ulv.w};
                unsigned int ho[4], lo_[4];
#pragma unroll
                for (int e = 0; e < 4; ++e) {
                    int c0 = s * 8 + e * 2;
                    float x0 = bf2f((unsigned short)(hd[e] & 0xFFFF)) + bf2f((unsigned short)(ld[e] & 0xFFFF));
                    float x1 = bf2f((unsigned short)(hd[e] >> 16)) + bf2f((unsigned short)(ld[e] >> 16));
                    float y0v = gelu_f(fmaf(sc[c0 * 2], x0, sc[c0 * 2 + 1]));
                    float y1v = gelu_f(fmaf(sc[c0 * 2 + 2], x1, sc[c0 * 2 + 3]));
                    unsigned short h0 = f2bf(y0v), h1 = f2bf(y1v);
                    unsigned short l0 = f2bf(y0v - bf2f(h0)), l1 = f2bf(y1v - bf2f(h1));
                    ho[e] = (unsigned)h0 | ((unsigned)h1 << 16);
                    lo_[e] = (unsigned)l0 | ((unsigned)l1 << 16);
                }
                oh.x = ho[0]; oh.y = ho[1]; oh.z = ho[2]; oh.w = ho[3];
                ol.x = lo_[0]; ol.y = lo_[1]; ol.z = lo_[2]; ol.w = lo_[3];
            } else {
                oh.x = oh.y = oh.z = oh.w = 0;
                ol.x = ol.y = ol.z = ol.w = 0;
            }
            *(uint4*)(dst + ((s + rot) & 7) * 16) = oh;
            *(uint4*)(dst + ((s + 4 + rot) & 7) * 16) = ol;
        }
    }
    __syncthreads();

    f32x16_t acc[4];
#pragma unroll
    for (int i = 0; i < 4; ++i)
#pragma unroll
        for (int j = 0; j < 16; ++j) acc[i][j] = 0.0f;

    for (int kx = 0; kx < 3; ++kx) {
        bf16x8_t Wf[3][2][2];  // [ky][kstep][hl]
#pragma unroll
        for (int ky = 0; ky < 3; ++ky)
#pragma unroll
            for (int k2 = 0; k2 < 2; ++k2)
#pragma unroll
                for (int hl = 0; hl < 2; ++hl) {
                    int fi = ((ky * 3 + kx) * 2 + k2) * 2 + hl;
                    Wf[ky][k2][hl] = __builtin_bit_cast(
                        bf16x8_t, *(const uint4*)(wq + (size_t)fi * 512 + lane * 8));
                }
        const int slotb = xh32 + kx + m;
        const int mrot = (m + kx + 7) & 7;
#pragma unroll
        for (int li = 0; li < 6; ++li) {
            const char* rowp = sQ + li * 8448 + slotb * 128;
            bf16x8_t Ah[2], Al[2];
#pragma unroll
            for (int k2 = 0; k2 < 2; ++k2) {
                int sh = k2 * 2 + hf;
                Ah[k2] = __builtin_bit_cast(bf16x8_t, *(const uint4*)(rowp + ((sh + mrot) & 7) * 16));
                Al[k2] = __builtin_bit_cast(bf16x8_t, *(const uint4*)(rowp + ((sh + 4 + mrot) & 7) * 16));
            }
#pragma unroll
            for (int ky = 0; ky < 3; ++ky) {
                int orow = li - ky;
                if (orow < 0 || orow > 3) continue;
#pragma unroll
                for (int k2 = 0; k2 < 2; ++k2) {
                    acc[orow] = __builtin_amdgcn_mfma_f32_32x32x16_bf16(Ah[k2], Wf[ky][k2][0], acc[orow], 0, 0, 0);
                    acc[orow] = __builtin_amdgcn_mfma_f32_32x32x16_bf16(Ah[k2], Wf[ky][k2][1], acc[orow], 0, 0, 0);
                    acc[orow] = __builtin_amdgcn_mfma_f32_32x32x16_bf16(Al[k2], Wf[ky][k2][0], acc[orow], 0, 0, 0);
                }
            }
        }
    }

    __syncthreads();
    unsigned int* lds_t = (unsigned int*)sQ;  // [256 px][34] u32
    const int co = lane & 31;
    float s1 = 0.0f, s2 = 0.0f;
#pragma unroll
    for (int orow = 0; orow < 4; ++orow) {
#pragma unroll
        for (int r = 0; r < 16; ++r) {
            int mm = (r & 3) + 8 * (r >> 2) + 4 * hf;
            int pxl = (orow << 6) + xh32 + mm;
            float v = acc[orow][r];
            s1 += v;
            s2 = fmaf(v, v, s2);
            unsigned short hv = f2bf(v);
            unsigned short lv = f2bf(v - bf2f(hv));
            lds_t[pxl * 34 + co] = (unsigned)hv | ((unsigned)lv << 16);
        }
    }
    s1 += __shfl_xor(s1, 32); s2 += __shfl_xor(s2, 32);
    s1 += __shfl_xor(s1, 1);  s2 += __shfl_xor(s2, 1);
    s1 += __shfl_xor(s1, 2);  s2 += __shfl_xor(s2, 2);
    s1 += __shfl_xor(s1, 4);  s2 += __shfl_xor(s2, 4);
    if (lane < 32 && (lane & 7) == 0) {
        sRed[wv][co >> 3] = s1;
        sRed[wv][4 + (co >> 3)] = s2;
    }
    __syncthreads();
    if (tid < 8) statp[((size_t)b * 16 + strip) * 8 + tid] = sRed[0][tid] + sRed[1][tid];

    char* qb = (char*)qout + (size_t)b * 8 * HW * 16;
    const int p0 = y0 * 64;
#pragma unroll
    for (int pi = 0; pi < 2; ++pi) {
        int p = pi * 128 + tid;          // 0..255
#pragma unroll
        for (int s = 0; s < 4; ++s) {
            unsigned int hw_[4], lw_[4];
#pragma unroll
            for (int j = 0; j < 4; ++j) {
                int c0 = s * 8 + j * 2;
                uint2 t2 = *(const uint2*)(lds_t + p * 34 + c0);
                hw_[j] = (t2.x & 0xFFFFu) | (t2.y << 16);
                lw_[j] = (t2.x >> 16) | (t2.y & 0xFFFF0000u);
            }
            uint4 uh; uh.x = hw_[0]; uh.y = hw_[1]; uh.z = hw_[2]; uh.w = hw_[3];
            uint4 ul; ul.x = lw_[0]; ul.y = lw_[1]; ul.z = lw_[2]; ul.w = lw_[3];
            *(uint4*)(qb + ((size_t)(s * HW) + p0 + p) * 16) = uh;
            *(uint4*)(qb + ((size_t)((s + 4) * HW) + p0 + p) * 16) = ul;
        }
    }
}

// ---------------------------------------------------------------------------
// Projection + l2norm + FUSED gauss-pool partials from planar Q.
// vpad=1: write edge-padded vn planes [c][64][72]; vpad=0: plain [c][HW].
// ---------------------------------------------------------------------------
__global__ __launch_bounds__(256) void proj_kernel(
    const unsigned short* __restrict__ q, const float* __restrict__ coef,
    const float* __restrict__ pw, unsigned short* __restrict__ outn,
    float* __restrict__ poolp, float* __restrict__ E, float* __restrict__ swp,
    const float* __restrict__ gauss, int vpad) {
    int b = blockIdx.y, chunk = blockIdx.x, tid = threadIdx.x;
    int p = chunk * 256 + tid;
    __shared__ float sR[4];
    __shared__ float sc[64];
    __shared__ float red[32][257];
    if (tid < 64) sc[tid] = coef[b * 64 + tid];
    __syncthreads();
    float feat[32];
    {
        const char* qb = (const char*)q + (size_t)b * 8 * HW * 16;
#pragma unroll
        for (int s = 0; s < 4; ++s) {
            uint4 uh = *(const uint4*)(qb + ((size_t)(s * HW) + p) * 16);
            uint4 ul = *(const uint4*)(qb + ((size_t)((s + 4) * HW) + p) * 16);
            unsigned int hd[4] = {uh.x, uh.y, uh.z, uh.w};
            unsigned int ld[4] = {ul.x, ul.y, ul.z, ul.w};
#pragma unroll
            for (int e = 0; e < 4; ++e) {
                int c0 = s * 8 + e * 2;
                float x0 = bf2f((unsigned short)(hd[e] & 0xFFFF)) + bf2f((unsigned short)(ld[e] & 0xFFFF));
                float x1 = bf2f((unsigned short)(hd[e] >> 16)) + bf2f((unsigned short)(ld[e] >> 16));
                feat[c0] = gelu_f(fmaf(sc[c0 * 2], x0, sc[c0 * 2 + 1]));
                feat[c0 + 1] = gelu_f(fmaf(sc[(c0 + 1) * 2], x1, sc[(c0 + 1) * 2 + 1]));
            }
        }
    }
    float g = gauss[p];
#pragma unroll
    for (int c = 0; c < 32; ++c) red[c][tid] = feat[c] * g;

    float o[32];
#pragma unroll
    for (int oo = 0; oo < 32; ++oo) o[oo] = 0.0f;
    for (int c = 0; c < 32; ++c) {
        float f = feat[c];
#pragma unroll
        for (int oo = 0; oo < 32; ++oo) o[oo] = fmaf(pw[oo * 32 + c], f, o[oo]);
    }
    float nn = 0.0f;
#pragma unroll
    for (int oo = 0; oo < 32; ++oo) nn = fmaf(o[oo], o[oo], nn);
    float n = sqrtf(nn);
    float inv = 1.0f / fmaxf(n, 1e-6f);
    if (vpad) {
        int y = p >> 6, x = p & 63;
        unsigned short* vb_ = outn + (size_t)b * 32 * 4608 + y * 72 + x + 4;
#pragma unroll
        for (int oo = 0; oo < 32; ++oo) {
            unsigned short hv = f2bf(o[oo] * inv);
            unsigned short* row = vb_ + (size_t)oo * 4608;
            row[0] = hv;
            if (x == 0) { row[-4] = hv; row[-3] = hv; row[-2] = hv; row[-1] = hv; }
            if (x == 63) { row[1] = hv; row[2] = hv; row[3] = hv; row[4] = hv; }
        }
    } else {
        unsigned short* obp = outn + (size_t)b * 32 * HW + p;
#pragma unroll
        for (int oo = 0; oo < 32; ++oo) obp[(size_t)oo * HW] = f2bf(o[oo] * inv);
    }

    __syncthreads();
    if (tid < 32) {
        float s = 0.0f;
#pragma unroll 8
        for (int i = 0; i < 256; ++i) s += red[tid][i];
        poolp[((size_t)b * 16 + chunk) * 32 + tid] = s;
    }

    if (E != nullptr) {
        float e = nn * inv * inv;
        E[(size_t)b * HW + p] = e;
        float wvv = e * g;
#pragma unroll
        for (int off = 32; off > 0; off >>= 1) wvv += __shfl_down(wvv, off);
        if ((tid & 63) == 0) sR[tid >> 6] = wvv;
        __syncthreads();
        if (tid == 0) swp[b * 16 + chunk] = sR[0] + sR[1] + sR[2] + sR[3];
    }
}

// ---------------------------------------------------------------------------
// 49-offset correlation logits, channel-split grid (bc, 8). No LDS staging:
// reads padded vn planes directly from global (L2-resident); fused swapply
// (q = E*gauss*scale/(sum+1e-8) inline).
// ---------------------------------------------------------------------------
__global__ __launch_bounds__(256) void logits_kernel(
    const unsigned short* __restrict__ rn, const unsigned short* __restrict__ vnp,
    const float* __restrict__ E, const float* __restrict__ swp,
    const float* __restrict__ gauss, float* __restrict__ lgpart) {
    int b = blockIdx.x, cg = blockIdx.y, tid = threadIdx.x;
    __shared__ float sR[4][49];
    float acc[49];
#pragma unroll
    for (int k = 0; k < 49; ++k) acc[k] = 0.0f;
    float ssum = 0.0f;
#pragma unroll
    for (int i = 0; i < 16; ++i) ssum += swp[b * 16 + i];
    const float scale = 0.17677669529663688f / (ssum + 1e-8f);
    const int x0 = (tid & 7) * 8;
    const float* Eb = E + (size_t)b * HW;
#pragma unroll 1
    for (int half = 0; half < 2; ++half) {
        const int y = half * 32 + (tid >> 3);
        const int pbase = y * 64 + x0;
        float4 e0 = *(const float4*)(Eb + pbase);
        float4 e1 = *(const float4*)(Eb + pbase + 4);
        float4 g0 = *(const float4*)(gauss + pbase);
        float4 g1 = *(const float4*)(gauss + pbase + 4);
        float qw[8];
        qw[0] = e0.x * g0.x * scale; qw[1] = e0.y * g0.y * scale;
        qw[2] = e0.z * g0.z * scale; qw[3] = e0.w * g0.w * scale;
        qw[4] = e1.x * g1.x * scale; qw[5] = e1.y * g1.y * scale;
        qw[6] = e1.z * g1.z * scale; qw[7] = e1.w * g1.w * scale;
#pragma unroll 1
        for (int cc = 0; cc < 4; ++cc) {
            int c = cg * 4 + cc;
            const unsigned short* rb = rn + ((size_t)b * 32 + c) * HW;
            uint4 rv = *(const uint4*)(rb + pbase);
            unsigned int rd[4] = {rv.x, rv.y, rv.z, rv.w};
            float r_[8];
            r_[0] = bf2f((unsigned short)(rd[0] & 0xFFFF)) * qw[0];
            r_[1] = bf2f((unsigned short)(rd[0] >> 16)) * qw[1];
            r_[2] = bf2f((unsigned short)(rd[1] & 0xFFFF)) * qw[2];
            r_[3] = bf2f((unsigned short)(rd[1] >> 16)) * qw[3];
            r_[4] = bf2f((unsigned short)(rd[2] & 0xFFFF)) * qw[4];
            r_[5] = bf2f((unsigned short)(rd[2] >> 16)) * qw[5];
            r_[6] = bf2f((unsigned short)(rd[3] & 0xFFFF)) * qw[6];
            r_[7] = bf2f((unsigned short)(rd[3] >> 16)) * qw[7];
            const unsigned short* vplane = vnp + ((size_t)b * 32 + c) * 4608;
#pragma unroll
            for (int dy = 0; dy < 7; ++dy) {
                int ry = y + dy - 3;
                ry = ry < 0 ? 0 : (ry > 63 ? 63 : ry);
                const unsigned short* vp = vplane + ry * 72 + x0;
                uint4 va = *(const uint4*)vp;
                uint4 vb2 = *(const uint4*)(vp + 8);
                unsigned int vd[8] = {va.x, va.y, va.z, va.w, vb2.x, vb2.y, vb2.z, vb2.w};
                float v[16];
#pragma unroll
                for (int j2 = 0; j2 < 8; ++j2) {
                    v[j2 * 2] = bf2f((unsigned short)(vd[j2] & 0xFFFF));
                    v[j2 * 2 + 1] = bf2f((unsigned short)(vd[j2] >> 16));
                }
#pragma unroll
                for (int dx = 0; dx < 7; ++dx)
#pragma unroll
                    for (int j = 0; j < 8; ++j)
                        acc[dy * 7 + dx] = fmaf(r_[j], v[j + dx + 1], acc[dy * 7 + dx]);
            }
        }
    }
#pragma unroll
    for (int k = 0; k < 49; ++k) {
#pragma unroll
        for (int off = 32; off > 0; off >>= 1) acc[k] += __shfl_down(acc[k], off);
    }
    int wid = tid >> 6;
    if ((tid & 63) == 0) {
#pragma unroll
        for (int k = 0; k < 49; ++k) sR[wid][k] = acc[k];
    }
    __syncthreads();
    if (tid < 49)
        lgpart[((size_t)b * 8 + cg) * 49 + tid] =
            sR[0][tid] + sR[1][tid] + sR[2][tid] + sR[3][tid];
}

// ---------------------------------------------------------------------------
// Softmax/coarse + MLP head + output assembly. Reduces logit & pool partials.
// ---------------------------------------------------------------------------
__global__ __launch_bounds__(128) void head_kernel(
    const float* __restrict__ lg, const float* __restrict__ rpp,
    const float* __restrict__ vpp, const float* __restrict__ p2s,
    const float* __restrict__ log_temp,
    const float* __restrict__ W1, const float* __restrict__ b1,
    const float* __restrict__ W2, const float* __restrict__ b2,
    const float* __restrict__ W3, const float* __restrict__ b3,
    float* __restrict__ out) {
    int b = blockIdx.x, t = threadIdx.x;
    __shared__ float slg[49];
    __shared__ float pooled[98];
    __shared__ float h1[128], h2[128];
    __shared__ float cxy[2];
    __shared__ float res[3];
    const float* lgp = lg + (size_t)b * 8 * 49;
    if (t < 49) {
        float s = 0.0f;
#pragma unroll
        for (int g = 0; g < 8; ++g) s += lgp[g * 49 + t];
        slg[t] = s;
    }
    __syncthreads();
    if (t == 0) {
        float temp = fmaxf(expf(log_temp[0]), 0.001f);
        float invT = 1.0f / temp;
        float m = -1e30f;
        for (int k = 0; k < 49; ++k) m = fmaxf(m, slg[k] * invT);
        float s = 0.0f, pdx = 0.0f, pdy = 0.0f;
        for (int k = 0; k < 49; ++k) {
            float e = expf(slg[k] * invT - m);
            s += e;
            pdx += e * (float)((k % 7) - 3);
            pdy += e * (float)((k / 7) - 3);
        }
        cxy[0] = pdx / s;
        cxy[1] = pdy / s;
    }
    __syncthreads();
    if (t < 32) {
        float a = 0.0f, c = 0.0f;
#pragma unroll
        for (int k = 0; k < 16; ++k) {
            a += rpp[((size_t)b * 16 + k) * 32 + t];
            c += vpp[((size_t)b * 16 + k) * 32 + t];
        }
        pooled[t] = a;
        pooled[32 + t] = c;
        pooled[64 + t] = a - c;
    }
    if (t == 0) {
        pooled[96] = cxy[0];
        pooled[97] = cxy[1];
    }
    __syncthreads();
    float s1 = b1[t];
    for (int i = 0; i < 98; ++i) s1 = fmaf(pooled[i], W1[i * 128 + t], s1);
    h1[t] = gelu_f(s1);
    __syncthreads();
    float s2 = b2[t];
    for (int i = 0; i < 128; ++i) s2 = fmaf(h1[i], W2[i * 128 + t], s2);
    h2[t] = gelu_f(s2);
    __syncthreads();
    if (t < 3) {
        float r = b3[t];
        for (int i = 0; i < 128; ++i) r = fmaf(h2[i], W3[i * 3 + t], r);
        res[t] = r;
    }
    __syncthreads();
    if (t == 0) {
        float dxp = cxy[0] + res[0];
        float dyp = cxy[1] + res[1];
        float ls = fminf(fmaxf(res[2], -6.0f), 3.0f);
        const float* M = p2s + b * 4;
        float* ob = out + b * 54;
        ob[0] = dxp;
        ob[1] = dyp;
        ob[2] = M[0] * dxp + M[1] * dyp;
        ob[3] = M[2] * dxp + M[3] * dyp;
        ob[4] = ls;
    }
    if (t < 49) out[b * 54 + 5 + t] = slg[t];
}

extern "C" void kernel_launch(void* const* d_in, const int* in_sizes, int n_in,
                              void* d_out, int out_size, void* d_ws, size_t ws_size,
                              hipStream_t stream) {
    (void)in_sizes; (void)n_in; (void)out_size;
    const float* rubin = (const float*)d_in[0];
    const float* vis   = (const float*)d_in[1];
    const float* p2s   = (const float*)d_in[2];
    const float* rW0   = (const float*)d_in[3];
    const float* rWs   = (const float*)d_in[4];
    const float* rG    = (const float*)d_in[5];
    const float* rBt   = (const float*)d_in[6];
    const float* vW0   = (const float*)d_in[7];
    const float* vWs   = (const float*)d_in[8];
    const float* vG    = (const float*)d_in[9];
    const float* vBt   = (const float*)d_in[10];
    const float* projR = (const float*)d_in[11];
    const float* projV = (const float*)d_in[12];
    const float* logT  = (const float*)d_in[13];
    const float* W1    = (const float*)d_in[14];
    const float* b1    = (const float*)d_in[15];
    const float* W2    = (const float*)d_in[16];
    const float* b2    = (const float*)d_in[17];
    const float* W3    = (const float*)d_in[18];
    const float* b3    = (const float*)d_in[19];
    float* out = (float*)d_out;

    // ---- workspace layout (bytes)
    char* ws = (char*)d_ws;
    size_t off = 0;
    unsigned short* vnB = (unsigned short*)(ws + off); off += (size_t)NB * 32 * 4608 * 2;  // 75.5 MB padded
    float* gauss  = (float*)(ws + off); off += HW * 4;
    float* statp  = (float*)(ws + off); off += (size_t)NB * 16 * 8 * 4;
    float* coefS  = (float*)(ws + off); off += (size_t)NB * 64 * 4;
    float* swp    = (float*)(ws + off); off += (size_t)NB * 16 * 4;
    float* rpp    = (float*)(ws + off); off += (size_t)NB * 16 * 32 * 4;
    float* vpp    = (float*)(ws + off); off += (size_t)NB * 16 * 32 * 4;
    float* lgbuf  = (float*)(ws + off); off += (size_t)NB * 8 * 49 * 4;
    unsigned short* wq = (unsigned short*)(ws + off); off += 110592ull * 2;
    off = (off + 255) & ~(size_t)255;
    const size_t fixed_bytes = off;
    const size_t perb = 2ull * HW * 128 + HW * 4;  // Q1+Q2 planar blocks + E
    int BC = 1;
    if (ws_size > fixed_bytes + perb) {
        size_t t = (ws_size - fixed_bytes) / perb;
        BC = t > (size_t)NB ? NB : (int)t;
    }
    unsigned short* Q1 = (unsigned short*)(ws + off);
    unsigned short* Q2 = (unsigned short*)(ws + off + (size_t)BC * HW * 128);
    float* E = (float*)(ws + off + 2ull * BC * HW * 128);

    dim3 blk256(256), blk128(128);
    gauss_kernel<<<1, 256, 0, stream>>>(gauss);
    prep_w_kernel<<<432, 256, 0, stream>>>(rWs, vWs, wq);

    // ================= VIS encoder (all chunks) =================
    for (int b0 = 0; b0 < NB; b0 += BC) {
        const int bc = (NB - b0) < BC ? (NB - b0) : BC;
        dim3 cg16(16, bc);
        const int gnblk = (bc * 32 + 255) / 256;
        float* sp = statp + (size_t)b0 * 128;
        float* cS = coefS + (size_t)b0 * 64;

        conv_first_kernel<1><<<cg16, blk256, 0, stream>>>(vis + (size_t)b0 * HW, vW0, Q1, sp);
        gn_finalize_kernel<<<gnblk, 256, 0, stream>>>(sp, vG + 0, vBt + 0, cS, bc * 32);
        convm_kernel<<<cg16, blk128, 0, stream>>>(Q1, cS, wq + 3 * 18432, Q2, sp);
        gn_finalize_kernel<<<gnblk, 256, 0, stream>>>(sp, vG + 32, vBt + 32, cS, bc * 32);
        convm_kernel<<<cg16, blk128, 0, stream>>>(Q2, cS, wq + 4 * 18432, Q1, sp);
        gn_finalize_kernel<<<gnblk, 256, 0, stream>>>(sp, vG + 64, vBt + 64, cS, bc * 32);
        convm_kernel<<<cg16, blk128, 0, stream>>>(Q1, cS, wq + 5 * 18432, Q2, sp);
        gn_finalize_kernel<<<gnblk, 256, 0, stream>>>(sp, vG + 96, vBt + 96, cS, bc * 32);
        proj_kernel<<<cg16, blk256, 0, stream>>>(Q2, cS, projV, vnB + (size_t)b0 * 32 * 4608,
                                                 vpp + (size_t)b0 * 512,
                                                 (float*)nullptr, (float*)nullptr, gauss, 1);
    }

    // ================= RUBIN encoder + logits (all chunks) =================
    for (int b0 = 0; b0 < NB; b0 += BC) {
        const int bc = (NB - b0) < BC ? (NB - b0) : BC;
        dim3 cg16(16, bc);
        const int gnblk = (bc * 32 + 255) / 256;
        float* sp = statp + (size_t)b0 * 128;
        float* cS = coefS + (size_t)b0 * 64;
        float* sw = swp + (size_t)b0 * 16;
        unsigned short* rnB = Q1;  // dead after last convm reads it

        conv_first_kernel<6><<<cg16, blk256, 0, stream>>>(rubin + (size_t)b0 * 6 * HW, rW0, Q1, sp);
        gn_finalize_kernel<<<gnblk, 256, 0, stream>>>(sp, rG + 0, rBt + 0, cS, bc * 32);
        convm_kernel<<<cg16, blk128, 0, stream>>>(Q1, cS, wq + 0 * 18432, Q2, sp);
        gn_finalize_kernel<<<gnblk, 256, 0, stream>>>(sp, rG + 32, rBt + 32, cS, bc * 32);
        convm_kernel<<<cg16, blk128, 0, stream>>>(Q2, cS, wq + 1 * 18432, Q1, sp);
        gn_finalize_kernel<<<gnblk, 256, 0, stream>>>(sp, rG + 64, rBt + 64, cS, bc * 32);
        convm_kernel<<<cg16, blk128, 0, stream>>>(Q1, cS, wq + 2 * 18432, Q2, sp);
        gn_finalize_kernel<<<gnblk, 256, 0, stream>>>(sp, rG + 96, rBt + 96, cS, bc * 32);
        proj_kernel<<<cg16, blk256, 0, stream>>>(Q2, cS, projR, rnB,
                                                 rpp + (size_t)b0 * 512, E, sw, gauss, 0);
        logits_kernel<<<dim3(bc, 8), blk256, 0, stream>>>(rnB, vnB + (size_t)b0 * 32 * 4608,
                                                          E, sw, gauss,
                                                          lgbuf + (size_t)b0 * 8 * 49);
    }

    head_kernel<<<NB, 128, 0, stream>>>(lgbuf, rpp, vpp, p2s, logT, W1, b1, W2, b2, W3, b3, out);
}

// Round 11
// 993.209 us; speedup vs baseline: 2.4606x; 1.5430x over previous
//
#include <hip/hip_runtime.h>
#include <math.h>

#define HW 4096
#define NB 256

typedef __attribute__((ext_vector_type(8))) short bf16x8_t;
typedef __attribute__((ext_vector_type(16))) float f32x16_t;

// Fast erf-based GELU (A&S 7.1.26, |err| <= 1.5e-7)
__device__ __forceinline__ float gelu_f(float x) {
    float z = x * 0.70710678118654752440f;
    float az = fabsf(z);
    float t = 1.0f / fmaf(0.3275911f, az, 1.0f);
    float p = t * fmaf(t, fmaf(t, fmaf(t, fmaf(t, 1.061405429f, -1.453152027f),
                                       1.421413741f), -0.284496736f), 0.254829592f);
    float e = __expf(-az * az);
    float er = 1.0f - p * e;
    er = copysignf(er, z);
    return 0.5f * x * (1.0f + er);
}
__device__ __forceinline__ unsigned short f2bf(float f) {
    unsigned int u = __float_as_uint(f);
    unsigned int r = u + 0x7FFFu + ((u >> 16) & 1u);
    return (unsigned short)(r >> 16);
}
__device__ __forceinline__ float bf2f(unsigned short h) {
    return __uint_as_float(((unsigned int)h) << 16);
}

// Q layout (PLANAR, single-bf16): Q[b][s][p], s=0..3 = ci-group (8 ch, 16 B),
// p = pixel. 64 B/px total. Weights stay split hi/lo (2-term x*wh + x*wl).
// vn planes edge-padded [c][64][72] bf16.

// ---------------------------------------------------------------------------
__global__ __launch_bounds__(256) void gauss_kernel(float* __restrict__ gauss) {
    __shared__ float sg[HW];
    __shared__ float sR[4];
    int tid = threadIdx.x;
    float part = 0.0f;
    for (int p = tid; p < HW; p += 256) {
        int y = p >> 6, x = p & 63;
        float yy = -1.0f + (2.0f / 63.0f) * (float)y;
        float xx = -1.0f + (2.0f / 63.0f) * (float)x;
        float g = expf(-(yy * yy + xx * xx) * 2.0f);
        sg[p] = g;
        part += g;
    }
#pragma unroll
    for (int off = 32; off > 0; off >>= 1) part += __shfl_down(part, off);
    if ((tid & 63) == 0) sR[tid >> 6] = part;
    __syncthreads();
    float invt = 1.0f / (sR[0] + sR[1] + sR[2] + sR[3]);
    for (int p = tid; p < HW; p += 256) gauss[p] = sg[p] * invt;
}

// ---------------------------------------------------------------------------
__global__ __launch_bounds__(256) void prep_w_kernel(
    const float* __restrict__ rWs, const float* __restrict__ vWs,
    unsigned short* __restrict__ wq) {
    int i = blockIdx.x * 256 + threadIdx.x;
    if (i >= 110592) return;
    int j = i & 7;
    int lane = (i >> 3) & 63;
    int f = i >> 9;
    int hl = f & 1, k2 = (f >> 1) & 1, tap = (f >> 2) % 9, layer = (f >> 2) / 9;
    int co = lane & 31, hf = lane >> 5;
    int ci = k2 * 16 + hf * 8 + j;
    int ky = tap / 3, kx = tap % 3;
    float wv = (layer < 3)
        ? rWs[(((size_t)layer * 32 + co) * 32 + ci) * 9 + ky * 3 + kx]
        : vWs[(((size_t)(layer - 3) * 32 + co) * 32 + ci) * 9 + ky * 3 + kx];
    unsigned short h = f2bf(wv);
    unsigned short l = f2bf(wv - bf2f(h));
    wq[i] = hl ? l : h;
}

// ---------------------------------------------------------------------------
// First conv layer, fp32 VALU. Writes RAW single-bf16 planar Q + stats.
// ---------------------------------------------------------------------------
template <int CIN>
__global__ __launch_bounds__(256) void conv_first_kernel(
    const float* __restrict__ in, const float* __restrict__ w,
    unsigned short* __restrict__ qout, float* __restrict__ statp) {
    const int b = blockIdx.y;
    const int strip = blockIdx.x;
    const int tid = threadIdx.x;
    const int x = tid & 63;
    const int wid = tid >> 6;

    __shared__ float sIn[CIN][6][66];
    __shared__ float sRed[4][8];

    const float* inb = in + (size_t)b * CIN * HW;
    for (int idx = tid; idx < CIN * 6 * 66; idx += 256) {
        int ci = idx / (6 * 66);
        int rem = idx - ci * (6 * 66);
        int r = rem / 66;
        int p = rem - r * 66;
        int gy = strip * 4 - 1 + r;
        int gx = p - 1;
        float v = 0.0f;
        if (gy >= 0 && gy < 64 && gx >= 0 && gx < 64) v = inb[ci * HW + gy * 64 + gx];
        sIn[ci][r][p] = v;
    }
    __syncthreads();

    float acc[32];
#pragma unroll
    for (int co = 0; co < 32; ++co) acc[co] = 0.0f;

    for (int ci = 0; ci < CIN; ++ci) {
        float vv[9];
#pragma unroll
        for (int ky = 0; ky < 3; ++ky)
#pragma unroll
            for (int kx = 0; kx < 3; ++kx) vv[ky * 3 + kx] = sIn[ci][wid + ky][x + kx];
#pragma unroll
        for (int co = 0; co < 32; ++co) {
            const float* wk = w + ((size_t)co * CIN + ci) * 9;
            float s = acc[co];
#pragma unroll
            for (int k = 0; k < 9; ++k) s = fmaf(wk[k], vv[k], s);
            acc[co] = s;
        }
    }

    const int gy = strip * 4 + wid;
    {
        int gp = gy * 64 + x;
        char* qb = (char*)qout + (size_t)b * 4 * HW * 16;
#pragma unroll
        for (int s = 0; s < 4; ++s) {
            unsigned int hw_[4];
#pragma unroll
            for (int e = 0; e < 4; ++e) {
                int c = s * 8 + e * 2;
                hw_[e] = (unsigned)f2bf(acc[c]) | ((unsigned)f2bf(acc[c + 1]) << 16);
            }
            uint4 uh; uh.x = hw_[0]; uh.y = hw_[1]; uh.z = hw_[2]; uh.w = hw_[3];
            *(uint4*)(qb + ((size_t)(s * HW) + gp) * 16) = uh;
        }
    }
    float s1[4] = {0, 0, 0, 0}, s2[4] = {0, 0, 0, 0};
#pragma unroll
    for (int co = 0; co < 32; ++co) {
        float v = acc[co];
        s1[co >> 3] += v;
        s2[co >> 3] = fmaf(v, v, s2[co >> 3]);
    }
#pragma unroll
    for (int off = 32; off > 0; off >>= 1) {
#pragma unroll
        for (int g = 0; g < 4; ++g) {
            s1[g] += __shfl_down(s1[g], off);
            s2[g] += __shfl_down(s2[g], off);
        }
    }
    if ((tid & 63) == 0) {
#pragma unroll
        for (int g = 0; g < 4; ++g) {
            sRed[wid][g] = s1[g];
            sRed[wid][4 + g] = s2[g];
        }
    }
    __syncthreads();
    if (tid < 8) {
        float t = sRed[0][tid] + sRed[1][tid] + sRed[2][tid] + sRed[3][tid];
        statp[((size_t)b * 16 + strip) * 8 + tid] = t;
    }
}

// ---------------------------------------------------------------------------
__global__ __launch_bounds__(256) void gn_finalize_kernel(
    const float* __restrict__ statp, const float* __restrict__ gma,
    const float* __restrict__ bta, float* __restrict__ coef, int n) {
    int i = blockIdx.x * 256 + threadIdx.x;
    if (i >= n) return;
    int b = i >> 5, c = i & 31, g = c >> 3;
    float s1 = 0.0f, s2 = 0.0f;
    for (int s = 0; s < 16; ++s) {
        s1 += statp[((size_t)b * 16 + s) * 8 + g];
        s2 += statp[((size_t)b * 16 + s) * 8 + 4 + g];
    }
    const float invN = 1.0f / 32768.0f;
    float mean = s1 * invN;
    float var = s2 * invN - mean * mean;
    float rstd = rsqrtf(var + 1e-5f);
    float a = rstd * gma[c];
    float bb = bta[c] - mean * a;
    coef[i * 2 + 0] = a;
    coef[i * 2 + 1] = bb;
}

// ---------------------------------------------------------------------------
// MFMA 3x3 conv, fused GN+GELU, single-bf16 x, split-w 2-term.
// LDS: 6 rows x 66 slots x 80 B (64 B data = 4 sub-blocks rotated by px&3,
// +16 B pad to break bank aliasing) = 31.7 KB -> ~5 blocks/CU.
// ---------------------------------------------------------------------------
#define SLOT 80
#define ROWB (66 * SLOT)
__global__ __launch_bounds__(128) void convm_kernel(
    const unsigned short* __restrict__ qin, const float* __restrict__ coef,
    const unsigned short* __restrict__ wq,
    unsigned short* __restrict__ qout, float* __restrict__ statp) {
    const int b = blockIdx.y;
    const int strip = blockIdx.x;
    const int tid = threadIdx.x;
    const int wv = tid >> 6;
    const int lane = tid & 63;
    const int m = lane & 31;
    const int hf = lane >> 5;
    const int xh32 = wv * 32;

    __shared__ __align__(16) char sQ[6 * ROWB];   // 31680 B
    __shared__ float sRed[2][8];
    __shared__ float sc[64];

    const int y0 = strip * 4;
    const char* img = (const char*)qin + (size_t)b * 4 * HW * 16;

    if (tid < 64) sc[tid] = coef[b * 64 + tid];
    // zero halo slots 0 and 65 (all 4 sub-blocks)
    if (tid < 48) {
        int r = tid >> 3, side = (tid >> 2) & 1, sub = tid & 3;
        uint4 z; z.x = z.y = z.z = z.w = 0;
        *(uint4*)(sQ + r * ROWB + side * 65 * SLOT + sub * 16) = z;
    }
    __syncthreads();

    // staging: thread -> pixel px; wave+k -> sub-block s in {wv, wv+2}
    const int px = tid & 63;
    const int rot = px & 3;
    float ca[2][8], cb[2][8];
#pragma unroll
    for (int k = 0; k < 2; ++k) {
        int s = k * 2 + wv;
#pragma unroll
        for (int e = 0; e < 8; ++e) {
            ca[k][e] = sc[(s * 8 + e) * 2 + 0];
            cb[k][e] = sc[(s * 8 + e) * 2 + 1];
        }
    }
    char* dstp = sQ + (px + 1) * SLOT;
#pragma unroll
    for (int r = 0; r < 6; ++r) {
        int gy = y0 - 1 + r;
        int gp = gy * 64 + px;
        char* dst = dstp + r * ROWB;
#pragma unroll
        for (int k = 0; k < 2; ++k) {
            int s = k * 2 + wv;
            uint4 oh;
            if (gy >= 0 && gy < 64) {
                uint4 uhv = *(const uint4*)(img + ((size_t)(s * HW) + gp) * 16);
                unsigned int hd[4] = {uhv.x, uhv.y, uhv.z, uhv.w};
                unsigned int ho[4];
#pragma unroll
                for (int e = 0; e < 4; ++e) {
                    float x0 = bf2f((unsigned short)(hd[e] & 0xFFFF));
                    float x1 = bf2f((unsigned short)(hd[e] >> 16));
                    float y0v = gelu_f(fmaf(ca[k][e * 2], x0, cb[k][e * 2]));
                    float y1v = gelu_f(fmaf(ca[k][e * 2 + 1], x1, cb[k][e * 2 + 1]));
                    ho[e] = (unsigned)f2bf(y0v) | ((unsigned)f2bf(y1v) << 16);
                }
                oh.x = ho[0]; oh.y = ho[1]; oh.z = ho[2]; oh.w = ho[3];
            } else {
                oh.x = oh.y = oh.z = oh.w = 0;
            }
            *(uint4*)(dst + ((s + rot) & 3) * 16) = oh;
        }
    }
    __syncthreads();

    f32x16_t acc[4];
#pragma unroll
    for (int i = 0; i < 4; ++i)
#pragma unroll
        for (int j = 0; j < 16; ++j) acc[i][j] = 0.0f;

    for (int kx = 0; kx < 3; ++kx) {
        bf16x8_t Wf[3][2][2];  // [ky][kstep][hl]
#pragma unroll
        for (int ky = 0; ky < 3; ++ky)
#pragma unroll
            for (int k2 = 0; k2 < 2; ++k2)
#pragma unroll
                for (int hl = 0; hl < 2; ++hl) {
                    int fi = ((ky * 3 + kx) * 2 + k2) * 2 + hl;
                    Wf[ky][k2][hl] = __builtin_bit_cast(
                        bf16x8_t, *(const uint4*)(wq + (size_t)fi * 512 + lane * 8));
                }
        const int slotb = xh32 + kx + m;
        const int prot = (m + kx + 3) & 3;     // (xh32+m+kx-1)&3, xh32%4==0
#pragma unroll
        for (int li = 0; li < 6; ++li) {
            const char* rowp = sQ + li * ROWB + slotb * SLOT;
            bf16x8_t Ah[2];
#pragma unroll
            for (int k2 = 0; k2 < 2; ++k2) {
                int s = k2 * 2 + hf;
                Ah[k2] = __builtin_bit_cast(bf16x8_t, *(const uint4*)(rowp + ((s + prot) & 3) * 16));
            }
#pragma unroll
            for (int ky = 0; ky < 3; ++ky) {
                int orow = li - ky;
                if (orow < 0 || orow > 3) continue;
#pragma unroll
                for (int k2 = 0; k2 < 2; ++k2) {
                    acc[orow] = __builtin_amdgcn_mfma_f32_32x32x16_bf16(Ah[k2], Wf[ky][k2][0], acc[orow], 0, 0, 0);
                    acc[orow] = __builtin_amdgcn_mfma_f32_32x32x16_bf16(Ah[k2], Wf[ky][k2][1], acc[orow], 0, 0, 0);
                }
            }
        }
    }

    // ---- epilogue: stats + u16 LDS transpose (stride 40 u16 = 80 B) + stores
    __syncthreads();
    unsigned short* lds_t = (unsigned short*)sQ;  // [256 px][40] u16
    const int co = lane & 31;
    float s1 = 0.0f, s2 = 0.0f;
#pragma unroll
    for (int orow = 0; orow < 4; ++orow) {
#pragma unroll
        for (int r = 0; r < 16; ++r) {
            int mm = (r & 3) + 8 * (r >> 2) + 4 * hf;
            int pxl = (orow << 6) + xh32 + mm;
            float v = acc[orow][r];
            s1 += v;
            s2 = fmaf(v, v, s2);
            lds_t[pxl * 40 + co] = f2bf(v);
        }
    }
    s1 += __shfl_xor(s1, 32); s2 += __shfl_xor(s2, 32);
    s1 += __shfl_xor(s1, 1);  s2 += __shfl_xor(s2, 1);
    s1 += __shfl_xor(s1, 2);  s2 += __shfl_xor(s2, 2);
    s1 += __shfl_xor(s1, 4);  s2 += __shfl_xor(s2, 4);
    if (lane < 32 && (lane & 7) == 0) {
        sRed[wv][co >> 3] = s1;
        sRed[wv][4 + (co >> 3)] = s2;
    }
    __syncthreads();
    if (tid < 8) statp[((size_t)b * 16 + strip) * 8 + tid] = sRed[0][tid] + sRed[1][tid];

    char* qb = (char*)qout + (size_t)b * 4 * HW * 16;
    const int p0 = y0 * 64;
#pragma unroll
    for (int pi = 0; pi < 2; ++pi) {
        int p = pi * 128 + tid;          // 0..255
#pragma unroll
        for (int s = 0; s < 4; ++s) {
            uint4 uh = *(const uint4*)(lds_t + p * 40 + s * 8);
            *(uint4*)(qb + ((size_t)(s * HW) + p0 + p) * 16) = uh;
        }
    }
}

// ---------------------------------------------------------------------------
// Projection + l2norm + fused gauss-pool partials from single-bf16 planar Q.
// ---------------------------------------------------------------------------
__global__ __launch_bounds__(256) void proj_kernel(
    const unsigned short* __restrict__ q, const float* __restrict__ coef,
    const float* __restrict__ pw, unsigned short* __restrict__ outn,
    float* __restrict__ poolp, float* __restrict__ E, float* __restrict__ swp,
    const float* __restrict__ gauss, int vpad) {
    int b = blockIdx.y, chunk = blockIdx.x, tid = threadIdx.x;
    int p = chunk * 256 + tid;
    __shared__ float sR[4];
    __shared__ float sc[64];
    __shared__ float red[32][257];
    if (tid < 64) sc[tid] = coef[b * 64 + tid];
    __syncthreads();
    float feat[32];
    {
        const char* qb = (const char*)q + (size_t)b * 4 * HW * 16;
#pragma unroll
        for (int s = 0; s < 4; ++s) {
            uint4 uh = *(const uint4*)(qb + ((size_t)(s * HW) + p) * 16);
            unsigned int hd[4] = {uh.x, uh.y, uh.z, uh.w};
#pragma unroll
            for (int e = 0; e < 4; ++e) {
                int c0 = s * 8 + e * 2;
                float x0 = bf2f((unsigned short)(hd[e] & 0xFFFF));
                float x1 = bf2f((unsigned short)(hd[e] >> 16));
                feat[c0] = gelu_f(fmaf(sc[c0 * 2], x0, sc[c0 * 2 + 1]));
                feat[c0 + 1] = gelu_f(fmaf(sc[(c0 + 1) * 2], x1, sc[(c0 + 1) * 2 + 1]));
            }
        }
    }
    float g = gauss[p];
#pragma unroll
    for (int c = 0; c < 32; ++c) red[c][tid] = feat[c] * g;

    float o[32];
#pragma unroll
    for (int oo = 0; oo < 32; ++oo) o[oo] = 0.0f;
    for (int c = 0; c < 32; ++c) {
        float f = feat[c];
#pragma unroll
        for (int oo = 0; oo < 32; ++oo) o[oo] = fmaf(pw[oo * 32 + c], f, o[oo]);
    }
    float nn = 0.0f;
#pragma unroll
    for (int oo = 0; oo < 32; ++oo) nn = fmaf(o[oo], o[oo], nn);
    float n = sqrtf(nn);
    float inv = 1.0f / fmaxf(n, 1e-6f);
    if (vpad) {
        int y = p >> 6, x = p & 63;
        unsigned short* vb_ = outn + (size_t)b * 32 * 4608 + y * 72 + x + 4;
#pragma unroll
        for (int oo = 0; oo < 32; ++oo) {
            unsigned short hv = f2bf(o[oo] * inv);
            unsigned short* row = vb_ + (size_t)oo * 4608;
            row[0] = hv;
            if (x == 0) { row[-4] = hv; row[-3] = hv; row[-2] = hv; row[-1] = hv; }
            if (x == 63) { row[1] = hv; row[2] = hv; row[3] = hv; row[4] = hv; }
        }
    } else {
        unsigned short* obp = outn + (size_t)b * 32 * HW + p;
#pragma unroll
        for (int oo = 0; oo < 32; ++oo) obp[(size_t)oo * HW] = f2bf(o[oo] * inv);
    }

    __syncthreads();
    if (tid < 32) {
        float s = 0.0f;
#pragma unroll 8
        for (int i = 0; i < 256; ++i) s += red[tid][i];
        poolp[((size_t)b * 16 + chunk) * 32 + tid] = s;
    }

    if (E != nullptr) {
        float e = nn * inv * inv;
        E[(size_t)b * HW + p] = e;
        float wvv = e * g;
#pragma unroll
        for (int off = 32; off > 0; off >>= 1) wvv += __shfl_down(wvv, off);
        if ((tid & 63) == 0) sR[tid >> 6] = wvv;
        __syncthreads();
        if (tid == 0) swp[b * 16 + chunk] = sR[0] + sR[1] + sR[2] + sR[3];
    }
}

// ---------------------------------------------------------------------------
// 49-offset correlation logits, channel-split grid (bc, 8), no LDS staging,
// fused swapply.
// ---------------------------------------------------------------------------
__global__ __launch_bounds__(256) void logits_kernel(
    const unsigned short* __restrict__ rn, const unsigned short* __restrict__ vnp,
    const float* __restrict__ E, const float* __restrict__ swp,
    const float* __restrict__ gauss, float* __restrict__ lgpart) {
    int b = blockIdx.x, cg = blockIdx.y, tid = threadIdx.x;
    __shared__ float sR[4][49];
    float acc[49];
#pragma unroll
    for (int k = 0; k < 49; ++k) acc[k] = 0.0f;
    float ssum = 0.0f;
#pragma unroll
    for (int i = 0; i < 16; ++i) ssum += swp[b * 16 + i];
    const float scale = 0.17677669529663688f / (ssum + 1e-8f);
    const int x0 = (tid & 7) * 8;
    const float* Eb = E + (size_t)b * HW;
#pragma unroll 1
    for (int half = 0; half < 2; ++half) {
        const int y = half * 32 + (tid >> 3);
        const int pbase = y * 64 + x0;
        float4 e0 = *(const float4*)(Eb + pbase);
        float4 e1 = *(const float4*)(Eb + pbase + 4);
        float4 g0 = *(const float4*)(gauss + pbase);
        float4 g1 = *(const float4*)(gauss + pbase + 4);
        float qw[8];
        qw[0] = e0.x * g0.x * scale; qw[1] = e0.y * g0.y * scale;
        qw[2] = e0.z * g0.z * scale; qw[3] = e0.w * g0.w * scale;
        qw[4] = e1.x * g1.x * scale; qw[5] = e1.y * g1.y * scale;
        qw[6] = e1.z * g1.z * scale; qw[7] = e1.w * g1.w * scale;
#pragma unroll 1
        for (int cc = 0; cc < 4; ++cc) {
            int c = cg * 4 + cc;
            const unsigned short* rb = rn + ((size_t)b * 32 + c) * HW;
            uint4 rv = *(const uint4*)(rb + pbase);
            unsigned int rd[4] = {rv.x, rv.y, rv.z, rv.w};
            float r_[8];
            r_[0] = bf2f((unsigned short)(rd[0] & 0xFFFF)) * qw[0];
            r_[1] = bf2f((unsigned short)(rd[0] >> 16)) * qw[1];
            r_[2] = bf2f((unsigned short)(rd[1] & 0xFFFF)) * qw[2];
            r_[3] = bf2f((unsigned short)(rd[1] >> 16)) * qw[3];
            r_[4] = bf2f((unsigned short)(rd[2] & 0xFFFF)) * qw[4];
            r_[5] = bf2f((unsigned short)(rd[2] >> 16)) * qw[5];
            r_[6] = bf2f((unsigned short)(rd[3] & 0xFFFF)) * qw[6];
            r_[7] = bf2f((unsigned short)(rd[3] >> 16)) * qw[7];
            const unsigned short* vplane = vnp + ((size_t)b * 32 + c) * 4608;
#pragma unroll
            for (int dy = 0; dy < 7; ++dy) {
                int ry = y + dy - 3;
                ry = ry < 0 ? 0 : (ry > 63 ? 63 : ry);
                const unsigned short* vp = vplane + ry * 72 + x0;
                uint4 va = *(const uint4*)vp;
                uint4 vb2 = *(const uint4*)(vp + 8);
                unsigned int vd[8] = {va.x, va.y, va.z, va.w, vb2.x, vb2.y, vb2.z, vb2.w};
                float v[16];
#pragma unroll
                for (int j2 = 0; j2 < 8; ++j2) {
                    v[j2 * 2] = bf2f((unsigned short)(vd[j2] & 0xFFFF));
                    v[j2 * 2 + 1] = bf2f((unsigned short)(vd[j2] >> 16));
                }
#pragma unroll
                for (int dx = 0; dx < 7; ++dx)
#pragma unroll
                    for (int j = 0; j < 8; ++j)
                        acc[dy * 7 + dx] = fmaf(r_[j], v[j + dx + 1], acc[dy * 7 + dx]);
            }
        }
    }
#pragma unroll
    for (int k = 0; k < 49; ++k) {
#pragma unroll
        for (int off = 32; off > 0; off >>= 1) acc[k] += __shfl_down(acc[k], off);
    }
    int wid = tid >> 6;
    if ((tid & 63) == 0) {
#pragma unroll
        for (int k = 0; k < 49; ++k) sR[wid][k] = acc[k];
    }
    __syncthreads();
    if (tid < 49)
        lgpart[((size_t)b * 8 + cg) * 49 + tid] =
            sR[0][tid] + sR[1][tid] + sR[2][tid] + sR[3][tid];
}

// ---------------------------------------------------------------------------
__global__ __launch_bounds__(128) void head_kernel(
    const float* __restrict__ lg, const float* __restrict__ rpp,
    const float* __restrict__ vpp, const float* __restrict__ p2s,
    const float* __restrict__ log_temp,
    const float* __restrict__ W1, const float* __restrict__ b1,
    const float* __restrict__ W2, const float* __restrict__ b2,
    const float* __restrict__ W3, const float* __restrict__ b3,
    float* __restrict__ out) {
    int b = blockIdx.x, t = threadIdx.x;
    __shared__ float slg[49];
    __shared__ float pooled[98];
    __shared__ float h1[128], h2[128];
    __shared__ float cxy[2];
    __shared__ float res[3];
    const float* lgp = lg + (size_t)b * 8 * 49;
    if (t < 49) {
        float s = 0.0f;
#pragma unroll
        for (int g = 0; g < 8; ++g) s += lgp[g * 49 + t];
        slg[t] = s;
    }
    __syncthreads();
    if (t == 0) {
        float temp = fmaxf(expf(log_temp[0]), 0.001f);
        float invT = 1.0f / temp;
        float m = -1e30f;
        for (int k = 0; k < 49; ++k) m = fmaxf(m, slg[k] * invT);
        float s = 0.0f, pdx = 0.0f, pdy = 0.0f;
        for (int k = 0; k < 49; ++k) {
            float e = expf(slg[k] * invT - m);
            s += e;
            pdx += e * (float)((k % 7) - 3);
            pdy += e * (float)((k / 7) - 3);
        }
        cxy[0] = pdx / s;
        cxy[1] = pdy / s;
    }
    __syncthreads();
    if (t < 32) {
        float a = 0.0f, c = 0.0f;
#pragma unroll
        for (int k = 0; k < 16; ++k) {
            a += rpp[((size_t)b * 16 + k) * 32 + t];
            c += vpp[((size_t)b * 16 + k) * 32 + t];
        }
        pooled[t] = a;
        pooled[32 + t] = c;
        pooled[64 + t] = a - c;
    }
    if (t == 0) {
        pooled[96] = cxy[0];
        pooled[97] = cxy[1];
    }
    __syncthreads();
    float s1 = b1[t];
    for (int i = 0; i < 98; ++i) s1 = fmaf(pooled[i], W1[i * 128 + t], s1);
    h1[t] = gelu_f(s1);
    __syncthreads();
    float s2 = b2[t];
    for (int i = 0; i < 128; ++i) s2 = fmaf(h1[i], W2[i * 128 + t], s2);
    h2[t] = gelu_f(s2);
    __syncthreads();
    if (t < 3) {
        float r = b3[t];
        for (int i = 0; i < 128; ++i) r = fmaf(h2[i], W3[i * 3 + t], r);
        res[t] = r;
    }
    __syncthreads();
    if (t == 0) {
        float dxp = cxy[0] + res[0];
        float dyp = cxy[1] + res[1];
        float ls = fminf(fmaxf(res[2], -6.0f), 3.0f);
        const float* M = p2s + b * 4;
        float* ob = out + b * 54;
        ob[0] = dxp;
        ob[1] = dyp;
        ob[2] = M[0] * dxp + M[1] * dyp;
        ob[3] = M[2] * dxp + M[3] * dyp;
        ob[4] = ls;
    }
    if (t < 49) out[b * 54 + 5 + t] = slg[t];
}

extern "C" void kernel_launch(void* const* d_in, const int* in_sizes, int n_in,
                              void* d_out, int out_size, void* d_ws, size_t ws_size,
                              hipStream_t stream) {
    (void)in_sizes; (void)n_in; (void)out_size;
    const float* rubin = (const float*)d_in[0];
    const float* vis   = (const float*)d_in[1];
    const float* p2s   = (const float*)d_in[2];
    const float* rW0   = (const float*)d_in[3];
    const float* rWs   = (const float*)d_in[4];
    const float* rG    = (const float*)d_in[5];
    const float* rBt   = (const float*)d_in[6];
    const float* vW0   = (const float*)d_in[7];
    const float* vWs   = (const float*)d_in[8];
    const float* vG    = (const float*)d_in[9];
    const float* vBt   = (const float*)d_in[10];
    const float* projR = (const float*)d_in[11];
    const float* projV = (const float*)d_in[12];
    const float* logT  = (const float*)d_in[13];
    const float* W1    = (const float*)d_in[14];
    const float* b1    = (const float*)d_in[15];
    const float* W2    = (const float*)d_in[16];
    const float* b2    = (const float*)d_in[17];
    const float* W3    = (const float*)d_in[18];
    const float* b3    = (const float*)d_in[19];
    float* out = (float*)d_out;

    // ---- workspace layout (bytes)
    char* ws = (char*)d_ws;
    size_t off = 0;
    unsigned short* vnB = (unsigned short*)(ws + off); off += (size_t)NB * 32 * 4608 * 2;
    float* gauss  = (float*)(ws + off); off += HW * 4;
    float* statp  = (float*)(ws + off); off += (size_t)NB * 16 * 8 * 4;
    float* coefS  = (float*)(ws + off); off += (size_t)NB * 64 * 4;
    float* swp    = (float*)(ws + off); off += (size_t)NB * 16 * 4;
    float* rpp    = (float*)(ws + off); off += (size_t)NB * 16 * 32 * 4;
    float* vpp    = (float*)(ws + off); off += (size_t)NB * 16 * 32 * 4;
    float* lgbuf  = (float*)(ws + off); off += (size_t)NB * 8 * 49 * 4;
    unsigned short* wq = (unsigned short*)(ws + off); off += 110592ull * 2;
    off = (off + 255) & ~(size_t)255;
    const size_t fixed_bytes = off;
    const size_t perb = 2ull * HW * 64 + HW * 4;  // Q1+Q2 (64 B/px) + E
    int BC = 1;
    if (ws_size > fixed_bytes + perb) {
        size_t t = (ws_size - fixed_bytes) / perb;
        BC = t > (size_t)NB ? NB : (int)t;
    }
    unsigned short* Q1 = (unsigned short*)(ws + off);
    unsigned short* Q2 = (unsigned short*)(ws + off + (size_t)BC * HW * 64);
    float* E = (float*)(ws + off + 2ull * BC * HW * 64);

    dim3 blk256(256), blk128(128);
    gauss_kernel<<<1, 256, 0, stream>>>(gauss);
    prep_w_kernel<<<432, 256, 0, stream>>>(rWs, vWs, wq);

    // ================= VIS encoder (all chunks) =================
    for (int b0 = 0; b0 < NB; b0 += BC) {
        const int bc = (NB - b0) < BC ? (NB - b0) : BC;
        dim3 cg16(16, bc);
        const int gnblk = (bc * 32 + 255) / 256;
        float* sp = statp + (size_t)b0 * 128;
        float* cS = coefS + (size_t)b0 * 64;

        conv_first_kernel<1><<<cg16, blk256, 0, stream>>>(vis + (size_t)b0 * HW, vW0, Q1, sp);
        gn_finalize_kernel<<<gnblk, 256, 0, stream>>>(sp, vG + 0, vBt + 0, cS, bc * 32);
        convm_kernel<<<cg16, blk128, 0, stream>>>(Q1, cS, wq + 3 * 18432, Q2, sp);
        gn_finalize_kernel<<<gnblk, 256, 0, stream>>>(sp, vG + 32, vBt + 32, cS, bc * 32);
        convm_kernel<<<cg16, blk128, 0, stream>>>(Q2, cS, wq + 4 * 18432, Q1, sp);
        gn_finalize_kernel<<<gnblk, 256, 0, stream>>>(sp, vG + 64, vBt + 64, cS, bc * 32);
        convm_kernel<<<cg16, blk128, 0, stream>>>(Q1, cS, wq + 5 * 18432, Q2, sp);
        gn_finalize_kernel<<<gnblk, 256, 0, stream>>>(sp, vG + 96, vBt + 96, cS, bc * 32);
        proj_kernel<<<cg16, blk256, 0, stream>>>(Q2, cS, projV, vnB + (size_t)b0 * 32 * 4608,
                                                 vpp + (size_t)b0 * 512,
                                                 (float*)nullptr, (float*)nullptr, gauss, 1);
    }

    // ================= RUBIN encoder + logits (all chunks) =================
    for (int b0 = 0; b0 < NB; b0 += BC) {
        const int bc = (NB - b0) < BC ? (NB - b0) : BC;
        dim3 cg16(16, bc);
        const int gnblk = (bc * 32 + 255) / 256;
        float* sp = statp + (size_t)b0 * 128;
        float* cS = coefS + (size_t)b0 * 64;
        float* sw = swp + (size_t)b0 * 16;
        unsigned short* rnB = Q1;  // reuse: Q1 dead after last convm reads it

        conv_first_kernel<6><<<cg16, blk256, 0, stream>>>(rubin + (size_t)b0 * 6 * HW, rW0, Q1, sp);
        gn_finalize_kernel<<<gnblk, 256, 0, stream>>>(sp, rG + 0, rBt + 0, cS, bc * 32);
        convm_kernel<<<cg16, blk128, 0, stream>>>(Q1, cS, wq + 0 * 18432, Q2, sp);
        gn_finalize_kernel<<<gnblk, 256, 0, stream>>>(sp, rG + 32, rBt + 32, cS, bc * 32);
        convm_kernel<<<cg16, blk128, 0, stream>>>(Q2, cS, wq + 1 * 18432, Q1, sp);
        gn_finalize_kernel<<<gnblk, 256, 0, stream>>>(sp, rG + 64, rBt + 64, cS, bc * 32);
        convm_kernel<<<cg16, blk128, 0, stream>>>(Q1, cS, wq + 2 * 18432, Q2, sp);
        gn_finalize_kernel<<<gnblk, 256, 0, stream>>>(sp, rG + 96, rBt + 96, cS, bc * 32);
        proj_kernel<<<cg16, blk256, 0, stream>>>(Q2, cS, projR, rnB,
                                                 rpp + (size_t)b0 * 512, E, sw, gauss, 0);
        logits_kernel<<<dim3(bc, 8), blk256, 0, stream>>>(rnB, vnB + (size_t)b0 * 32 * 4608,
                                                          E, sw, gauss,
                                                          lgbuf + (size_t)b0 * 8 * 49);
    }

    head_kernel<<<NB, 128, 0, stream>>>(lgbuf, rpp, vpp, p2s, logT, W1, b1, W2, b2, W3, b3, out);
}

// Round 12
// 959.926 us; speedup vs baseline: 2.5460x; 1.0347x over previous
//
#include <hip/hip_runtime.h>
#include <math.h>

#define HW 4096
#define NB 256

typedef __attribute__((ext_vector_type(8))) short bf16x8_t;
typedef __attribute__((ext_vector_type(16))) float f32x16_t;

// Fast erf-based GELU (A&S 7.1.26, |err| <= 1.5e-7)
__device__ __forceinline__ float gelu_f(float x) {
    float z = x * 0.70710678118654752440f;
    float az = fabsf(z);
    float t = 1.0f / fmaf(0.3275911f, az, 1.0f);
    float p = t * fmaf(t, fmaf(t, fmaf(t, fmaf(t, 1.061405429f, -1.453152027f),
                                       1.421413741f), -0.284496736f), 0.254829592f);
    float e = __expf(-az * az);
    float er = 1.0f - p * e;
    er = copysignf(er, z);
    return 0.5f * x * (1.0f + er);
}
__device__ __forceinline__ unsigned short f2bf(float f) {
    unsigned int u = __float_as_uint(f);
    unsigned int r = u + 0x7FFFu + ((u >> 16) & 1u);
    return (unsigned short)(r >> 16);
}
__device__ __forceinline__ float bf2f(unsigned short h) {
    return __uint_as_float(((unsigned int)h) << 16);
}

// Q layout (PLANAR, single-bf16): Q[b][s][p], s=0..3 = ci-group (8 ch, 16 B).
// Weights split hi/lo (2-term). vn planes edge-padded [c][64][72] bf16.

// ---------------------------------------------------------------------------
__global__ __launch_bounds__(256) void gauss_kernel(float* __restrict__ gauss) {
    __shared__ float sg[HW];
    __shared__ float sR[4];
    int tid = threadIdx.x;
    float part = 0.0f;
    for (int p = tid; p < HW; p += 256) {
        int y = p >> 6, x = p & 63;
        float yy = -1.0f + (2.0f / 63.0f) * (float)y;
        float xx = -1.0f + (2.0f / 63.0f) * (float)x;
        float g = expf(-(yy * yy + xx * xx) * 2.0f);
        sg[p] = g;
        part += g;
    }
#pragma unroll
    for (int off = 32; off > 0; off >>= 1) part += __shfl_down(part, off);
    if ((tid & 63) == 0) sR[tid >> 6] = part;
    __syncthreads();
    float invt = 1.0f / (sR[0] + sR[1] + sR[2] + sR[3]);
    for (int p = tid; p < HW; p += 256) gauss[p] = sg[p] * invt;
}

// ---------------------------------------------------------------------------
// Pack conv weights into MFMA B-fragment order, split bf16 hi/lo.
// i < 110592: layers 1-3 (rubin) / 4-6 (vis), as before.
// 110592..114687: rubin W0 (K=54 pad 64, 4 ksteps x 2 hl x 512).
// 114688..115711: vis W0 (K=9 pad 16, 1 kstep x 2 hl x 512).
// ---------------------------------------------------------------------------
__global__ __launch_bounds__(256) void prep_w_kernel(
    const float* __restrict__ rWs, const float* __restrict__ vWs,
    const float* __restrict__ rW0, const float* __restrict__ vW0,
    unsigned short* __restrict__ wq) {
    int i = blockIdx.x * 256 + threadIdx.x;
    if (i >= 115712) return;
    float wv;
    if (i < 110592) {
        int j = i & 7;
        int lane = (i >> 3) & 63;
        int f = i >> 9;
        int hl = f & 1, k2 = (f >> 1) & 1, tap = (f >> 2) % 9, layer = (f >> 2) / 9;
        int co = lane & 31, hf = lane >> 5;
        int ci = k2 * 16 + hf * 8 + j;
        int ky = tap / 3, kx = tap % 3;
        wv = (layer < 3)
            ? rWs[(((size_t)layer * 32 + co) * 32 + ci) * 9 + ky * 3 + kx]
            : vWs[(((size_t)(layer - 3) * 32 + co) * 32 + ci) * 9 + ky * 3 + kx];
        unsigned short h = f2bf(wv);
        unsigned short l = f2bf(wv - bf2f(h));
        wq[i] = hl ? l : h;
        return;
    }
    int i2 = i - 110592;
    int j = i2 & 7;
    int lane = (i2 >> 3) & 63;
    int co = lane & 31, hf = lane >> 5;
    if (i2 < 4096) {
        int f = i2 >> 9;          // (ks*2+hl)
        int hl = f & 1, ks = f >> 1;
        int q = ks * 16 + hf * 8 + j;
        wv = (q < 54) ? rW0[((size_t)co * 6 + q / 9) * 9 + q % 9] : 0.0f;
        unsigned short h = f2bf(wv);
        unsigned short l = f2bf(wv - bf2f(h));
        wq[i] = hl ? l : h;
    } else {
        int i3 = i2 - 4096;
        int f = i3 >> 9;          // hl
        int q = hf * 8 + j;
        wv = (q < 9) ? vW0[(size_t)co * 9 + q] : 0.0f;
        unsigned short h = f2bf(wv);
        unsigned short l = f2bf(wv - bf2f(h));
        wq[i] = f ? l : h;
    }
}

// ---------------------------------------------------------------------------
// First conv layer via MFMA implicit GEMM over K = CIN*9 (padded to 16*KS).
// Block 128 thr (2 waves), strip of 4 rows; grid (16, bc). Input staged fp32
// in LDS [CIN][6][66] (edge-zero); A-frags gathered at precomputed offsets,
// cvt to bf16 (padded-k weights are 0 -> garbage A harmless). Split-w 2-term.
// Epilogue identical to convm: stats + u16 LDS transpose + planar stores.
// ---------------------------------------------------------------------------
template <int CIN>
__global__ __launch_bounds__(128) void conv_first_m_kernel(
    const float* __restrict__ in, const unsigned short* __restrict__ wq0,
    unsigned short* __restrict__ qout, float* __restrict__ statp) {
    constexpr int KQ = CIN * 9;
    constexpr int KS = (KQ + 15) / 16;
    const int b = blockIdx.y;
    const int strip = blockIdx.x;
    const int tid = threadIdx.x;
    const int wv = tid >> 6;
    const int lane = tid & 63;
    const int m = lane & 31;
    const int hf = lane >> 5;
    const int xh32 = wv * 32;

    __shared__ __align__(16) char smem[20736];  // max(stage 9504, transpose 20480)
    __shared__ float sRed[2][8];
    float* sInF = (float*)smem;

    const int y0 = strip * 4;
    const float* inb = in + (size_t)b * CIN * HW;
    for (int idx = tid; idx < CIN * 6 * 66; idx += 128) {
        int ci = idx / 396;
        int rem = idx - ci * 396;
        int r = rem / 66;
        int col = rem - r * 66;
        int gy = y0 - 1 + r;
        int gx = col - 1;
        float v = 0.0f;
        if (gy >= 0 && gy < 64 && gx >= 0 && gx < 64) v = inb[ci * HW + gy * 64 + gx];
        sInF[ci * 396 + r * 66 + col] = v;
    }

    // per-thread A-gather offsets and weight frags
    int P[KS][8];
#pragma unroll
    for (int ks = 0; ks < KS; ++ks)
#pragma unroll
        for (int j = 0; j < 8; ++j) {
            int q = ks * 16 + hf * 8 + j;
            int ci = q / 9, tap = q - ci * 9;
            int ky = tap / 3, kx = tap - ky * 3;
            P[ks][j] = (q < KQ) ? (ci * 396 + ky * 66 + kx) : 0;
        }
    bf16x8_t Wf[KS][2];
#pragma unroll
    for (int ks = 0; ks < KS; ++ks)
#pragma unroll
        for (int hl = 0; hl < 2; ++hl)
            Wf[ks][hl] = __builtin_bit_cast(
                bf16x8_t, *(const uint4*)(wq0 + (size_t)(ks * 2 + hl) * 512 + lane * 8));
    __syncthreads();

    f32x16_t acc[4];
#pragma unroll
    for (int i = 0; i < 4; ++i)
#pragma unroll
        for (int j = 0; j < 16; ++j) acc[i][j] = 0.0f;

    const int xcol = xh32 + m;
#pragma unroll
    for (int orow = 0; orow < 4; ++orow) {
        const int obase = orow * 66 + xcol;
#pragma unroll
        for (int ks = 0; ks < KS; ++ks) {
            unsigned int pk[4];
#pragma unroll
            for (int e = 0; e < 4; ++e) {
                float v0 = sInF[P[ks][e * 2] + obase];
                float v1 = sInF[P[ks][e * 2 + 1] + obase];
                pk[e] = (unsigned)f2bf(v0) | ((unsigned)f2bf(v1) << 16);
            }
            uint4 u; u.x = pk[0]; u.y = pk[1]; u.z = pk[2]; u.w = pk[3];
            bf16x8_t A = __builtin_bit_cast(bf16x8_t, u);
            acc[orow] = __builtin_amdgcn_mfma_f32_32x32x16_bf16(A, Wf[ks][0], acc[orow], 0, 0, 0);
            acc[orow] = __builtin_amdgcn_mfma_f32_32x32x16_bf16(A, Wf[ks][1], acc[orow], 0, 0, 0);
        }
    }

    // ---- epilogue: stats + u16 LDS transpose + coalesced planar stores
    __syncthreads();
    unsigned short* lds_t = (unsigned short*)smem;  // [256 px][40] u16
    const int co = lane & 31;
    float s1 = 0.0f, s2 = 0.0f;
#pragma unroll
    for (int orow = 0; orow < 4; ++orow) {
#pragma unroll
        for (int r = 0; r < 16; ++r) {
            int mm = (r & 3) + 8 * (r >> 2) + 4 * hf;
            int pxl = (orow << 6) + xh32 + mm;
            float v = acc[orow][r];
            s1 += v;
            s2 = fmaf(v, v, s2);
            lds_t[pxl * 40 + co] = f2bf(v);
        }
    }
    s1 += __shfl_xor(s1, 32); s2 += __shfl_xor(s2, 32);
    s1 += __shfl_xor(s1, 1);  s2 += __shfl_xor(s2, 1);
    s1 += __shfl_xor(s1, 2);  s2 += __shfl_xor(s2, 2);
    s1 += __shfl_xor(s1, 4);  s2 += __shfl_xor(s2, 4);
    if (lane < 32 && (lane & 7) == 0) {
        sRed[wv][co >> 3] = s1;
        sRed[wv][4 + (co >> 3)] = s2;
    }
    __syncthreads();
    if (tid < 8) statp[((size_t)b * 16 + strip) * 8 + tid] = sRed[0][tid] + sRed[1][tid];

    char* qb = (char*)qout + (size_t)b * 4 * HW * 16;
    const int p0 = y0 * 64;
#pragma unroll
    for (int pi = 0; pi < 2; ++pi) {
        int p = pi * 128 + tid;
#pragma unroll
        for (int s = 0; s < 4; ++s) {
            uint4 uh = *(const uint4*)(lds_t + p * 40 + s * 8);
            *(uint4*)(qb + ((size_t)(s * HW) + p0 + p) * 16) = uh;
        }
    }
}

// ---------------------------------------------------------------------------
__global__ __launch_bounds__(256) void gn_finalize_kernel(
    const float* __restrict__ statp, const float* __restrict__ gma,
    const float* __restrict__ bta, float* __restrict__ coef, int n) {
    int i = blockIdx.x * 256 + threadIdx.x;
    if (i >= n) return;
    int b = i >> 5, c = i & 31, g = c >> 3;
    float s1 = 0.0f, s2 = 0.0f;
    for (int s = 0; s < 16; ++s) {
        s1 += statp[((size_t)b * 16 + s) * 8 + g];
        s2 += statp[((size_t)b * 16 + s) * 8 + 4 + g];
    }
    const float invN = 1.0f / 32768.0f;
    float mean = s1 * invN;
    float var = s2 * invN - mean * mean;
    float rstd = rsqrtf(var + 1e-5f);
    float a = rstd * gma[c];
    float bb = bta[c] - mean * a;
    coef[i * 2 + 0] = a;
    coef[i * 2 + 1] = bb;
}

// ---------------------------------------------------------------------------
// MFMA 3x3 conv, fused GN+GELU, single-bf16 x, split-w 2-term. (unchanged)
// ---------------------------------------------------------------------------
#define SLOT 80
#define ROWB (66 * SLOT)
__global__ __launch_bounds__(128) void convm_kernel(
    const unsigned short* __restrict__ qin, const float* __restrict__ coef,
    const unsigned short* __restrict__ wq,
    unsigned short* __restrict__ qout, float* __restrict__ statp) {
    const int b = blockIdx.y;
    const int strip = blockIdx.x;
    const int tid = threadIdx.x;
    const int wv = tid >> 6;
    const int lane = tid & 63;
    const int m = lane & 31;
    const int hf = lane >> 5;
    const int xh32 = wv * 32;

    __shared__ __align__(16) char sQ[6 * ROWB];
    __shared__ float sRed[2][8];
    __shared__ float sc[64];

    const int y0 = strip * 4;
    const char* img = (const char*)qin + (size_t)b * 4 * HW * 16;

    if (tid < 64) sc[tid] = coef[b * 64 + tid];
    if (tid < 48) {
        int r = tid >> 3, side = (tid >> 2) & 1, sub = tid & 3;
        uint4 z; z.x = z.y = z.z = z.w = 0;
        *(uint4*)(sQ + r * ROWB + side * 65 * SLOT + sub * 16) = z;
    }
    __syncthreads();

    const int px = tid & 63;
    const int rot = px & 3;
    float ca[2][8], cb[2][8];
#pragma unroll
    for (int k = 0; k < 2; ++k) {
        int s = k * 2 + wv;
#pragma unroll
        for (int e = 0; e < 8; ++e) {
            ca[k][e] = sc[(s * 8 + e) * 2 + 0];
            cb[k][e] = sc[(s * 8 + e) * 2 + 1];
        }
    }
    char* dstp = sQ + (px + 1) * SLOT;
#pragma unroll
    for (int r = 0; r < 6; ++r) {
        int gy = y0 - 1 + r;
        int gp = gy * 64 + px;
        char* dst = dstp + r * ROWB;
#pragma unroll
        for (int k = 0; k < 2; ++k) {
            int s = k * 2 + wv;
            uint4 oh;
            if (gy >= 0 && gy < 64) {
                uint4 uhv = *(const uint4*)(img + ((size_t)(s * HW) + gp) * 16);
                unsigned int hd[4] = {uhv.x, uhv.y, uhv.z, uhv.w};
                unsigned int ho[4];
#pragma unroll
                for (int e = 0; e < 4; ++e) {
                    float x0 = bf2f((unsigned short)(hd[e] & 0xFFFF));
                    float x1 = bf2f((unsigned short)(hd[e] >> 16));
                    float y0v = gelu_f(fmaf(ca[k][e * 2], x0, cb[k][e * 2]));
                    float y1v = gelu_f(fmaf(ca[k][e * 2 + 1], x1, cb[k][e * 2 + 1]));
                    ho[e] = (unsigned)f2bf(y0v) | ((unsigned)f2bf(y1v) << 16);
                }
                oh.x = ho[0]; oh.y = ho[1]; oh.z = ho[2]; oh.w = ho[3];
            } else {
                oh.x = oh.y = oh.z = oh.w = 0;
            }
            *(uint4*)(dst + ((s + rot) & 3) * 16) = oh;
        }
    }
    __syncthreads();

    f32x16_t acc[4];
#pragma unroll
    for (int i = 0; i < 4; ++i)
#pragma unroll
        for (int j = 0; j < 16; ++j) acc[i][j] = 0.0f;

    for (int kx = 0; kx < 3; ++kx) {
        bf16x8_t Wf[3][2][2];
#pragma unroll
        for (int ky = 0; ky < 3; ++ky)
#pragma unroll
            for (int k2 = 0; k2 < 2; ++k2)
#pragma unroll
                for (int hl = 0; hl < 2; ++hl) {
                    int fi = ((ky * 3 + kx) * 2 + k2) * 2 + hl;
                    Wf[ky][k2][hl] = __builtin_bit_cast(
                        bf16x8_t, *(const uint4*)(wq + (size_t)fi * 512 + lane * 8));
                }
        const int slotb = xh32 + kx + m;
        const int prot = (m + kx + 3) & 3;
#pragma unroll
        for (int li = 0; li < 6; ++li) {
            const char* rowp = sQ + li * ROWB + slotb * SLOT;
            bf16x8_t Ah[2];
#pragma unroll
            for (int k2 = 0; k2 < 2; ++k2) {
                int s = k2 * 2 + hf;
                Ah[k2] = __builtin_bit_cast(bf16x8_t, *(const uint4*)(rowp + ((s + prot) & 3) * 16));
            }
#pragma unroll
            for (int ky = 0; ky < 3; ++ky) {
                int orow = li - ky;
                if (orow < 0 || orow > 3) continue;
#pragma unroll
                for (int k2 = 0; k2 < 2; ++k2) {
                    acc[orow] = __builtin_amdgcn_mfma_f32_32x32x16_bf16(Ah[k2], Wf[ky][k2][0], acc[orow], 0, 0, 0);
                    acc[orow] = __builtin_amdgcn_mfma_f32_32x32x16_bf16(Ah[k2], Wf[ky][k2][1], acc[orow], 0, 0, 0);
                }
            }
        }
    }

    __syncthreads();
    unsigned short* lds_t = (unsigned short*)sQ;
    const int co = lane & 31;
    float s1 = 0.0f, s2 = 0.0f;
#pragma unroll
    for (int orow = 0; orow < 4; ++orow) {
#pragma unroll
        for (int r = 0; r < 16; ++r) {
            int mm = (r & 3) + 8 * (r >> 2) + 4 * hf;
            int pxl = (orow << 6) + xh32 + mm;
            float v = acc[orow][r];
            s1 += v;
            s2 = fmaf(v, v, s2);
            lds_t[pxl * 40 + co] = f2bf(v);
        }
    }
    s1 += __shfl_xor(s1, 32); s2 += __shfl_xor(s2, 32);
    s1 += __shfl_xor(s1, 1);  s2 += __shfl_xor(s2, 1);
    s1 += __shfl_xor(s1, 2);  s2 += __shfl_xor(s2, 2);
    s1 += __shfl_xor(s1, 4);  s2 += __shfl_xor(s2, 4);
    if (lane < 32 && (lane & 7) == 0) {
        sRed[wv][co >> 3] = s1;
        sRed[wv][4 + (co >> 3)] = s2;
    }
    __syncthreads();
    if (tid < 8) statp[((size_t)b * 16 + strip) * 8 + tid] = sRed[0][tid] + sRed[1][tid];

    char* qb = (char*)qout + (size_t)b * 4 * HW * 16;
    const int p0 = y0 * 64;
#pragma unroll
    for (int pi = 0; pi < 2; ++pi) {
        int p = pi * 128 + tid;
#pragma unroll
        for (int s = 0; s < 4; ++s) {
            uint4 uh = *(const uint4*)(lds_t + p * 40 + s * 8);
            *(uint4*)(qb + ((size_t)(s * HW) + p0 + p) * 16) = uh;
        }
    }
}

// ---------------------------------------------------------------------------
// Projection + l2norm + fused gauss-pool partials. (unchanged)
// ---------------------------------------------------------------------------
__global__ __launch_bounds__(256) void proj_kernel(
    const unsigned short* __restrict__ q, const float* __restrict__ coef,
    const float* __restrict__ pw, unsigned short* __restrict__ outn,
    float* __restrict__ poolp, float* __restrict__ E, float* __restrict__ swp,
    const float* __restrict__ gauss, int vpad) {
    int b = blockIdx.y, chunk = blockIdx.x, tid = threadIdx.x;
    int p = chunk * 256 + tid;
    __shared__ float sR[4];
    __shared__ float sc[64];
    __shared__ float red[32][257];
    if (tid < 64) sc[tid] = coef[b * 64 + tid];
    __syncthreads();
    float feat[32];
    {
        const char* qb = (const char*)q + (size_t)b * 4 * HW * 16;
#pragma unroll
        for (int s = 0; s < 4; ++s) {
            uint4 uh = *(const uint4*)(qb + ((size_t)(s * HW) + p) * 16);
            unsigned int hd[4] = {uh.x, uh.y, uh.z, uh.w};
#pragma unroll
            for (int e = 0; e < 4; ++e) {
                int c0 = s * 8 + e * 2;
                float x0 = bf2f((unsigned short)(hd[e] & 0xFFFF));
                float x1 = bf2f((unsigned short)(hd[e] >> 16));
                feat[c0] = gelu_f(fmaf(sc[c0 * 2], x0, sc[c0 * 2 + 1]));
                feat[c0 + 1] = gelu_f(fmaf(sc[(c0 + 1) * 2], x1, sc[(c0 + 1) * 2 + 1]));
            }
        }
    }
    float g = gauss[p];
#pragma unroll
    for (int c = 0; c < 32; ++c) red[c][tid] = feat[c] * g;

    float o[32];
#pragma unroll
    for (int oo = 0; oo < 32; ++oo) o[oo] = 0.0f;
    for (int c = 0; c < 32; ++c) {
        float f = feat[c];
#pragma unroll
        for (int oo = 0; oo < 32; ++oo) o[oo] = fmaf(pw[oo * 32 + c], f, o[oo]);
    }
    float nn = 0.0f;
#pragma unroll
    for (int oo = 0; oo < 32; ++oo) nn = fmaf(o[oo], o[oo], nn);
    float n = sqrtf(nn);
    float inv = 1.0f / fmaxf(n, 1e-6f);
    if (vpad) {
        int y = p >> 6, x = p & 63;
        unsigned short* vb_ = outn + (size_t)b * 32 * 4608 + y * 72 + x + 4;
#pragma unroll
        for (int oo = 0; oo < 32; ++oo) {
            unsigned short hv = f2bf(o[oo] * inv);
            unsigned short* row = vb_ + (size_t)oo * 4608;
            row[0] = hv;
            if (x == 0) { row[-4] = hv; row[-3] = hv; row[-2] = hv; row[-1] = hv; }
            if (x == 63) { row[1] = hv; row[2] = hv; row[3] = hv; row[4] = hv; }
        }
    } else {
        unsigned short* obp = outn + (size_t)b * 32 * HW + p;
#pragma unroll
        for (int oo = 0; oo < 32; ++oo) obp[(size_t)oo * HW] = f2bf(o[oo] * inv);
    }

    __syncthreads();
    if (tid < 32) {
        float s = 0.0f;
#pragma unroll 8
        for (int i = 0; i < 256; ++i) s += red[tid][i];
        poolp[((size_t)b * 16 + chunk) * 32 + tid] = s;
    }

    if (E != nullptr) {
        float e = nn * inv * inv;
        E[(size_t)b * HW + p] = e;
        float wvv = e * g;
#pragma unroll
        for (int off = 32; off > 0; off >>= 1) wvv += __shfl_down(wvv, off);
        if ((tid & 63) == 0) sR[tid >> 6] = wvv;
        __syncthreads();
        if (tid == 0) swp[b * 16 + chunk] = sR[0] + sR[1] + sR[2] + sR[3];
    }
}

// ---------------------------------------------------------------------------
// 49-offset correlation logits. (unchanged)
// ---------------------------------------------------------------------------
__global__ __launch_bounds__(256) void logits_kernel(
    const unsigned short* __restrict__ rn, const unsigned short* __restrict__ vnp,
    const float* __restrict__ E, const float* __restrict__ swp,
    const float* __restrict__ gauss, float* __restrict__ lgpart) {
    int b = blockIdx.x, cg = blockIdx.y, tid = threadIdx.x;
    __shared__ float sR[4][49];
    float acc[49];
#pragma unroll
    for (int k = 0; k < 49; ++k) acc[k] = 0.0f;
    float ssum = 0.0f;
#pragma unroll
    for (int i = 0; i < 16; ++i) ssum += swp[b * 16 + i];
    const float scale = 0.17677669529663688f / (ssum + 1e-8f);
    const int x0 = (tid & 7) * 8;
    const float* Eb = E + (size_t)b * HW;
#pragma unroll 1
    for (int half = 0; half < 2; ++half) {
        const int y = half * 32 + (tid >> 3);
        const int pbase = y * 64 + x0;
        float4 e0 = *(const float4*)(Eb + pbase);
        float4 e1 = *(const float4*)(Eb + pbase + 4);
        float4 g0 = *(const float4*)(gauss + pbase);
        float4 g1 = *(const float4*)(gauss + pbase + 4);
        float qw[8];
        qw[0] = e0.x * g0.x * scale; qw[1] = e0.y * g0.y * scale;
        qw[2] = e0.z * g0.z * scale; qw[3] = e0.w * g0.w * scale;
        qw[4] = e1.x * g1.x * scale; qw[5] = e1.y * g1.y * scale;
        qw[6] = e1.z * g1.z * scale; qw[7] = e1.w * g1.w * scale;
#pragma unroll 1
        for (int cc = 0; cc < 4; ++cc) {
            int c = cg * 4 + cc;
            const unsigned short* rb = rn + ((size_t)b * 32 + c) * HW;
            uint4 rv = *(const uint4*)(rb + pbase);
            unsigned int rd[4] = {rv.x, rv.y, rv.z, rv.w};
            float r_[8];
            r_[0] = bf2f((unsigned short)(rd[0] & 0xFFFF)) * qw[0];
            r_[1] = bf2f((unsigned short)(rd[0] >> 16)) * qw[1];
            r_[2] = bf2f((unsigned short)(rd[1] & 0xFFFF)) * qw[2];
            r_[3] = bf2f((unsigned short)(rd[1] >> 16)) * qw[3];
            r_[4] = bf2f((unsigned short)(rd[2] & 0xFFFF)) * qw[4];
            r_[5] = bf2f((unsigned short)(rd[2] >> 16)) * qw[5];
            r_[6] = bf2f((unsigned short)(rd[3] & 0xFFFF)) * qw[6];
            r_[7] = bf2f((unsigned short)(rd[3] >> 16)) * qw[7];
            const unsigned short* vplane = vnp + ((size_t)b * 32 + c) * 4608;
#pragma unroll
            for (int dy = 0; dy < 7; ++dy) {
                int ry = y + dy - 3;
                ry = ry < 0 ? 0 : (ry > 63 ? 63 : ry);
                const unsigned short* vp = vplane + ry * 72 + x0;
                uint4 va = *(const uint4*)vp;
                uint4 vb2 = *(const uint4*)(vp + 8);
                unsigned int vd[8] = {va.x, va.y, va.z, va.w, vb2.x, vb2.y, vb2.z, vb2.w};
                float v[16];
#pragma unroll
                for (int j2 = 0; j2 < 8; ++j2) {
                    v[j2 * 2] = bf2f((unsigned short)(vd[j2] & 0xFFFF));
                    v[j2 * 2 + 1] = bf2f((unsigned short)(vd[j2] >> 16));
                }
#pragma unroll
                for (int dx = 0; dx < 7; ++dx)
#pragma unroll
                    for (int j = 0; j < 8; ++j)
                        acc[dy * 7 + dx] = fmaf(r_[j], v[j + dx + 1], acc[dy * 7 + dx]);
            }
        }
    }
#pragma unroll
    for (int k = 0; k < 49; ++k) {
#pragma unroll
        for (int off = 32; off > 0; off >>= 1) acc[k] += __shfl_down(acc[k], off);
    }
    int wid = tid >> 6;
    if ((tid & 63) == 0) {
#pragma unroll
        for (int k = 0; k < 49; ++k) sR[wid][k] = acc[k];
    }
    __syncthreads();
    if (tid < 49)
        lgpart[((size_t)b * 8 + cg) * 49 + tid] =
            sR[0][tid] + sR[1][tid] + sR[2][tid] + sR[3][tid];
}

// ---------------------------------------------------------------------------
__global__ __launch_bounds__(128) void head_kernel(
    const float* __restrict__ lg, const float* __restrict__ rpp,
    const float* __restrict__ vpp, const float* __restrict__ p2s,
    const float* __restrict__ log_temp,
    const float* __restrict__ W1, const float* __restrict__ b1,
    const float* __restrict__ W2, const float* __restrict__ b2,
    const float* __restrict__ W3, const float* __restrict__ b3,
    float* __restrict__ out) {
    int b = blockIdx.x, t = threadIdx.x;
    __shared__ float slg[49];
    __shared__ float pooled[98];
    __shared__ float h1[128], h2[128];
    __shared__ float cxy[2];
    __shared__ float res[3];
    const float* lgp = lg + (size_t)b * 8 * 49;
    if (t < 49) {
        float s = 0.0f;
#pragma unroll
        for (int g = 0; g < 8; ++g) s += lgp[g * 49 + t];
        slg[t] = s;
    }
    __syncthreads();
    if (t == 0) {
        float temp = fmaxf(expf(log_temp[0]), 0.001f);
        float invT = 1.0f / temp;
        float m = -1e30f;
        for (int k = 0; k < 49; ++k) m = fmaxf(m, slg[k] * invT);
        float s = 0.0f, pdx = 0.0f, pdy = 0.0f;
        for (int k = 0; k < 49; ++k) {
            float e = expf(slg[k] * invT - m);
            s += e;
            pdx += e * (float)((k % 7) - 3);
            pdy += e * (float)((k / 7) - 3);
        }
        cxy[0] = pdx / s;
        cxy[1] = pdy / s;
    }
    __syncthreads();
    if (t < 32) {
        float a = 0.0f, c = 0.0f;
#pragma unroll
        for (int k = 0; k < 16; ++k) {
            a += rpp[((size_t)b * 16 + k) * 32 + t];
            c += vpp[((size_t)b * 16 + k) * 32 + t];
        }
        pooled[t] = a;
        pooled[32 + t] = c;
        pooled[64 + t] = a - c;
    }
    if (t == 0) {
        pooled[96] = cxy[0];
        pooled[97] = cxy[1];
    }
    __syncthreads();
    float s1 = b1[t];
    for (int i = 0; i < 98; ++i) s1 = fmaf(pooled[i], W1[i * 128 + t], s1);
    h1[t] = gelu_f(s1);
    __syncthreads();
    float s2 = b2[t];
    for (int i = 0; i < 128; ++i) s2 = fmaf(h1[i], W2[i * 128 + t], s2);
    h2[t] = gelu_f(s2);
    __syncthreads();
    if (t < 3) {
        float r = b3[t];
        for (int i = 0; i < 128; ++i) r = fmaf(h2[i], W3[i * 3 + t], r);
        res[t] = r;
    }
    __syncthreads();
    if (t == 0) {
        float dxp = cxy[0] + res[0];
        float dyp = cxy[1] + res[1];
        float ls = fminf(fmaxf(res[2], -6.0f), 3.0f);
        const float* M = p2s + b * 4;
        float* ob = out + b * 54;
        ob[0] = dxp;
        ob[1] = dyp;
        ob[2] = M[0] * dxp + M[1] * dyp;
        ob[3] = M[2] * dxp + M[3] * dyp;
        ob[4] = ls;
    }
    if (t < 49) out[b * 54 + 5 + t] = slg[t];
}

extern "C" void kernel_launch(void* const* d_in, const int* in_sizes, int n_in,
                              void* d_out, int out_size, void* d_ws, size_t ws_size,
                              hipStream_t stream) {
    (void)in_sizes; (void)n_in; (void)out_size;
    const float* rubin = (const float*)d_in[0];
    const float* vis   = (const float*)d_in[1];
    const float* p2s   = (const float*)d_in[2];
    const float* rW0   = (const float*)d_in[3];
    const float* rWs   = (const float*)d_in[4];
    const float* rG    = (const float*)d_in[5];
    const float* rBt   = (const float*)d_in[6];
    const float* vW0   = (const float*)d_in[7];
    const float* vWs   = (const float*)d_in[8];
    const float* vG    = (const float*)d_in[9];
    const float* vBt   = (const float*)d_in[10];
    const float* projR = (const float*)d_in[11];
    const float* projV = (const float*)d_in[12];
    const float* logT  = (const float*)d_in[13];
    const float* W1    = (const float*)d_in[14];
    const float* b1    = (const float*)d_in[15];
    const float* W2    = (const float*)d_in[16];
    const float* b2    = (const float*)d_in[17];
    const float* W3    = (const float*)d_in[18];
    const float* b3    = (const float*)d_in[19];
    float* out = (float*)d_out;

    // ---- workspace layout (bytes)
    char* ws = (char*)d_ws;
    size_t off = 0;
    unsigned short* vnB = (unsigned short*)(ws + off); off += (size_t)NB * 32 * 4608 * 2;
    float* gauss  = (float*)(ws + off); off += HW * 4;
    float* statp  = (float*)(ws + off); off += (size_t)NB * 16 * 8 * 4;
    float* coefS  = (float*)(ws + off); off += (size_t)NB * 64 * 4;
    float* swp    = (float*)(ws + off); off += (size_t)NB * 16 * 4;
    float* rpp    = (float*)(ws + off); off += (size_t)NB * 16 * 32 * 4;
    float* vpp    = (float*)(ws + off); off += (size_t)NB * 16 * 32 * 4;
    float* lgbuf  = (float*)(ws + off); off += (size_t)NB * 8 * 49 * 4;
    unsigned short* wq = (unsigned short*)(ws + off); off += 115712ull * 2;
    off = (off + 255) & ~(size_t)255;
    const size_t fixed_bytes = off;
    const size_t perb = 2ull * HW * 64 + HW * 4;
    int BC = 1;
    if (ws_size > fixed_bytes + perb) {
        size_t t = (ws_size - fixed_bytes) / perb;
        BC = t > (size_t)NB ? NB : (int)t;
    }
    unsigned short* Q1 = (unsigned short*)(ws + off);
    unsigned short* Q2 = (unsigned short*)(ws + off + (size_t)BC * HW * 64);
    float* E = (float*)(ws + off + 2ull * BC * HW * 64);
    unsigned short* wq0r = wq + 110592;
    unsigned short* wq0v = wq + 114688;

    dim3 blk256(256), blk128(128);
    gauss_kernel<<<1, 256, 0, stream>>>(gauss);
    prep_w_kernel<<<452, 256, 0, stream>>>(rWs, vWs, rW0, vW0, wq);

    // ================= VIS encoder (all chunks) =================
    for (int b0 = 0; b0 < NB; b0 += BC) {
        const int bc = (NB - b0) < BC ? (NB - b0) : BC;
        dim3 cg16(16, bc);
        const int gnblk = (bc * 32 + 255) / 256;
        float* sp = statp + (size_t)b0 * 128;
        float* cS = coefS + (size_t)b0 * 64;

        conv_first_m_kernel<1><<<cg16, blk128, 0, stream>>>(vis + (size_t)b0 * HW, wq0v, Q1, sp);
        gn_finalize_kernel<<<gnblk, 256, 0, stream>>>(sp, vG + 0, vBt + 0, cS, bc * 32);
        convm_kernel<<<cg16, blk128, 0, stream>>>(Q1, cS, wq + 3 * 18432, Q2, sp);
        gn_finalize_kernel<<<gnblk, 256, 0, stream>>>(sp, vG + 32, vBt + 32, cS, bc * 32);
        convm_kernel<<<cg16, blk128, 0, stream>>>(Q2, cS, wq + 4 * 18432, Q1, sp);
        gn_finalize_kernel<<<gnblk, 256, 0, stream>>>(sp, vG + 64, vBt + 64, cS, bc * 32);
        convm_kernel<<<cg16, blk128, 0, stream>>>(Q1, cS, wq + 5 * 18432, Q2, sp);
        gn_finalize_kernel<<<gnblk, 256, 0, stream>>>(sp, vG + 96, vBt + 96, cS, bc * 32);
        proj_kernel<<<cg16, blk256, 0, stream>>>(Q2, cS, projV, vnB + (size_t)b0 * 32 * 4608,
                                                 vpp + (size_t)b0 * 512,
                                                 (float*)nullptr, (float*)nullptr, gauss, 1);
    }

    // ================= RUBIN encoder + logits (all chunks) =================
    for (int b0 = 0; b0 < NB; b0 += BC) {
        const int bc = (NB - b0) < BC ? (NB - b0) : BC;
        dim3 cg16(16, bc);
        const int gnblk = (bc * 32 + 255) / 256;
        float* sp = statp + (size_t)b0 * 128;
        float* cS = coefS + (size_t)b0 * 64;
        float* sw = swp + (size_t)b0 * 16;
        unsigned short* rnB = Q1;

        conv_first_m_kernel<6><<<cg16, blk128, 0, stream>>>(rubin + (size_t)b0 * 6 * HW, wq0r, Q1, sp);
        gn_finalize_kernel<<<gnblk, 256, 0, stream>>>(sp, rG + 0, rBt + 0, cS, bc * 32);
        convm_kernel<<<cg16, blk128, 0, stream>>>(Q1, cS, wq + 0 * 18432, Q2, sp);
        gn_finalize_kernel<<<gnblk, 256, 0, stream>>>(sp, rG + 32, rBt + 32, cS, bc * 32);
        convm_kernel<<<cg16, blk128, 0, stream>>>(Q2, cS, wq + 1 * 18432, Q1, sp);
        gn_finalize_kernel<<<gnblk, 256, 0, stream>>>(sp, rG + 64, rBt + 64, cS, bc * 32);
        convm_kernel<<<cg16, blk128, 0, stream>>>(Q1, cS, wq + 2 * 18432, Q2, sp);
        gn_finalize_kernel<<<gnblk, 256, 0, stream>>>(sp, rG + 96, rBt + 96, cS, bc * 32);
        proj_kernel<<<cg16, blk256, 0, stream>>>(Q2, cS, projR, rnB,
                                                 rpp + (size_t)b0 * 512, E, sw, gauss, 0);
        logits_kernel<<<dim3(bc, 8), blk256, 0, stream>>>(rnB, vnB + (size_t)b0 * 32 * 4608,
                                                          E, sw, gauss,
                                                          lgbuf + (size_t)b0 * 8 * 49);
    }

    head_kernel<<<NB, 128, 0, stream>>>(lgbuf, rpp, vpp, p2s, logT, W1, b1, W2, b2, W3, b3, out);
}

// Round 13
// 760.025 us; speedup vs baseline: 3.2156x; 1.2630x over previous
//
#include <hip/hip_runtime.h>
#include <math.h>

#define HW 4096
#define NB 256

typedef __attribute__((ext_vector_type(8))) short bf16x8_t;
typedef __attribute__((ext_vector_type(16))) float f32x16_t;

// Fast erf-based GELU (A&S 7.1.26, |err| <= 1.5e-7)
__device__ __forceinline__ float gelu_f(float x) {
    float z = x * 0.70710678118654752440f;
    float az = fabsf(z);
    float t = 1.0f / fmaf(0.3275911f, az, 1.0f);
    float p = t * fmaf(t, fmaf(t, fmaf(t, fmaf(t, 1.061405429f, -1.453152027f),
                                       1.421413741f), -0.284496736f), 0.254829592f);
    float e = __expf(-az * az);
    float er = 1.0f - p * e;
    er = copysignf(er, z);
    return 0.5f * x * (1.0f + er);
}
__device__ __forceinline__ unsigned short f2bf(float f) {
    unsigned int u = __float_as_uint(f);
    unsigned int r = u + 0x7FFFu + ((u >> 16) & 1u);
    return (unsigned short)(r >> 16);
}
__device__ __forceinline__ float bf2f(unsigned short h) {
    return __uint_as_float(((unsigned int)h) << 16);
}

// Q layout (PLANAR, single-bf16): Q[b][s][p], s=0..3 = ci-group (8 ch, 16 B).
// convm weights single-bf16 (hi only); conv_first weights split hi/lo.
// vn planes edge-padded [c][64][72] bf16.

// ---------------------------------------------------------------------------
__global__ __launch_bounds__(256) void gauss_kernel(float* __restrict__ gauss) {
    __shared__ float sg[HW];
    __shared__ float sR[4];
    int tid = threadIdx.x;
    float part = 0.0f;
    for (int p = tid; p < HW; p += 256) {
        int y = p >> 6, x = p & 63;
        float yy = -1.0f + (2.0f / 63.0f) * (float)y;
        float xx = -1.0f + (2.0f / 63.0f) * (float)x;
        float g = expf(-(yy * yy + xx * xx) * 2.0f);
        sg[p] = g;
        part += g;
    }
#pragma unroll
    for (int off = 32; off > 0; off >>= 1) part += __shfl_down(part, off);
    if ((tid & 63) == 0) sR[tid >> 6] = part;
    __syncthreads();
    float invt = 1.0f / (sR[0] + sR[1] + sR[2] + sR[3]);
    for (int p = tid; p < HW; p += 256) gauss[p] = sg[p] * invt;
}

// ---------------------------------------------------------------------------
// Pack conv weights into MFMA B-fragment order.
// i < 110592: layers 1-3 rubin / 4-6 vis, frag ((ky3+kx)*2+k2)*2+hl (hl kept
// for layout compat; convm reads hl=0 only).
// 110592..114687: rubin W0 (K=54 pad 64); 114688..115711: vis W0 (K=9 pad 16).
// ---------------------------------------------------------------------------
__global__ __launch_bounds__(256) void prep_w_kernel(
    const float* __restrict__ rWs, const float* __restrict__ vWs,
    const float* __restrict__ rW0, const float* __restrict__ vW0,
    unsigned short* __restrict__ wq) {
    int i = blockIdx.x * 256 + threadIdx.x;
    if (i >= 115712) return;
    float wv;
    if (i < 110592) {
        int j = i & 7;
        int lane = (i >> 3) & 63;
        int f = i >> 9;
        int hl = f & 1, k2 = (f >> 1) & 1, tap = (f >> 2) % 9, layer = (f >> 2) / 9;
        int co = lane & 31, hf = lane >> 5;
        int ci = k2 * 16 + hf * 8 + j;
        int ky = tap / 3, kx = tap % 3;
        wv = (layer < 3)
            ? rWs[(((size_t)layer * 32 + co) * 32 + ci) * 9 + ky * 3 + kx]
            : vWs[(((size_t)(layer - 3) * 32 + co) * 32 + ci) * 9 + ky * 3 + kx];
        unsigned short h = f2bf(wv);
        unsigned short l = f2bf(wv - bf2f(h));
        wq[i] = hl ? l : h;
        return;
    }
    int i2 = i - 110592;
    int j = i2 & 7;
    int lane = (i2 >> 3) & 63;
    int co = lane & 31, hf = lane >> 5;
    if (i2 < 4096) {
        int f = i2 >> 9;
        int hl = f & 1, ks = f >> 1;
        int q = ks * 16 + hf * 8 + j;
        wv = (q < 54) ? rW0[((size_t)co * 6 + q / 9) * 9 + q % 9] : 0.0f;
        unsigned short h = f2bf(wv);
        unsigned short l = f2bf(wv - bf2f(h));
        wq[i] = hl ? l : h;
    } else {
        int i3 = i2 - 4096;
        int f = i3 >> 9;
        int q = hf * 8 + j;
        wv = (q < 9) ? vW0[(size_t)co * 9 + q] : 0.0f;
        unsigned short h = f2bf(wv);
        unsigned short l = f2bf(wv - bf2f(h));
        wq[i] = f ? l : h;
    }
}

// ---------------------------------------------------------------------------
// First conv layer via MFMA implicit GEMM (unchanged; split-w 2-term).
// ---------------------------------------------------------------------------
template <int CIN>
__global__ __launch_bounds__(128) void conv_first_m_kernel(
    const float* __restrict__ in, const unsigned short* __restrict__ wq0,
    unsigned short* __restrict__ qout, float* __restrict__ statp) {
    constexpr int KQ = CIN * 9;
    constexpr int KS = (KQ + 15) / 16;
    const int b = blockIdx.y;
    const int strip = blockIdx.x;
    const int tid = threadIdx.x;
    const int wv = tid >> 6;
    const int lane = tid & 63;
    const int m = lane & 31;
    const int hf = lane >> 5;
    const int xh32 = wv * 32;

    __shared__ __align__(16) char smem[20736];
    __shared__ float sRed[2][8];
    float* sInF = (float*)smem;

    const int y0 = strip * 4;
    const float* inb = in + (size_t)b * CIN * HW;
    for (int idx = tid; idx < CIN * 6 * 66; idx += 128) {
        int ci = idx / 396;
        int rem = idx - ci * 396;
        int r = rem / 66;
        int col = rem - r * 66;
        int gy = y0 - 1 + r;
        int gx = col - 1;
        float v = 0.0f;
        if (gy >= 0 && gy < 64 && gx >= 0 && gx < 64) v = inb[ci * HW + gy * 64 + gx];
        sInF[ci * 396 + r * 66 + col] = v;
    }

    int P[KS][8];
#pragma unroll
    for (int ks = 0; ks < KS; ++ks)
#pragma unroll
        for (int j = 0; j < 8; ++j) {
            int q = ks * 16 + hf * 8 + j;
            int ci = q / 9, tap = q - ci * 9;
            int ky = tap / 3, kx = tap - ky * 3;
            P[ks][j] = (q < KQ) ? (ci * 396 + ky * 66 + kx) : 0;
        }
    bf16x8_t Wf[KS][2];
#pragma unroll
    for (int ks = 0; ks < KS; ++ks)
#pragma unroll
        for (int hl = 0; hl < 2; ++hl)
            Wf[ks][hl] = __builtin_bit_cast(
                bf16x8_t, *(const uint4*)(wq0 + (size_t)(ks * 2 + hl) * 512 + lane * 8));
    __syncthreads();

    f32x16_t acc[4];
#pragma unroll
    for (int i = 0; i < 4; ++i)
#pragma unroll
        for (int j = 0; j < 16; ++j) acc[i][j] = 0.0f;

    const int xcol = xh32 + m;
#pragma unroll
    for (int orow = 0; orow < 4; ++orow) {
        const int obase = orow * 66 + xcol;
#pragma unroll
        for (int ks = 0; ks < KS; ++ks) {
            unsigned int pk[4];
#pragma unroll
            for (int e = 0; e < 4; ++e) {
                float v0 = sInF[P[ks][e * 2] + obase];
                float v1 = sInF[P[ks][e * 2 + 1] + obase];
                pk[e] = (unsigned)f2bf(v0) | ((unsigned)f2bf(v1) << 16);
            }
            uint4 u; u.x = pk[0]; u.y = pk[1]; u.z = pk[2]; u.w = pk[3];
            bf16x8_t A = __builtin_bit_cast(bf16x8_t, u);
            acc[orow] = __builtin_amdgcn_mfma_f32_32x32x16_bf16(A, Wf[ks][0], acc[orow], 0, 0, 0);
            acc[orow] = __builtin_amdgcn_mfma_f32_32x32x16_bf16(A, Wf[ks][1], acc[orow], 0, 0, 0);
        }
    }

    __syncthreads();
    unsigned short* lds_t = (unsigned short*)smem;
    const int co = lane & 31;
    float s1 = 0.0f, s2 = 0.0f;
#pragma unroll
    for (int orow = 0; orow < 4; ++orow) {
#pragma unroll
        for (int r = 0; r < 16; ++r) {
            int mm = (r & 3) + 8 * (r >> 2) + 4 * hf;
            int pxl = (orow << 6) + xh32 + mm;
            float v = acc[orow][r];
            s1 += v;
            s2 = fmaf(v, v, s2);
            lds_t[pxl * 40 + co] = f2bf(v);
        }
    }
    s1 += __shfl_xor(s1, 32); s2 += __shfl_xor(s2, 32);
    s1 += __shfl_xor(s1, 1);  s2 += __shfl_xor(s2, 1);
    s1 += __shfl_xor(s1, 2);  s2 += __shfl_xor(s2, 2);
    s1 += __shfl_xor(s1, 4);  s2 += __shfl_xor(s2, 4);
    if (lane < 32 && (lane & 7) == 0) {
        sRed[wv][co >> 3] = s1;
        sRed[wv][4 + (co >> 3)] = s2;
    }
    __syncthreads();
    if (tid < 8) statp[((size_t)b * 16 + strip) * 8 + tid] = sRed[0][tid] + sRed[1][tid];

    char* qb = (char*)qout + (size_t)b * 4 * HW * 16;
    const int p0 = y0 * 64;
#pragma unroll
    for (int pi = 0; pi < 2; ++pi) {
        int p = pi * 128 + tid;
#pragma unroll
        for (int s = 0; s < 4; ++s) {
            uint4 uh = *(const uint4*)(lds_t + p * 40 + s * 8);
            *(uint4*)(qb + ((size_t)(s * HW) + p0 + p) * 16) = uh;
        }
    }
}

// ---------------------------------------------------------------------------
// GN finalize over ns strips.
// ---------------------------------------------------------------------------
__global__ __launch_bounds__(256) void gn_finalize_kernel(
    const float* __restrict__ statp, const float* __restrict__ gma,
    const float* __restrict__ bta, float* __restrict__ coef, int n, int ns) {
    int i = blockIdx.x * 256 + threadIdx.x;
    if (i >= n) return;
    int b = i >> 5, c = i & 31, g = c >> 3;
    float s1 = 0.0f, s2 = 0.0f;
    for (int s = 0; s < ns; ++s) {
        s1 += statp[((size_t)b * 16 + s) * 8 + g];
        s2 += statp[((size_t)b * 16 + s) * 8 + 4 + g];
    }
    const float invN = 1.0f / 32768.0f;
    float mean = s1 * invN;
    float var = s2 * invN - mean * mean;
    float rstd = rsqrtf(var + 1e-5f);
    float a = rstd * gma[c];
    float bb = bta[c] - mean * a;
    coef[i * 2 + 0] = a;
    coef[i * 2 + 1] = bb;
}

// ---------------------------------------------------------------------------
// MFMA 3x3 conv, fused GN+GELU, single-bf16 x AND w. 8-row strips, 256 thr
// (4 waves: rq = wv&1 row-quad, xh = wv>>1 x-half). LDS: 10 rows x 66 slots
// x 80 B = 52.8 KB -> 3 blocks/CU = 12 waves. Staging: wave owns sub-block
// s = tid>>6 (coefs wave-uniform), thread owns pixel; 10-row register
// prefetch then gelu/pack/LDS-store. 72 MFMAs/wave.
// ---------------------------------------------------------------------------
#define SLOT 80
#define ROWB (66 * SLOT)
__global__ __launch_bounds__(256) void convm_kernel(
    const unsigned short* __restrict__ qin, const float* __restrict__ coef,
    const unsigned short* __restrict__ wq,
    unsigned short* __restrict__ qout, float* __restrict__ statp) {
    const int b = blockIdx.y;
    const int strip = blockIdx.x;
    const int tid = threadIdx.x;
    const int wv = tid >> 6;
    const int lane = tid & 63;
    const int m = lane & 31;
    const int hf = lane >> 5;

    __shared__ __align__(16) char sQ[10 * ROWB];   // 52800 B
    __shared__ float sRed[4][8];
    __shared__ float sc[64];

    const int y0 = strip * 8;
    const char* img = (const char*)qin + (size_t)b * 4 * HW * 16;

    if (tid < 64) sc[tid] = coef[b * 64 + tid];
    // zero halo slots 0 and 65 (10 rows x 2 sides x 4 subs = 80)
    if (tid < 80) {
        int r = tid >> 3, side = (tid >> 2) & 1, sub = tid & 3;
        uint4 z; z.x = z.y = z.z = z.w = 0;
        *(uint4*)(sQ + r * ROWB + side * 65 * SLOT + sub * 16) = z;
    }
    __syncthreads();

    // ---- staging: thread -> (pixel px, sub-block s); register prefetch
    const int px = tid & 63;
    const int s_id = tid >> 6;          // wave-uniform
    const int rot = px & 3;
    float ca[8], cb[8];
#pragma unroll
    for (int e = 0; e < 8; ++e) {
        ca[e] = sc[(s_id * 8 + e) * 2 + 0];
        cb[e] = sc[(s_id * 8 + e) * 2 + 1];
    }
    uint4 ld[10];
#pragma unroll
    for (int r = 0; r < 10; ++r) {
        int gy = y0 - 1 + r;
        if (gy >= 0 && gy < 64) {
            ld[r] = *(const uint4*)(img + ((size_t)(s_id * HW) + gy * 64 + px) * 16);
        } else {
            ld[r].x = ld[r].y = ld[r].z = ld[r].w = 0;
        }
    }
    char* dstc = sQ + (px + 1) * SLOT + ((s_id + rot) & 3) * 16;
#pragma unroll
    for (int r = 0; r < 10; ++r) {
        unsigned int hd[4] = {ld[r].x, ld[r].y, ld[r].z, ld[r].w};
        unsigned int ho[4];
#pragma unroll
        for (int e = 0; e < 4; ++e) {
            float x0 = bf2f((unsigned short)(hd[e] & 0xFFFF));
            float x1 = bf2f((unsigned short)(hd[e] >> 16));
            float y0v = gelu_f(fmaf(ca[e * 2], x0, cb[e * 2]));
            float y1v = gelu_f(fmaf(ca[e * 2 + 1], x1, cb[e * 2 + 1]));
            ho[e] = (unsigned)f2bf(y0v) | ((unsigned)f2bf(y1v) << 16);
        }
        uint4 oh; oh.x = ho[0]; oh.y = ho[1]; oh.z = ho[2]; oh.w = ho[3];
        *(uint4*)(dstc + r * ROWB) = oh;
    }
    __syncthreads();

    // ---- MFMA: wave = (rq row-quad, xh x-half)
    const int rq = wv & 1;
    const int xh32 = (wv >> 1) * 32;
    f32x16_t acc[4];
#pragma unroll
    for (int i = 0; i < 4; ++i)
#pragma unroll
        for (int j = 0; j < 16; ++j) acc[i][j] = 0.0f;

    for (int kx = 0; kx < 3; ++kx) {
        bf16x8_t Wf[3][2];  // [ky][k2], single-bf16 (hl=0)
#pragma unroll
        for (int ky = 0; ky < 3; ++ky)
#pragma unroll
            for (int k2 = 0; k2 < 2; ++k2) {
                int fi = (((ky * 3 + kx) * 2 + k2) * 2);
                Wf[ky][k2] = __builtin_bit_cast(
                    bf16x8_t, *(const uint4*)(wq + (size_t)fi * 512 + lane * 8));
            }
        const int slotb = xh32 + kx + m;
        const int prot = (m + kx + 3) & 3;
#pragma unroll
        for (int li = 0; li < 6; ++li) {
            const char* rowp = sQ + (rq * 4 + li) * ROWB + slotb * SLOT;
            bf16x8_t Ah[2];
#pragma unroll
            for (int k2 = 0; k2 < 2; ++k2) {
                int s = k2 * 2 + hf;
                Ah[k2] = __builtin_bit_cast(bf16x8_t, *(const uint4*)(rowp + ((s + prot) & 3) * 16));
            }
#pragma unroll
            for (int ky = 0; ky < 3; ++ky) {
                int orow = li - ky;
                if (orow < 0 || orow > 3) continue;
#pragma unroll
                for (int k2 = 0; k2 < 2; ++k2)
                    acc[orow] = __builtin_amdgcn_mfma_f32_32x32x16_bf16(Ah[k2], Wf[ky][k2], acc[orow], 0, 0, 0);
            }
        }
    }

    // ---- epilogue: stats + u16 LDS transpose [512][40] + planar stores
    __syncthreads();
    unsigned short* lds_t = (unsigned short*)sQ;
    const int co = lane & 31;
    float s1 = 0.0f, s2 = 0.0f;
#pragma unroll
    for (int orow = 0; orow < 4; ++orow) {
#pragma unroll
        for (int r = 0; r < 16; ++r) {
            int mm = (r & 3) + 8 * (r >> 2) + 4 * hf;
            int pxl = (rq * 4 + orow) * 64 + xh32 + mm;
            float v = acc[orow][r];
            s1 += v;
            s2 = fmaf(v, v, s2);
            lds_t[pxl * 40 + co] = f2bf(v);
        }
    }
    s1 += __shfl_xor(s1, 32); s2 += __shfl_xor(s2, 32);
    s1 += __shfl_xor(s1, 1);  s2 += __shfl_xor(s2, 1);
    s1 += __shfl_xor(s1, 2);  s2 += __shfl_xor(s2, 2);
    s1 += __shfl_xor(s1, 4);  s2 += __shfl_xor(s2, 4);
    if (lane < 32 && (lane & 7) == 0) {
        sRed[wv][co >> 3] = s1;
        sRed[wv][4 + (co >> 3)] = s2;
    }
    __syncthreads();
    if (tid < 8)
        statp[((size_t)b * 16 + strip) * 8 + tid] =
            sRed[0][tid] + sRed[1][tid] + sRed[2][tid] + sRed[3][tid];

    char* qb = (char*)qout + (size_t)b * 4 * HW * 16;
    const int p0 = y0 * 64;
#pragma unroll
    for (int pi = 0; pi < 2; ++pi) {
        int p = pi * 256 + tid;          // 0..511
#pragma unroll
        for (int s = 0; s < 4; ++s) {
            uint4 uh = *(const uint4*)(lds_t + p * 40 + s * 8);
            *(uint4*)(qb + ((size_t)(s * HW) + p0 + p) * 16) = uh;
        }
    }
}

// ---------------------------------------------------------------------------
// Projection + l2norm + fused gauss-pool partials. (unchanged)
// ---------------------------------------------------------------------------
__global__ __launch_bounds__(256) void proj_kernel(
    const unsigned short* __restrict__ q, const float* __restrict__ coef,
    const float* __restrict__ pw, unsigned short* __restrict__ outn,
    float* __restrict__ poolp, float* __restrict__ E, float* __restrict__ swp,
    const float* __restrict__ gauss, int vpad) {
    int b = blockIdx.y, chunk = blockIdx.x, tid = threadIdx.x;
    int p = chunk * 256 + tid;
    __shared__ float sR[4];
    __shared__ float sc[64];
    __shared__ float red[32][257];
    if (tid < 64) sc[tid] = coef[b * 64 + tid];
    __syncthreads();
    float feat[32];
    {
        const char* qb = (const char*)q + (size_t)b * 4 * HW * 16;
#pragma unroll
        for (int s = 0; s < 4; ++s) {
            uint4 uh = *(const uint4*)(qb + ((size_t)(s * HW) + p) * 16);
            unsigned int hd[4] = {uh.x, uh.y, uh.z, uh.w};
#pragma unroll
            for (int e = 0; e < 4; ++e) {
                int c0 = s * 8 + e * 2;
                float x0 = bf2f((unsigned short)(hd[e] & 0xFFFF));
                float x1 = bf2f((unsigned short)(hd[e] >> 16));
                feat[c0] = gelu_f(fmaf(sc[c0 * 2], x0, sc[c0 * 2 + 1]));
                feat[c0 + 1] = gelu_f(fmaf(sc[(c0 + 1) * 2], x1, sc[(c0 + 1) * 2 + 1]));
            }
        }
    }
    float g = gauss[p];
#pragma unroll
    for (int c = 0; c < 32; ++c) red[c][tid] = feat[c] * g;

    float o[32];
#pragma unroll
    for (int oo = 0; oo < 32; ++oo) o[oo] = 0.0f;
    for (int c = 0; c < 32; ++c) {
        float f = feat[c];
#pragma unroll
        for (int oo = 0; oo < 32; ++oo) o[oo] = fmaf(pw[oo * 32 + c], f, o[oo]);
    }
    float nn = 0.0f;
#pragma unroll
    for (int oo = 0; oo < 32; ++oo) nn = fmaf(o[oo], o[oo], nn);
    float n = sqrtf(nn);
    float inv = 1.0f / fmaxf(n, 1e-6f);
    if (vpad) {
        int y = p >> 6, x = p & 63;
        unsigned short* vb_ = outn + (size_t)b * 32 * 4608 + y * 72 + x + 4;
#pragma unroll
        for (int oo = 0; oo < 32; ++oo) {
            unsigned short hv = f2bf(o[oo] * inv);
            unsigned short* row = vb_ + (size_t)oo * 4608;
            row[0] = hv;
            if (x == 0) { row[-4] = hv; row[-3] = hv; row[-2] = hv; row[-1] = hv; }
            if (x == 63) { row[1] = hv; row[2] = hv; row[3] = hv; row[4] = hv; }
        }
    } else {
        unsigned short* obp = outn + (size_t)b * 32 * HW + p;
#pragma unroll
        for (int oo = 0; oo < 32; ++oo) obp[(size_t)oo * HW] = f2bf(o[oo] * inv);
    }

    __syncthreads();
    if (tid < 32) {
        float s = 0.0f;
#pragma unroll 8
        for (int i = 0; i < 256; ++i) s += red[tid][i];
        poolp[((size_t)b * 16 + chunk) * 32 + tid] = s;
    }

    if (E != nullptr) {
        float e = nn * inv * inv;
        E[(size_t)b * HW + p] = e;
        float wvv = e * g;
#pragma unroll
        for (int off = 32; off > 0; off >>= 1) wvv += __shfl_down(wvv, off);
        if ((tid & 63) == 0) sR[tid >> 6] = wvv;
        __syncthreads();
        if (tid == 0) swp[b * 16 + chunk] = sR[0] + sR[1] + sR[2] + sR[3];
    }
}

// ---------------------------------------------------------------------------
// 49-offset correlation logits. (unchanged)
// ---------------------------------------------------------------------------
__global__ __launch_bounds__(256) void logits_kernel(
    const unsigned short* __restrict__ rn, const unsigned short* __restrict__ vnp,
    const float* __restrict__ E, const float* __restrict__ swp,
    const float* __restrict__ gauss, float* __restrict__ lgpart) {
    int b = blockIdx.x, cg = blockIdx.y, tid = threadIdx.x;
    __shared__ float sR[4][49];
    float acc[49];
#pragma unroll
    for (int k = 0; k < 49; ++k) acc[k] = 0.0f;
    float ssum = 0.0f;
#pragma unroll
    for (int i = 0; i < 16; ++i) ssum += swp[b * 16 + i];
    const float scale = 0.17677669529663688f / (ssum + 1e-8f);
    const int x0 = (tid & 7) * 8;
    const float* Eb = E + (size_t)b * HW;
#pragma unroll 1
    for (int half = 0; half < 2; ++half) {
        const int y = half * 32 + (tid >> 3);
        const int pbase = y * 64 + x0;
        float4 e0 = *(const float4*)(Eb + pbase);
        float4 e1 = *(const float4*)(Eb + pbase + 4);
        float4 g0 = *(const float4*)(gauss + pbase);
        float4 g1 = *(const float4*)(gauss + pbase + 4);
        float qw[8];
        qw[0] = e0.x * g0.x * scale; qw[1] = e0.y * g0.y * scale;
        qw[2] = e0.z * g0.z * scale; qw[3] = e0.w * g0.w * scale;
        qw[4] = e1.x * g1.x * scale; qw[5] = e1.y * g1.y * scale;
        qw[6] = e1.z * g1.z * scale; qw[7] = e1.w * g1.w * scale;
#pragma unroll 1
        for (int cc = 0; cc < 4; ++cc) {
            int c = cg * 4 + cc;
            const unsigned short* rb = rn + ((size_t)b * 32 + c) * HW;
            uint4 rv = *(const uint4*)(rb + pbase);
            unsigned int rd[4] = {rv.x, rv.y, rv.z, rv.w};
            float r_[8];
            r_[0] = bf2f((unsigned short)(rd[0] & 0xFFFF)) * qw[0];
            r_[1] = bf2f((unsigned short)(rd[0] >> 16)) * qw[1];
            r_[2] = bf2f((unsigned short)(rd[1] & 0xFFFF)) * qw[2];
            r_[3] = bf2f((unsigned short)(rd[1] >> 16)) * qw[3];
            r_[4] = bf2f((unsigned short)(rd[2] & 0xFFFF)) * qw[4];
            r_[5] = bf2f((unsigned short)(rd[2] >> 16)) * qw[5];
            r_[6] = bf2f((unsigned short)(rd[3] & 0xFFFF)) * qw[6];
            r_[7] = bf2f((unsigned short)(rd[3] >> 16)) * qw[7];
            const unsigned short* vplane = vnp + ((size_t)b * 32 + c) * 4608;
#pragma unroll
            for (int dy = 0; dy < 7; ++dy) {
                int ry = y + dy - 3;
                ry = ry < 0 ? 0 : (ry > 63 ? 63 : ry);
                const unsigned short* vp = vplane + ry * 72 + x0;
                uint4 va = *(const uint4*)vp;
                uint4 vb2 = *(const uint4*)(vp + 8);
                unsigned int vd[8] = {va.x, va.y, va.z, va.w, vb2.x, vb2.y, vb2.z, vb2.w};
                float v[16];
#pragma unroll
                for (int j2 = 0; j2 < 8; ++j2) {
                    v[j2 * 2] = bf2f((unsigned short)(vd[j2] & 0xFFFF));
                    v[j2 * 2 + 1] = bf2f((unsigned short)(vd[j2] >> 16));
                }
#pragma unroll
                for (int dx = 0; dx < 7; ++dx)
#pragma unroll
                    for (int j = 0; j < 8; ++j)
                        acc[dy * 7 + dx] = fmaf(r_[j], v[j + dx + 1], acc[dy * 7 + dx]);
            }
        }
    }
#pragma unroll
    for (int k = 0; k < 49; ++k) {
#pragma unroll
        for (int off = 32; off > 0; off >>= 1) acc[k] += __shfl_down(acc[k], off);
    }
    int wid = tid >> 6;
    if ((tid & 63) == 0) {
#pragma unroll
        for (int k = 0; k < 49; ++k) sR[wid][k] = acc[k];
    }
    __syncthreads();
    if (tid < 49)
        lgpart[((size_t)b * 8 + cg) * 49 + tid] =
            sR[0][tid] + sR[1][tid] + sR[2][tid] + sR[3][tid];
}

// ---------------------------------------------------------------------------
__global__ __launch_bounds__(128) void head_kernel(
    const float* __restrict__ lg, const float* __restrict__ rpp,
    const float* __restrict__ vpp, const float* __restrict__ p2s,
    const float* __restrict__ log_temp,
    const float* __restrict__ W1, const float* __restrict__ b1,
    const float* __restrict__ W2, const float* __restrict__ b2,
    const float* __restrict__ W3, const float* __restrict__ b3,
    float* __restrict__ out) {
    int b = blockIdx.x, t = threadIdx.x;
    __shared__ float slg[49];
    __shared__ float pooled[98];
    __shared__ float h1[128], h2[128];
    __shared__ float cxy[2];
    __shared__ float res[3];
    const float* lgp = lg + (size_t)b * 8 * 49;
    if (t < 49) {
        float s = 0.0f;
#pragma unroll
        for (int g = 0; g < 8; ++g) s += lgp[g * 49 + t];
        slg[t] = s;
    }
    __syncthreads();
    if (t == 0) {
        float temp = fmaxf(expf(log_temp[0]), 0.001f);
        float invT = 1.0f / temp;
        float m = -1e30f;
        for (int k = 0; k < 49; ++k) m = fmaxf(m, slg[k] * invT);
        float s = 0.0f, pdx = 0.0f, pdy = 0.0f;
        for (int k = 0; k < 49; ++k) {
            float e = expf(slg[k] * invT - m);
            s += e;
            pdx += e * (float)((k % 7) - 3);
            pdy += e * (float)((k / 7) - 3);
        }
        cxy[0] = pdx / s;
        cxy[1] = pdy / s;
    }
    __syncthreads();
    if (t < 32) {
        float a = 0.0f, c = 0.0f;
#pragma unroll
        for (int k = 0; k < 16; ++k) {
            a += rpp[((size_t)b * 16 + k) * 32 + t];
            c += vpp[((size_t)b * 16 + k) * 32 + t];
        }
        pooled[t] = a;
        pooled[32 + t] = c;
        pooled[64 + t] = a - c;
    }
    if (t == 0) {
        pooled[96] = cxy[0];
        pooled[97] = cxy[1];
    }
    __syncthreads();
    float s1 = b1[t];
    for (int i = 0; i < 98; ++i) s1 = fmaf(pooled[i], W1[i * 128 + t], s1);
    h1[t] = gelu_f(s1);
    __syncthreads();
    float s2 = b2[t];
    for (int i = 0; i < 128; ++i) s2 = fmaf(h1[i], W2[i * 128 + t], s2);
    h2[t] = gelu_f(s2);
    __syncthreads();
    if (t < 3) {
        float r = b3[t];
        for (int i = 0; i < 128; ++i) r = fmaf(h2[i], W3[i * 3 + t], r);
        res[t] = r;
    }
    __syncthreads();
    if (t == 0) {
        float dxp = cxy[0] + res[0];
        float dyp = cxy[1] + res[1];
        float ls = fminf(fmaxf(res[2], -6.0f), 3.0f);
        const float* M = p2s + b * 4;
        float* ob = out + b * 54;
        ob[0] = dxp;
        ob[1] = dyp;
        ob[2] = M[0] * dxp + M[1] * dyp;
        ob[3] = M[2] * dxp + M[3] * dyp;
        ob[4] = ls;
    }
    if (t < 49) out[b * 54 + 5 + t] = slg[t];
}

extern "C" void kernel_launch(void* const* d_in, const int* in_sizes, int n_in,
                              void* d_out, int out_size, void* d_ws, size_t ws_size,
                              hipStream_t stream) {
    (void)in_sizes; (void)n_in; (void)out_size;
    const float* rubin = (const float*)d_in[0];
    const float* vis   = (const float*)d_in[1];
    const float* p2s   = (const float*)d_in[2];
    const float* rW0   = (const float*)d_in[3];
    const float* rWs   = (const float*)d_in[4];
    const float* rG    = (const float*)d_in[5];
    const float* rBt   = (const float*)d_in[6];
    const float* vW0   = (const float*)d_in[7];
    const float* vWs   = (const float*)d_in[8];
    const float* vG    = (const float*)d_in[9];
    const float* vBt   = (const float*)d_in[10];
    const float* projR = (const float*)d_in[11];
    const float* projV = (const float*)d_in[12];
    const float* logT  = (const float*)d_in[13];
    const float* W1    = (const float*)d_in[14];
    const float* b1    = (const float*)d_in[15];
    const float* W2    = (const float*)d_in[16];
    const float* b2    = (const float*)d_in[17];
    const float* W3    = (const float*)d_in[18];
    const float* b3    = (const float*)d_in[19];
    float* out = (float*)d_out;

    // ---- workspace layout (bytes)
    char* ws = (char*)d_ws;
    size_t off = 0;
    unsigned short* vnB = (unsigned short*)(ws + off); off += (size_t)NB * 32 * 4608 * 2;
    float* gauss  = (float*)(ws + off); off += HW * 4;
    float* statp  = (float*)(ws + off); off += (size_t)NB * 16 * 8 * 4;
    float* coefS  = (float*)(ws + off); off += (size_t)NB * 64 * 4;
    float* swp    = (float*)(ws + off); off += (size_t)NB * 16 * 4;
    float* rpp    = (float*)(ws + off); off += (size_t)NB * 16 * 32 * 4;
    float* vpp    = (float*)(ws + off); off += (size_t)NB * 16 * 32 * 4;
    float* lgbuf  = (float*)(ws + off); off += (size_t)NB * 8 * 49 * 4;
    unsigned short* wq = (unsigned short*)(ws + off); off += 115712ull * 2;
    off = (off + 255) & ~(size_t)255;
    const size_t fixed_bytes = off;
    const size_t perb = 2ull * HW * 64 + HW * 4;
    int BC = 1;
    if (ws_size > fixed_bytes + perb) {
        size_t t = (ws_size - fixed_bytes) / perb;
        BC = t > (size_t)NB ? NB : (int)t;
    }
    unsigned short* Q1 = (unsigned short*)(ws + off);
    unsigned short* Q2 = (unsigned short*)(ws + off + (size_t)BC * HW * 64);
    float* E = (float*)(ws + off + 2ull * BC * HW * 64);
    unsigned short* wq0r = wq + 110592;
    unsigned short* wq0v = wq + 114688;

    dim3 blk256(256), blk128(128);
    gauss_kernel<<<1, 256, 0, stream>>>(gauss);
    prep_w_kernel<<<452, 256, 0, stream>>>(rWs, vWs, rW0, vW0, wq);

    // ================= VIS encoder (all chunks) =================
    for (int b0 = 0; b0 < NB; b0 += BC) {
        const int bc = (NB - b0) < BC ? (NB - b0) : BC;
        dim3 cg16(16, bc), cg8(8, bc);
        const int gnblk = (bc * 32 + 255) / 256;
        float* sp = statp + (size_t)b0 * 128;
        float* cS = coefS + (size_t)b0 * 64;

        conv_first_m_kernel<1><<<cg16, blk128, 0, stream>>>(vis + (size_t)b0 * HW, wq0v, Q1, sp);
        gn_finalize_kernel<<<gnblk, 256, 0, stream>>>(sp, vG + 0, vBt + 0, cS, bc * 32, 16);
        convm_kernel<<<cg8, blk256, 0, stream>>>(Q1, cS, wq + 3 * 18432, Q2, sp);
        gn_finalize_kernel<<<gnblk, 256, 0, stream>>>(sp, vG + 32, vBt + 32, cS, bc * 32, 8);
        convm_kernel<<<cg8, blk256, 0, stream>>>(Q2, cS, wq + 4 * 18432, Q1, sp);
        gn_finalize_kernel<<<gnblk, 256, 0, stream>>>(sp, vG + 64, vBt + 64, cS, bc * 32, 8);
        convm_kernel<<<cg8, blk256, 0, stream>>>(Q1, cS, wq + 5 * 18432, Q2, sp);
        gn_finalize_kernel<<<gnblk, 256, 0, stream>>>(sp, vG + 96, vBt + 96, cS, bc * 32, 8);
        proj_kernel<<<cg16, blk256, 0, stream>>>(Q2, cS, projV, vnB + (size_t)b0 * 32 * 4608,
                                                 vpp + (size_t)b0 * 512,
                                                 (float*)nullptr, (float*)nullptr, gauss, 1);
    }

    // ================= RUBIN encoder + logits (all chunks) =================
    for (int b0 = 0; b0 < NB; b0 += BC) {
        const int bc = (NB - b0) < BC ? (NB - b0) : BC;
        dim3 cg16(16, bc), cg8(8, bc);
        const int gnblk = (bc * 32 + 255) / 256;
        float* sp = statp + (size_t)b0 * 128;
        float* cS = coefS + (size_t)b0 * 64;
        float* sw = swp + (size_t)b0 * 16;
        unsigned short* rnB = Q1;

        conv_first_m_kernel<6><<<cg16, blk128, 0, stream>>>(rubin + (size_t)b0 * 6 * HW, wq0r, Q1, sp);
        gn_finalize_kernel<<<gnblk, 256, 0, stream>>>(sp, rG + 0, rBt + 0, cS, bc * 32, 16);
        convm_kernel<<<cg8, blk256, 0, stream>>>(Q1, cS, wq + 0 * 18432, Q2, sp);
        gn_finalize_kernel<<<gnblk, 256, 0, stream>>>(sp, rG + 32, rBt + 32, cS, bc * 32, 8);
        convm_kernel<<<cg8, blk256, 0, stream>>>(Q2, cS, wq + 1 * 18432, Q1, sp);
        gn_finalize_kernel<<<gnblk, 256, 0, stream>>>(sp, rG + 64, rBt + 64, cS, bc * 32, 8);
        convm_kernel<<<cg8, blk256, 0, stream>>>(Q1, cS, wq + 2 * 18432, Q2, sp);
        gn_finalize_kernel<<<gnblk, 256, 0, stream>>>(sp, rG + 96, rBt + 96, cS, bc * 32, 8);
        proj_kernel<<<cg16, blk256, 0, stream>>>(Q2, cS, projR, rnB,
                                                 rpp + (size_t)b0 * 512, E, sw, gauss, 0);
        logits_kernel<<<dim3(bc, 8), blk256, 0, stream>>>(rnB, vnB + (size_t)b0 * 32 * 4608,
                                                          E, sw, gauss,
                                                          lgbuf + (size_t)b0 * 8 * 49);
    }

    head_kernel<<<NB, 128, 0, stream>>>(lgbuf, rpp, vpp, p2s, logT, W1, b1, W2, b2, W3, b3, out);
}

// Round 14
// 726.696 us; speedup vs baseline: 3.3631x; 1.0459x over previous
//
#include <hip/hip_runtime.h>
#include <math.h>

#define HW 4096
#define NB 256

typedef __attribute__((ext_vector_type(8))) short bf16x8_t;
typedef __attribute__((ext_vector_type(16))) float f32x16_t;

// Fast erf-based GELU (A&S 7.1.26, |err| <= 1.5e-7)
__device__ __forceinline__ float gelu_f(float x) {
    float z = x * 0.70710678118654752440f;
    float az = fabsf(z);
    float t = 1.0f / fmaf(0.3275911f, az, 1.0f);
    float p = t * fmaf(t, fmaf(t, fmaf(t, fmaf(t, 1.061405429f, -1.453152027f),
                                       1.421413741f), -0.284496736f), 0.254829592f);
    float e = __expf(-az * az);
    float er = 1.0f - p * e;
    er = copysignf(er, z);
    return 0.5f * x * (1.0f + er);
}
__device__ __forceinline__ unsigned short f2bf(float f) {
    unsigned int u = __float_as_uint(f);
    unsigned int r = u + 0x7FFFu + ((u >> 16) & 1u);
    return (unsigned short)(r >> 16);
}
__device__ __forceinline__ float bf2f(unsigned short h) {
    return __uint_as_float(((unsigned int)h) << 16);
}

// Q layout (PLANAR, single-bf16): Q[b][s][p], s=0..3 = ci-group (8 ch, 16 B).
// convm weights single-bf16; conv_first + proj weights split hi/lo.
// vn planes edge-padded [c][64][72] bf16.

// ---------------------------------------------------------------------------
__global__ __launch_bounds__(256) void gauss_kernel(float* __restrict__ gauss) {
    __shared__ float sg[HW];
    __shared__ float sR[4];
    int tid = threadIdx.x;
    float part = 0.0f;
    for (int p = tid; p < HW; p += 256) {
        int y = p >> 6, x = p & 63;
        float yy = -1.0f + (2.0f / 63.0f) * (float)y;
        float xx = -1.0f + (2.0f / 63.0f) * (float)x;
        float g = expf(-(yy * yy + xx * xx) * 2.0f);
        sg[p] = g;
        part += g;
    }
#pragma unroll
    for (int off = 32; off > 0; off >>= 1) part += __shfl_down(part, off);
    if ((tid & 63) == 0) sR[tid >> 6] = part;
    __syncthreads();
    float invt = 1.0f / (sR[0] + sR[1] + sR[2] + sR[3]);
    for (int p = tid; p < HW; p += 256) gauss[p] = sg[p] * invt;
}

// ---------------------------------------------------------------------------
// Pack weights into MFMA B-fragment order.
// i < 110592: conv layers (split h/l; convm reads hl=0 only).
// 110592..114687: rubin W0 (K=54 pad 64). 114688..115711: vis W0 (K=9 pad 16).
// 115712..117759: projR frags (2 ksteps x 2 hl x 512). 117760..119807: projV.
// ---------------------------------------------------------------------------
__global__ __launch_bounds__(256) void prep_w_kernel(
    const float* __restrict__ rWs, const float* __restrict__ vWs,
    const float* __restrict__ rW0, const float* __restrict__ vW0,
    const float* __restrict__ projR, const float* __restrict__ projV,
    unsigned short* __restrict__ wq) {
    int i = blockIdx.x * 256 + threadIdx.x;
    if (i >= 119808) return;
    float wv;
    if (i < 110592) {
        int j = i & 7;
        int lane = (i >> 3) & 63;
        int f = i >> 9;
        int hl = f & 1, k2 = (f >> 1) & 1, tap = (f >> 2) % 9, layer = (f >> 2) / 9;
        int co = lane & 31, hf = lane >> 5;
        int ci = k2 * 16 + hf * 8 + j;
        int ky = tap / 3, kx = tap % 3;
        wv = (layer < 3)
            ? rWs[(((size_t)layer * 32 + co) * 32 + ci) * 9 + ky * 3 + kx]
            : vWs[(((size_t)(layer - 3) * 32 + co) * 32 + ci) * 9 + ky * 3 + kx];
        unsigned short h = f2bf(wv);
        unsigned short l = f2bf(wv - bf2f(h));
        wq[i] = hl ? l : h;
        return;
    }
    if (i < 115712) {
        int i2 = i - 110592;
        int j = i2 & 7;
        int lane = (i2 >> 3) & 63;
        int co = lane & 31, hf = lane >> 5;
        if (i2 < 4096) {
            int f = i2 >> 9;
            int hl = f & 1, ks = f >> 1;
            int q = ks * 16 + hf * 8 + j;
            wv = (q < 54) ? rW0[((size_t)co * 6 + q / 9) * 9 + q % 9] : 0.0f;
            unsigned short h = f2bf(wv);
            unsigned short l = f2bf(wv - bf2f(h));
            wq[i] = hl ? l : h;
        } else {
            int i3 = i2 - 4096;
            int f = i3 >> 9;
            int q = hf * 8 + j;
            wv = (q < 9) ? vW0[(size_t)co * 9 + q] : 0.0f;
            unsigned short h = f2bf(wv);
            unsigned short l = f2bf(wv - bf2f(h));
            wq[i] = f ? l : h;
        }
        return;
    }
    int i4 = i - 115712;
    const float* pw = (i4 < 2048) ? projR : projV;
    int r = i4 & 2047;
    int j = r & 7;
    int lane = (r >> 3) & 63;
    int f = r >> 9;                 // k2*2 + hl
    int hl = f & 1, k2 = f >> 1;
    int co = lane & 31, hf = lane >> 5;
    int ci = k2 * 16 + hf * 8 + j;
    wv = pw[(size_t)co * 32 + ci];
    unsigned short h = f2bf(wv);
    unsigned short l = f2bf(wv - bf2f(h));
    wq[i] = hl ? l : h;
}

// ---------------------------------------------------------------------------
// First conv layer via MFMA implicit GEMM (split-w 2-term). (unchanged)
// ---------------------------------------------------------------------------
template <int CIN>
__global__ __launch_bounds__(128) void conv_first_m_kernel(
    const float* __restrict__ in, const unsigned short* __restrict__ wq0,
    unsigned short* __restrict__ qout, float* __restrict__ statp) {
    constexpr int KQ = CIN * 9;
    constexpr int KS = (KQ + 15) / 16;
    const int b = blockIdx.y;
    const int strip = blockIdx.x;
    const int tid = threadIdx.x;
    const int wv = tid >> 6;
    const int lane = tid & 63;
    const int m = lane & 31;
    const int hf = lane >> 5;
    const int xh32 = wv * 32;

    __shared__ __align__(16) char smem[20736];
    __shared__ float sRed[2][8];
    float* sInF = (float*)smem;

    const int y0 = strip * 4;
    const float* inb = in + (size_t)b * CIN * HW;
    for (int idx = tid; idx < CIN * 6 * 66; idx += 128) {
        int ci = idx / 396;
        int rem = idx - ci * 396;
        int r = rem / 66;
        int col = rem - r * 66;
        int gy = y0 - 1 + r;
        int gx = col - 1;
        float v = 0.0f;
        if (gy >= 0 && gy < 64 && gx >= 0 && gx < 64) v = inb[ci * HW + gy * 64 + gx];
        sInF[ci * 396 + r * 66 + col] = v;
    }

    int P[KS][8];
#pragma unroll
    for (int ks = 0; ks < KS; ++ks)
#pragma unroll
        for (int j = 0; j < 8; ++j) {
            int q = ks * 16 + hf * 8 + j;
            int ci = q / 9, tap = q - ci * 9;
            int ky = tap / 3, kx = tap - ky * 3;
            P[ks][j] = (q < KQ) ? (ci * 396 + ky * 66 + kx) : 0;
        }
    bf16x8_t Wf[KS][2];
#pragma unroll
    for (int ks = 0; ks < KS; ++ks)
#pragma unroll
        for (int hl = 0; hl < 2; ++hl)
            Wf[ks][hl] = __builtin_bit_cast(
                bf16x8_t, *(const uint4*)(wq0 + (size_t)(ks * 2 + hl) * 512 + lane * 8));
    __syncthreads();

    f32x16_t acc[4];
#pragma unroll
    for (int i = 0; i < 4; ++i)
#pragma unroll
        for (int j = 0; j < 16; ++j) acc[i][j] = 0.0f;

    const int xcol = xh32 + m;
#pragma unroll
    for (int orow = 0; orow < 4; ++orow) {
        const int obase = orow * 66 + xcol;
#pragma unroll
        for (int ks = 0; ks < KS; ++ks) {
            unsigned int pk[4];
#pragma unroll
            for (int e = 0; e < 4; ++e) {
                float v0 = sInF[P[ks][e * 2] + obase];
                float v1 = sInF[P[ks][e * 2 + 1] + obase];
                pk[e] = (unsigned)f2bf(v0) | ((unsigned)f2bf(v1) << 16);
            }
            uint4 u; u.x = pk[0]; u.y = pk[1]; u.z = pk[2]; u.w = pk[3];
            bf16x8_t A = __builtin_bit_cast(bf16x8_t, u);
            acc[orow] = __builtin_amdgcn_mfma_f32_32x32x16_bf16(A, Wf[ks][0], acc[orow], 0, 0, 0);
            acc[orow] = __builtin_amdgcn_mfma_f32_32x32x16_bf16(A, Wf[ks][1], acc[orow], 0, 0, 0);
        }
    }

    __syncthreads();
    unsigned short* lds_t = (unsigned short*)smem;
    const int co = lane & 31;
    float s1 = 0.0f, s2 = 0.0f;
#pragma unroll
    for (int orow = 0; orow < 4; ++orow) {
#pragma unroll
        for (int r = 0; r < 16; ++r) {
            int mm = (r & 3) + 8 * (r >> 2) + 4 * hf;
            int pxl = (orow << 6) + xh32 + mm;
            float v = acc[orow][r];
            s1 += v;
            s2 = fmaf(v, v, s2);
            lds_t[pxl * 40 + co] = f2bf(v);
        }
    }
    s1 += __shfl_xor(s1, 32); s2 += __shfl_xor(s2, 32);
    s1 += __shfl_xor(s1, 1);  s2 += __shfl_xor(s2, 1);
    s1 += __shfl_xor(s1, 2);  s2 += __shfl_xor(s2, 2);
    s1 += __shfl_xor(s1, 4);  s2 += __shfl_xor(s2, 4);
    if (lane < 32 && (lane & 7) == 0) {
        sRed[wv][co >> 3] = s1;
        sRed[wv][4 + (co >> 3)] = s2;
    }
    __syncthreads();
    if (tid < 8) statp[((size_t)b * 16 + strip) * 8 + tid] = sRed[0][tid] + sRed[1][tid];

    char* qb = (char*)qout + (size_t)b * 4 * HW * 16;
    const int p0 = y0 * 64;
#pragma unroll
    for (int pi = 0; pi < 2; ++pi) {
        int p = pi * 128 + tid;
#pragma unroll
        for (int s = 0; s < 4; ++s) {
            uint4 uh = *(const uint4*)(lds_t + p * 40 + s * 8);
            *(uint4*)(qb + ((size_t)(s * HW) + p0 + p) * 16) = uh;
        }
    }
}

// ---------------------------------------------------------------------------
__global__ __launch_bounds__(256) void gn_finalize_kernel(
    const float* __restrict__ statp, const float* __restrict__ gma,
    const float* __restrict__ bta, float* __restrict__ coef, int n, int ns) {
    int i = blockIdx.x * 256 + threadIdx.x;
    if (i >= n) return;
    int b = i >> 5, c = i & 31, g = c >> 3;
    float s1 = 0.0f, s2 = 0.0f;
    for (int s = 0; s < ns; ++s) {
        s1 += statp[((size_t)b * 16 + s) * 8 + g];
        s2 += statp[((size_t)b * 16 + s) * 8 + 4 + g];
    }
    const float invN = 1.0f / 32768.0f;
    float mean = s1 * invN;
    float var = s2 * invN - mean * mean;
    float rstd = rsqrtf(var + 1e-5f);
    float a = rstd * gma[c];
    float bb = bta[c] - mean * a;
    coef[i * 2 + 0] = a;
    coef[i * 2 + 1] = bb;
}

// ---------------------------------------------------------------------------
// MFMA 3x3 conv, fused GN+GELU, single-bf16 x AND w, 8-row strips. (unchanged)
// ---------------------------------------------------------------------------
#define SLOT 80
#define ROWB (66 * SLOT)
__global__ __launch_bounds__(256) void convm_kernel(
    const unsigned short* __restrict__ qin, const float* __restrict__ coef,
    const unsigned short* __restrict__ wq,
    unsigned short* __restrict__ qout, float* __restrict__ statp) {
    const int b = blockIdx.y;
    const int strip = blockIdx.x;
    const int tid = threadIdx.x;
    const int wv = tid >> 6;
    const int lane = tid & 63;
    const int m = lane & 31;
    const int hf = lane >> 5;

    __shared__ __align__(16) char sQ[10 * ROWB];
    __shared__ float sRed[4][8];
    __shared__ float sc[64];

    const int y0 = strip * 8;
    const char* img = (const char*)qin + (size_t)b * 4 * HW * 16;

    if (tid < 64) sc[tid] = coef[b * 64 + tid];
    if (tid < 80) {
        int r = tid >> 3, side = (tid >> 2) & 1, sub = tid & 3;
        uint4 z; z.x = z.y = z.z = z.w = 0;
        *(uint4*)(sQ + r * ROWB + side * 65 * SLOT + sub * 16) = z;
    }
    __syncthreads();

    const int px = tid & 63;
    const int s_id = tid >> 6;
    const int rot = px & 3;
    float ca[8], cb[8];
#pragma unroll
    for (int e = 0; e < 8; ++e) {
        ca[e] = sc[(s_id * 8 + e) * 2 + 0];
        cb[e] = sc[(s_id * 8 + e) * 2 + 1];
    }
    uint4 ld[10];
#pragma unroll
    for (int r = 0; r < 10; ++r) {
        int gy = y0 - 1 + r;
        if (gy >= 0 && gy < 64) {
            ld[r] = *(const uint4*)(img + ((size_t)(s_id * HW) + gy * 64 + px) * 16);
        } else {
            ld[r].x = ld[r].y = ld[r].z = ld[r].w = 0;
        }
    }
    char* dstc = sQ + (px + 1) * SLOT + ((s_id + rot) & 3) * 16;
#pragma unroll
    for (int r = 0; r < 10; ++r) {
        unsigned int hd[4] = {ld[r].x, ld[r].y, ld[r].z, ld[r].w};
        unsigned int ho[4];
#pragma unroll
        for (int e = 0; e < 4; ++e) {
            float x0 = bf2f((unsigned short)(hd[e] & 0xFFFF));
            float x1 = bf2f((unsigned short)(hd[e] >> 16));
            float y0v = gelu_f(fmaf(ca[e * 2], x0, cb[e * 2]));
            float y1v = gelu_f(fmaf(ca[e * 2 + 1], x1, cb[e * 2 + 1]));
            ho[e] = (unsigned)f2bf(y0v) | ((unsigned)f2bf(y1v) << 16);
        }
        uint4 oh; oh.x = ho[0]; oh.y = ho[1]; oh.z = ho[2]; oh.w = ho[3];
        *(uint4*)(dstc + r * ROWB) = oh;
    }
    __syncthreads();

    const int rq = wv & 1;
    const int xh32 = (wv >> 1) * 32;
    f32x16_t acc[4];
#pragma unroll
    for (int i = 0; i < 4; ++i)
#pragma unroll
        for (int j = 0; j < 16; ++j) acc[i][j] = 0.0f;

    for (int kx = 0; kx < 3; ++kx) {
        bf16x8_t Wf[3][2];
#pragma unroll
        for (int ky = 0; ky < 3; ++ky)
#pragma unroll
            for (int k2 = 0; k2 < 2; ++k2) {
                int fi = (((ky * 3 + kx) * 2 + k2) * 2);
                Wf[ky][k2] = __builtin_bit_cast(
                    bf16x8_t, *(const uint4*)(wq + (size_t)fi * 512 + lane * 8));
            }
        const int slotb = xh32 + kx + m;
        const int prot = (m + kx + 3) & 3;
#pragma unroll
        for (int li = 0; li < 6; ++li) {
            const char* rowp = sQ + (rq * 4 + li) * ROWB + slotb * SLOT;
            bf16x8_t Ah[2];
#pragma unroll
            for (int k2 = 0; k2 < 2; ++k2) {
                int s = k2 * 2 + hf;
                Ah[k2] = __builtin_bit_cast(bf16x8_t, *(const uint4*)(rowp + ((s + prot) & 3) * 16));
            }
#pragma unroll
            for (int ky = 0; ky < 3; ++ky) {
                int orow = li - ky;
                if (orow < 0 || orow > 3) continue;
#pragma unroll
                for (int k2 = 0; k2 < 2; ++k2)
                    acc[orow] = __builtin_amdgcn_mfma_f32_32x32x16_bf16(Ah[k2], Wf[ky][k2], acc[orow], 0, 0, 0);
            }
        }
    }

    __syncthreads();
    unsigned short* lds_t = (unsigned short*)sQ;
    const int co = lane & 31;
    float s1 = 0.0f, s2 = 0.0f;
#pragma unroll
    for (int orow = 0; orow < 4; ++orow) {
#pragma unroll
        for (int r = 0; r < 16; ++r) {
            int mm = (r & 3) + 8 * (r >> 2) + 4 * hf;
            int pxl = (rq * 4 + orow) * 64 + xh32 + mm;
            float v = acc[orow][r];
            s1 += v;
            s2 = fmaf(v, v, s2);
            lds_t[pxl * 40 + co] = f2bf(v);
        }
    }
    s1 += __shfl_xor(s1, 32); s2 += __shfl_xor(s2, 32);
    s1 += __shfl_xor(s1, 1);  s2 += __shfl_xor(s2, 1);
    s1 += __shfl_xor(s1, 2);  s2 += __shfl_xor(s2, 2);
    s1 += __shfl_xor(s1, 4);  s2 += __shfl_xor(s2, 4);
    if (lane < 32 && (lane & 7) == 0) {
        sRed[wv][co >> 3] = s1;
        sRed[wv][4 + (co >> 3)] = s2;
    }
    __syncthreads();
    if (tid < 8)
        statp[((size_t)b * 16 + strip) * 8 + tid] =
            sRed[0][tid] + sRed[1][tid] + sRed[2][tid] + sRed[3][tid];

    char* qb = (char*)qout + (size_t)b * 4 * HW * 16;
    const int p0 = y0 * 64;
#pragma unroll
    for (int pi = 0; pi < 2; ++pi) {
        int p = pi * 256 + tid;
#pragma unroll
        for (int s = 0; s < 4; ++s) {
            uint4 uh = *(const uint4*)(lds_t + p * 40 + s * 8);
            *(uint4*)(qb + ((size_t)(s * HW) + p0 + p) * 16) = uh;
        }
    }
}

// ---------------------------------------------------------------------------
// Projection via MFMA (3-term split: fh*ph + fh*pl + fl*ph — value-identical
// to fp32 within ~2^-17) + l2norm + fused gauss-pool partials.
// Block 256 = 4 waves; wave = 64 px (2 m-tiles of 32). A-frags from planar Q
// (gelu fp32, split h/l); C transposed through LDS [256][33] for the
// per-pixel epilogue. Pool partials in-register + shfl.
// ---------------------------------------------------------------------------
__global__ __launch_bounds__(256) void proj_kernel(
    const unsigned short* __restrict__ q, const float* __restrict__ coef,
    const unsigned short* __restrict__ wqp, unsigned short* __restrict__ outn,
    float* __restrict__ poolp, float* __restrict__ E, float* __restrict__ swp,
    const float* __restrict__ gauss, int vpad) {
    int b = blockIdx.y, chunk = blockIdx.x, tid = threadIdx.x;
    const int wv = tid >> 6, lane = tid & 63;
    const int ln = lane & 31, hf = lane >> 5;
    __shared__ float sc[64];
    __shared__ float lds_o[256 * 33];
    __shared__ float poolw[4][32];
    __shared__ float sR[4];
    if (tid < 64) sc[tid] = coef[b * 64 + tid];
    __syncthreads();

    const char* qb = (const char*)q + (size_t)b * 4 * HW * 16;
    const int pb0 = chunk * 256 + wv * 64;

    bf16x8_t Bf[2][2];  // [k2][hl]
#pragma unroll
    for (int k2 = 0; k2 < 2; ++k2)
#pragma unroll
        for (int hl = 0; hl < 2; ++hl)
            Bf[k2][hl] = __builtin_bit_cast(
                bf16x8_t, *(const uint4*)(wqp + (size_t)(k2 * 2 + hl) * 512 + lane * 8));

    float psum[2][8];
#pragma unroll
    for (int k2 = 0; k2 < 2; ++k2)
#pragma unroll
        for (int j = 0; j < 8; ++j) psum[k2][j] = 0.0f;

    f32x16_t acc[2];
#pragma unroll
    for (int i = 0; i < 2; ++i)
#pragma unroll
        for (int j = 0; j < 16; ++j) acc[i][j] = 0.0f;

#pragma unroll
    for (int t = 0; t < 2; ++t) {
        int px = pb0 + t * 32 + ln;
        float g = gauss[px];
#pragma unroll
        for (int k2 = 0; k2 < 2; ++k2) {
            int s = k2 * 2 + hf;
            uint4 uh = *(const uint4*)(qb + ((size_t)(s * HW) + px) * 16);
            unsigned int hd[4] = {uh.x, uh.y, uh.z, uh.w};
            unsigned int ah[4], al[4];
#pragma unroll
            for (int e = 0; e < 4; ++e) {
                int c0 = s * 8 + e * 2;
                float x0 = bf2f((unsigned short)(hd[e] & 0xFFFF));
                float x1 = bf2f((unsigned short)(hd[e] >> 16));
                float f0 = gelu_f(fmaf(sc[c0 * 2], x0, sc[c0 * 2 + 1]));
                float f1 = gelu_f(fmaf(sc[c0 * 2 + 2], x1, sc[c0 * 2 + 3]));
                psum[k2][e * 2] = fmaf(f0, g, psum[k2][e * 2]);
                psum[k2][e * 2 + 1] = fmaf(f1, g, psum[k2][e * 2 + 1]);
                unsigned short h0 = f2bf(f0), h1 = f2bf(f1);
                unsigned short l0 = f2bf(f0 - bf2f(h0)), l1 = f2bf(f1 - bf2f(h1));
                ah[e] = (unsigned)h0 | ((unsigned)h1 << 16);
                al[e] = (unsigned)l0 | ((unsigned)l1 << 16);
            }
            uint4 uah; uah.x = ah[0]; uah.y = ah[1]; uah.z = ah[2]; uah.w = ah[3];
            uint4 ual; ual.x = al[0]; ual.y = al[1]; ual.z = al[2]; ual.w = al[3];
            bf16x8_t Ah = __builtin_bit_cast(bf16x8_t, uah);
            bf16x8_t Al = __builtin_bit_cast(bf16x8_t, ual);
            acc[t] = __builtin_amdgcn_mfma_f32_32x32x16_bf16(Ah, Bf[k2][0], acc[t], 0, 0, 0);
            acc[t] = __builtin_amdgcn_mfma_f32_32x32x16_bf16(Ah, Bf[k2][1], acc[t], 0, 0, 0);
            acc[t] = __builtin_amdgcn_mfma_f32_32x32x16_bf16(Al, Bf[k2][0], acc[t], 0, 0, 0);
        }
    }

    // C -> LDS transpose (rows = wave-local pixel, col = co)
#pragma unroll
    for (int t = 0; t < 2; ++t)
#pragma unroll
        for (int r = 0; r < 16; ++r) {
            int mm = (r & 3) + 8 * (r >> 2) + 4 * hf;
            lds_o[(wv * 64 + t * 32 + mm) * 33 + ln] = acc[t][r];
        }

    // pool partial reduce across the 32 m-lanes of each half
#pragma unroll
    for (int k2 = 0; k2 < 2; ++k2)
#pragma unroll
        for (int j = 0; j < 8; ++j) {
            float v = psum[k2][j];
            v += __shfl_xor(v, 1); v += __shfl_xor(v, 2);
            v += __shfl_xor(v, 4); v += __shfl_xor(v, 8);
            v += __shfl_xor(v, 16);
            psum[k2][j] = v;
        }
    if (ln == 0) {
#pragma unroll
        for (int k2 = 0; k2 < 2; ++k2)
#pragma unroll
            for (int j = 0; j < 8; ++j)
                poolw[wv][k2 * 16 + hf * 8 + j] = psum[k2][j];
    }
    __syncthreads();
    if (tid < 32) {
        float s = poolw[0][tid] + poolw[1][tid] + poolw[2][tid] + poolw[3][tid];
        poolp[((size_t)b * 16 + chunk) * 32 + tid] = s;
    }

    // ---- per-pixel epilogue
    int p = chunk * 256 + tid;
    float o[32];
    float nn = 0.0f;
#pragma unroll
    for (int oo = 0; oo < 32; ++oo) {
        o[oo] = lds_o[tid * 33 + oo];
        nn = fmaf(o[oo], o[oo], nn);
    }
    float n = sqrtf(nn);
    float inv = 1.0f / fmaxf(n, 1e-6f);
    if (vpad) {
        int y = p >> 6, x = p & 63;
        unsigned short* vb_ = outn + (size_t)b * 32 * 4608 + y * 72 + x + 4;
#pragma unroll
        for (int oo = 0; oo < 32; ++oo) {
            unsigned short hv = f2bf(o[oo] * inv);
            unsigned short* row = vb_ + (size_t)oo * 4608;
            row[0] = hv;
            if (x == 0) { row[-4] = hv; row[-3] = hv; row[-2] = hv; row[-1] = hv; }
            if (x == 63) { row[1] = hv; row[2] = hv; row[3] = hv; row[4] = hv; }
        }
    } else {
        unsigned short* obp = outn + (size_t)b * 32 * HW + p;
#pragma unroll
        for (int oo = 0; oo < 32; ++oo) obp[(size_t)oo * HW] = f2bf(o[oo] * inv);
    }

    if (E != nullptr) {
        float e = nn * inv * inv;
        E[(size_t)b * HW + p] = e;
        float wvv = e * gauss[p];
#pragma unroll
        for (int off = 32; off > 0; off >>= 1) wvv += __shfl_down(wvv, off);
        if ((tid & 63) == 0) sR[tid >> 6] = wvv;
        __syncthreads();
        if (tid == 0) swp[b * 16 + chunk] = sR[0] + sR[1] + sR[2] + sR[3];
    }
}

// ---------------------------------------------------------------------------
// 49-offset correlation logits. (unchanged)
// ---------------------------------------------------------------------------
__global__ __launch_bounds__(256) void logits_kernel(
    const unsigned short* __restrict__ rn, const unsigned short* __restrict__ vnp,
    const float* __restrict__ E, const float* __restrict__ swp,
    const float* __restrict__ gauss, float* __restrict__ lgpart) {
    int b = blockIdx.x, cg = blockIdx.y, tid = threadIdx.x;
    __shared__ float sR[4][49];
    float acc[49];
#pragma unroll
    for (int k = 0; k < 49; ++k) acc[k] = 0.0f;
    float ssum = 0.0f;
#pragma unroll
    for (int i = 0; i < 16; ++i) ssum += swp[b * 16 + i];
    const float scale = 0.17677669529663688f / (ssum + 1e-8f);
    const int x0 = (tid & 7) * 8;
    const float* Eb = E + (size_t)b * HW;
#pragma unroll 1
    for (int half = 0; half < 2; ++half) {
        const int y = half * 32 + (tid >> 3);
        const int pbase = y * 64 + x0;
        float4 e0 = *(const float4*)(Eb + pbase);
        float4 e1 = *(const float4*)(Eb + pbase + 4);
        float4 g0 = *(const float4*)(gauss + pbase);
        float4 g1 = *(const float4*)(gauss + pbase + 4);
        float qw[8];
        qw[0] = e0.x * g0.x * scale; qw[1] = e0.y * g0.y * scale;
        qw[2] = e0.z * g0.z * scale; qw[3] = e0.w * g0.w * scale;
        qw[4] = e1.x * g1.x * scale; qw[5] = e1.y * g1.y * scale;
        qw[6] = e1.z * g1.z * scale; qw[7] = e1.w * g1.w * scale;
#pragma unroll 1
        for (int cc = 0; cc < 4; ++cc) {
            int c = cg * 4 + cc;
            const unsigned short* rb = rn + ((size_t)b * 32 + c) * HW;
            uint4 rv = *(const uint4*)(rb + pbase);
            unsigned int rd[4] = {rv.x, rv.y, rv.z, rv.w};
            float r_[8];
            r_[0] = bf2f((unsigned short)(rd[0] & 0xFFFF)) * qw[0];
            r_[1] = bf2f((unsigned short)(rd[0] >> 16)) * qw[1];
            r_[2] = bf2f((unsigned short)(rd[1] & 0xFFFF)) * qw[2];
            r_[3] = bf2f((unsigned short)(rd[1] >> 16)) * qw[3];
            r_[4] = bf2f((unsigned short)(rd[2] & 0xFFFF)) * qw[4];
            r_[5] = bf2f((unsigned short)(rd[2] >> 16)) * qw[5];
            r_[6] = bf2f((unsigned short)(rd[3] & 0xFFFF)) * qw[6];
            r_[7] = bf2f((unsigned short)(rd[3] >> 16)) * qw[7];
            const unsigned short* vplane = vnp + ((size_t)b * 32 + c) * 4608;
#pragma unroll
            for (int dy = 0; dy < 7; ++dy) {
                int ry = y + dy - 3;
                ry = ry < 0 ? 0 : (ry > 63 ? 63 : ry);
                const unsigned short* vp = vplane + ry * 72 + x0;
                uint4 va = *(const uint4*)vp;
                uint4 vb2 = *(const uint4*)(vp + 8);
                unsigned int vd[8] = {va.x, va.y, va.z, va.w, vb2.x, vb2.y, vb2.z, vb2.w};
                float v[16];
#pragma unroll
                for (int j2 = 0; j2 < 8; ++j2) {
                    v[j2 * 2] = bf2f((unsigned short)(vd[j2] & 0xFFFF));
                    v[j2 * 2 + 1] = bf2f((unsigned short)(vd[j2] >> 16));
                }
#pragma unroll
                for (int dx = 0; dx < 7; ++dx)
#pragma unroll
                    for (int j = 0; j < 8; ++j)
                        acc[dy * 7 + dx] = fmaf(r_[j], v[j + dx + 1], acc[dy * 7 + dx]);
            }
        }
    }
#pragma unroll
    for (int k = 0; k < 49; ++k) {
#pragma unroll
        for (int off = 32; off > 0; off >>= 1) acc[k] += __shfl_down(acc[k], off);
    }
    int wid = tid >> 6;
    if ((tid & 63) == 0) {
#pragma unroll
        for (int k = 0; k < 49; ++k) sR[wid][k] = acc[k];
    }
    __syncthreads();
    if (tid < 49)
        lgpart[((size_t)b * 8 + cg) * 49 + tid] =
            sR[0][tid] + sR[1][tid] + sR[2][tid] + sR[3][tid];
}

// ---------------------------------------------------------------------------
__global__ __launch_bounds__(128) void head_kernel(
    const float* __restrict__ lg, const float* __restrict__ rpp,
    const float* __restrict__ vpp, const float* __restrict__ p2s,
    const float* __restrict__ log_temp,
    const float* __restrict__ W1, const float* __restrict__ b1,
    const float* __restrict__ W2, const float* __restrict__ b2,
    const float* __restrict__ W3, const float* __restrict__ b3,
    float* __restrict__ out) {
    int b = blockIdx.x, t = threadIdx.x;
    __shared__ float slg[49];
    __shared__ float pooled[98];
    __shared__ float h1[128], h2[128];
    __shared__ float cxy[2];
    __shared__ float res[3];
    const float* lgp = lg + (size_t)b * 8 * 49;
    if (t < 49) {
        float s = 0.0f;
#pragma unroll
        for (int g = 0; g < 8; ++g) s += lgp[g * 49 + t];
        slg[t] = s;
    }
    __syncthreads();
    if (t == 0) {
        float temp = fmaxf(expf(log_temp[0]), 0.001f);
        float invT = 1.0f / temp;
        float m = -1e30f;
        for (int k = 0; k < 49; ++k) m = fmaxf(m, slg[k] * invT);
        float s = 0.0f, pdx = 0.0f, pdy = 0.0f;
        for (int k = 0; k < 49; ++k) {
            float e = expf(slg[k] * invT - m);
            s += e;
            pdx += e * (float)((k % 7) - 3);
            pdy += e * (float)((k / 7) - 3);
        }
        cxy[0] = pdx / s;
        cxy[1] = pdy / s;
    }
    __syncthreads();
    if (t < 32) {
        float a = 0.0f, c = 0.0f;
#pragma unroll
        for (int k = 0; k < 16; ++k) {
            a += rpp[((size_t)b * 16 + k) * 32 + t];
            c += vpp[((size_t)b * 16 + k) * 32 + t];
        }
        pooled[t] = a;
        pooled[32 + t] = c;
        pooled[64 + t] = a - c;
    }
    if (t == 0) {
        pooled[96] = cxy[0];
        pooled[97] = cxy[1];
    }
    __syncthreads();
    float s1 = b1[t];
    for (int i = 0; i < 98; ++i) s1 = fmaf(pooled[i], W1[i * 128 + t], s1);
    h1[t] = gelu_f(s1);
    __syncthreads();
    float s2 = b2[t];
    for (int i = 0; i < 128; ++i) s2 = fmaf(h1[i], W2[i * 128 + t], s2);
    h2[t] = gelu_f(s2);
    __syncthreads();
    if (t < 3) {
        float r = b3[t];
        for (int i = 0; i < 128; ++i) r = fmaf(h2[i], W3[i * 3 + t], r);
        res[t] = r;
    }
    __syncthreads();
    if (t == 0) {
        float dxp = cxy[0] + res[0];
        float dyp = cxy[1] + res[1];
        float ls = fminf(fmaxf(res[2], -6.0f), 3.0f);
        const float* M = p2s + b * 4;
        float* ob = out + b * 54;
        ob[0] = dxp;
        ob[1] = dyp;
        ob[2] = M[0] * dxp + M[1] * dyp;
        ob[3] = M[2] * dxp + M[3] * dyp;
        ob[4] = ls;
    }
    if (t < 49) out[b * 54 + 5 + t] = slg[t];
}

extern "C" void kernel_launch(void* const* d_in, const int* in_sizes, int n_in,
                              void* d_out, int out_size, void* d_ws, size_t ws_size,
                              hipStream_t stream) {
    (void)in_sizes; (void)n_in; (void)out_size;
    const float* rubin = (const float*)d_in[0];
    const float* vis   = (const float*)d_in[1];
    const float* p2s   = (const float*)d_in[2];
    const float* rW0   = (const float*)d_in[3];
    const float* rWs   = (const float*)d_in[4];
    const float* rG    = (const float*)d_in[5];
    const float* rBt   = (const float*)d_in[6];
    const float* vW0   = (const float*)d_in[7];
    const float* vWs   = (const float*)d_in[8];
    const float* vG    = (const float*)d_in[9];
    const float* vBt   = (const float*)d_in[10];
    const float* projR = (const float*)d_in[11];
    const float* projV = (const float*)d_in[12];
    const float* logT  = (const float*)d_in[13];
    const float* W1    = (const float*)d_in[14];
    const float* b1    = (const float*)d_in[15];
    const float* W2    = (const float*)d_in[16];
    const float* b2    = (const float*)d_in[17];
    const float* W3    = (const float*)d_in[18];
    const float* b3    = (const float*)d_in[19];
    float* out = (float*)d_out;

    // ---- workspace layout (bytes)
    char* ws = (char*)d_ws;
    size_t off = 0;
    unsigned short* vnB = (unsigned short*)(ws + off); off += (size_t)NB * 32 * 4608 * 2;
    float* gauss  = (float*)(ws + off); off += HW * 4;
    float* statp  = (float*)(ws + off); off += (size_t)NB * 16 * 8 * 4;
    float* coefS  = (float*)(ws + off); off += (size_t)NB * 64 * 4;
    float* swp    = (float*)(ws + off); off += (size_t)NB * 16 * 4;
    float* rpp    = (float*)(ws + off); off += (size_t)NB * 16 * 32 * 4;
    float* vpp    = (float*)(ws + off); off += (size_t)NB * 16 * 32 * 4;
    float* lgbuf  = (float*)(ws + off); off += (size_t)NB * 8 * 49 * 4;
    unsigned short* wq = (unsigned short*)(ws + off); off += 119808ull * 2;
    off = (off + 255) & ~(size_t)255;
    const size_t fixed_bytes = off;
    const size_t perb = 2ull * HW * 64 + HW * 4;
    int BC = 1;
    if (ws_size > fixed_bytes + perb) {
        size_t t = (ws_size - fixed_bytes) / perb;
        BC = t > (size_t)NB ? NB : (int)t;
    }
    unsigned short* Q1 = (unsigned short*)(ws + off);
    unsigned short* Q2 = (unsigned short*)(ws + off + (size_t)BC * HW * 64);
    float* E = (float*)(ws + off + 2ull * BC * HW * 64);
    unsigned short* wq0r = wq + 110592;
    unsigned short* wq0v = wq + 114688;
    unsigned short* wqpR = wq + 115712;
    unsigned short* wqpV = wq + 117760;

    dim3 blk256(256), blk128(128);
    gauss_kernel<<<1, 256, 0, stream>>>(gauss);
    prep_w_kernel<<<468, 256, 0, stream>>>(rWs, vWs, rW0, vW0, projR, projV, wq);

    // ================= VIS encoder (all chunks) =================
    for (int b0 = 0; b0 < NB; b0 += BC) {
        const int bc = (NB - b0) < BC ? (NB - b0) : BC;
        dim3 cg16(16, bc), cg8(8, bc);
        const int gnblk = (bc * 32 + 255) / 256;
        float* sp = statp + (size_t)b0 * 128;
        float* cS = coefS + (size_t)b0 * 64;

        conv_first_m_kernel<1><<<cg16, blk128, 0, stream>>>(vis + (size_t)b0 * HW, wq0v, Q1, sp);
        gn_finalize_kernel<<<gnblk, 256, 0, stream>>>(sp, vG + 0, vBt + 0, cS, bc * 32, 16);
        convm_kernel<<<cg8, blk256, 0, stream>>>(Q1, cS, wq + 3 * 18432, Q2, sp);
        gn_finalize_kernel<<<gnblk, 256, 0, stream>>>(sp, vG + 32, vBt + 32, cS, bc * 32, 8);
        convm_kernel<<<cg8, blk256, 0, stream>>>(Q2, cS, wq + 4 * 18432, Q1, sp);
        gn_finalize_kernel<<<gnblk, 256, 0, stream>>>(sp, vG + 64, vBt + 64, cS, bc * 32, 8);
        convm_kernel<<<cg8, blk256, 0, stream>>>(Q1, cS, wq + 5 * 18432, Q2, sp);
        gn_finalize_kernel<<<gnblk, 256, 0, stream>>>(sp, vG + 96, vBt + 96, cS, bc * 32, 8);
        proj_kernel<<<cg16, blk256, 0, stream>>>(Q2, cS, wqpV, vnB + (size_t)b0 * 32 * 4608,
                                                 vpp + (size_t)b0 * 512,
                                                 (float*)nullptr, (float*)nullptr, gauss, 1);
    }

    // ================= RUBIN encoder + logits (all chunks) =================
    for (int b0 = 0; b0 < NB; b0 += BC) {
        const int bc = (NB - b0) < BC ? (NB - b0) : BC;
        dim3 cg16(16, bc), cg8(8, bc);
        const int gnblk = (bc * 32 + 255) / 256;
        float* sp = statp + (size_t)b0 * 128;
        float* cS = coefS + (size_t)b0 * 64;
        float* sw = swp + (size_t)b0 * 16;
        unsigned short* rnB = Q1;

        conv_first_m_kernel<6><<<cg16, blk128, 0, stream>>>(rubin + (size_t)b0 * 6 * HW, wq0r, Q1, sp);
        gn_finalize_kernel<<<gnblk, 256, 0, stream>>>(sp, rG + 0, rBt + 0, cS, bc * 32, 16);
        convm_kernel<<<cg8, blk256, 0, stream>>>(Q1, cS, wq + 0 * 18432, Q2, sp);
        gn_finalize_kernel<<<gnblk, 256, 0, stream>>>(sp, rG + 32, rBt + 32, cS, bc * 32, 8);
        convm_kernel<<<cg8, blk256, 0, stream>>>(Q2, cS, wq + 1 * 18432, Q1, sp);
        gn_finalize_kernel<<<gnblk, 256, 0, stream>>>(sp, rG + 64, rBt + 64, cS, bc * 32, 8);
        convm_kernel<<<cg8, blk256, 0, stream>>>(Q1, cS, wq + 2 * 18432, Q2, sp);
        gn_finalize_kernel<<<gnblk, 256, 0, stream>>>(sp, rG + 96, rBt + 96, cS, bc * 32, 8);
        proj_kernel<<<cg16, blk256, 0, stream>>>(Q2, cS, wqpR, rnB,
                                                 rpp + (size_t)b0 * 512, E, sw, gauss, 0);
        logits_kernel<<<dim3(bc, 8), blk256, 0, stream>>>(rnB, vnB + (size_t)b0 * 32 * 4608,
                                                          E, sw, gauss,
                                                          lgbuf + (size_t)b0 * 8 * 49);
    }

    head_kernel<<<NB, 128, 0, stream>>>(lgbuf, rpp, vpp, p2s, logT, W1, b1, W2, b2, W3, b3, out);
}